// Round 2
// baseline (297.795 us; speedup 1.0000x reference)
//
#include <hip/hip_runtime.h>
#include <hip/hip_bf16.h>

// Problem constants: B=2, T=2048, E=512, H=8, hd=64, M=64, l=32, BH=16.
#define TB 2048
#define EB 512

// ---------------------------------------------------------------- pool x
// xp[b][m][e] = mean_{i<32} x[b][m*32+i][e]
__global__ __launch_bounds__(256) void k_pool(const float* __restrict__ x,
                                              float* __restrict__ xp) {
  int idx = blockIdx.x * 256 + threadIdx.x;  // [0, 2*64*512)
  int b = idx >> 15;
  int rem = idx & 32767;
  int m = rem >> 9;
  int e = rem & 511;
  const float* src = x + (b * TB + m * 32) * EB + e;
  float s = 0.f;
#pragma unroll
  for (int i = 0; i < 32; ++i) s += src[i * EB];
  xp[idx] = s * (1.f / 32.f);
}

// ---------------------------------------------------------------- q GEMM
// q[b,h,t,d] = (x[4096,512] @ w_qkv[:,0:512] + b_qkv) * 0.125, head-major.
__global__ __launch_bounds__(256) void k_gemm_q(const float* __restrict__ x,
                                                const float* __restrict__ w,
                                                const float* __restrict__ bq,
                                                float* __restrict__ q) {
  __shared__ float As[16][68];  // [k][m] transposed
  __shared__ float Bs[16][68];  // [k][n]
  const int tid = threadIdx.x;
  const int n0 = blockIdx.x * 64, m0 = blockIdx.y * 64;
  const int ty = tid >> 4, tx = tid & 15;
  const int lrow = tid >> 2, lkc = (tid & 3) * 4;
  const int brow = tid >> 4, bcol = (tid & 15) * 4;
  float acc[4][4] = {};
  for (int k0 = 0; k0 < 512; k0 += 16) {
    float4 av = *(const float4*)(x + (m0 + lrow) * 512 + k0 + lkc);
    float4 bv = *(const float4*)(w + (k0 + brow) * 1536 + n0 + bcol);
    As[lkc + 0][lrow] = av.x; As[lkc + 1][lrow] = av.y;
    As[lkc + 2][lrow] = av.z; As[lkc + 3][lrow] = av.w;
    *(float4*)&Bs[brow][bcol] = bv;
    __syncthreads();
#pragma unroll
    for (int kk = 0; kk < 16; ++kk) {
      float4 a4 = *(const float4*)&As[kk][ty * 4];
      float4 b4 = *(const float4*)&Bs[kk][tx * 4];
      const float* ap = (const float*)&a4;
      const float* bp = (const float*)&b4;
#pragma unroll
      for (int mi = 0; mi < 4; ++mi)
#pragma unroll
        for (int ni = 0; ni < 4; ++ni) acc[mi][ni] += ap[mi] * bp[ni];
    }
    __syncthreads();
  }
#pragma unroll
  for (int mi = 0; mi < 4; ++mi) {
    int r = m0 + ty * 4 + mi;
    int b = r >> 11, t = r & 2047;
#pragma unroll
    for (int ni = 0; ni < 4; ++ni) {
      int c = n0 + tx * 4 + ni;
      int h = c >> 6, d = c & 63;
      q[(((b << 3) | h) * 2048 + t) * 64 + d] = (acc[mi][ni] + bq[c]) * 0.125f;
    }
  }
}

// ---------------------------------------------------------------- small GEMMs
// variant 0: rows = (b, t<64) of x, cols 512..1535 -> k64, v64
// variant 1: rows = pooled xp,   cols 0..1023     -> ql(*0.125), kl
__global__ __launch_bounds__(256) void k_gemm_small(
    const float* __restrict__ x, const float* __restrict__ xp,
    const float* __restrict__ w, const float* __restrict__ bq,
    float* __restrict__ k64, float* __restrict__ v64,
    float* __restrict__ ql, float* __restrict__ kl) {
  __shared__ float As[16][68];
  __shared__ float Bs[16][68];
  const int variant = blockIdx.z;
  const int tid = threadIdx.x;
  const int n0 = blockIdx.x * 64, row0 = blockIdx.y * 64;
  const int bcol0 = (variant == 0 ? 512 : 0) + n0;  // global w column base
  const int ty = tid >> 4, tx = tid & 15;
  const int lrow = tid >> 2, lkc = (tid & 3) * 4;
  const int brow = tid >> 4, bcol = (tid & 15) * 4;
  float acc[4][4] = {};
  for (int k0 = 0; k0 < 512; k0 += 16) {
    int gr = row0 + lrow;  // 0..127
    const float* arow;
    if (variant == 0) {
      int b = gr >> 6, t = gr & 63;
      arow = x + (b * TB + t) * EB;
    } else {
      arow = xp + gr * EB;
    }
    float4 av = *(const float4*)(arow + k0 + lkc);
    float4 bv = *(const float4*)(w + (k0 + brow) * 1536 + bcol0 + bcol);
    As[lkc + 0][lrow] = av.x; As[lkc + 1][lrow] = av.y;
    As[lkc + 2][lrow] = av.z; As[lkc + 3][lrow] = av.w;
    *(float4*)&Bs[brow][bcol] = bv;
    __syncthreads();
#pragma unroll
    for (int kk = 0; kk < 16; ++kk) {
      float4 a4 = *(const float4*)&As[kk][ty * 4];
      float4 b4 = *(const float4*)&Bs[kk][tx * 4];
      const float* ap = (const float*)&a4;
      const float* bp = (const float*)&b4;
#pragma unroll
      for (int mi = 0; mi < 4; ++mi)
#pragma unroll
        for (int ni = 0; ni < 4; ++ni) acc[mi][ni] += ap[mi] * bp[ni];
    }
    __syncthreads();
  }
#pragma unroll
  for (int mi = 0; mi < 4; ++mi) {
    int r = row0 + ty * 4 + mi;
    int b = r >> 6, t = r & 63;  // t is landmark index for variant 1
#pragma unroll
    for (int ni = 0; ni < 4; ++ni) {
      int j = tx * 4 + ni;
      int cloc = n0 + j;              // 0..1023 local col
      int gc = bcol0 + j;             // global w col
      float val = acc[mi][ni] + bq[gc];
      int which = cloc >> 9;
      int hd_ = cloc & 511;
      int h = hd_ >> 6, d = hd_ & 63;
      int dst = ((b * 8 + h) * 64 + t) * 64 + d;
      if (variant == 0) {
        if (which == 0) k64[dst] = val; else v64[dst] = val;
      } else {
        if (which == 0) ql[dst] = val * 0.125f; else kl[dst] = val;
      }
    }
  }
}

// ---------------------------------------------------------------- A and BV
// A[i,j]  = softmax_{j<=i}(ql[i]·kl[j])   (zeros above diag)
// BV[i,d] = sum_j softmax_{j<=i}(ql[i]·k[j]) * v[j,d]
__global__ __launch_bounds__(256) void k_a_bv(
    const float* __restrict__ ql, const float* __restrict__ kl,
    const float* __restrict__ k64, const float* __restrict__ v64,
    float* __restrict__ A, float* __restrict__ BV) {
  __shared__ float qls[64][65], kls[64][65], ks[64][65], vs[64][65];
  __shared__ float ps[4][64];
  const int bh = blockIdx.x, tid = threadIdx.x;
  const int base = bh * 4096;
  for (int i = 0; i < 16; ++i) {
    int idx = i * 256 + tid;
    int r = idx >> 6, c = idx & 63;
    qls[r][c] = ql[base + idx];
    kls[r][c] = kl[base + idx];
    ks[r][c] = k64[base + idx];
    vs[r][c] = v64[base + idx];
  }
  __syncthreads();
  const int w = tid >> 6, lane = tid & 63;
  for (int rr = 0; rr < 16; ++rr) {
    int i = rr * 4 + w;
    bool ok = lane <= i;
    // --- A
    float s = 0.f;
    for (int d = 0; d < 64; ++d) s += qls[i][d] * kls[lane][d];
    float mv = ok ? s : -1e30f;
#pragma unroll
    for (int off = 32; off; off >>= 1) mv = fmaxf(mv, __shfl_xor(mv, off));
    float e = ok ? __expf(s - mv) : 0.f;
    float su = e;
#pragma unroll
    for (int off = 32; off; off >>= 1) su += __shfl_xor(su, off);
    A[base + i * 64 + lane] = e / su;
    // --- B_t row and BV
    s = 0.f;
    for (int d = 0; d < 64; ++d) s += qls[i][d] * ks[lane][d];
    mv = ok ? s : -1e30f;
#pragma unroll
    for (int off = 32; off; off >>= 1) mv = fmaxf(mv, __shfl_xor(mv, off));
    e = ok ? __expf(s - mv) : 0.f;
    su = e;
#pragma unroll
    for (int off = 32; off; off >>= 1) su += __shfl_xor(su, off);
    ps[w][lane] = e / su;
    float bv = 0.f;
    for (int j = 0; j < 64; ++j) bv += ps[w][j] * vs[j][lane];
    BV[base + i * 64 + lane] = bv;
  }
}

// ---------------------------------------------------------------- global scale
// scal[0] = 1 / (max over all rows of sum_j|A|  *  max over all cols of sum_i|A|)
__global__ __launch_bounds__(1024) void k_scal(const float* __restrict__ A,
                                               float* __restrict__ scal) {
  __shared__ float red[1024];
  const int tid = threadIdx.x;
  const int bh = tid >> 6, i = tid & 63;
  const float* Ab = A + bh * 4096;
  float cs = 0.f, rs = 0.f;
  for (int j = 0; j < 64; ++j) {
    cs += fabsf(Ab[i * 64 + j]);
    rs += fabsf(Ab[j * 64 + i]);
  }
  red[tid] = cs;
  __syncthreads();
  for (int s = 512; s; s >>= 1) {
    if (tid < s) red[tid] = fmaxf(red[tid], red[tid + s]);
    __syncthreads();
  }
  float mc = red[0];
  __syncthreads();
  red[tid] = rs;
  __syncthreads();
  for (int s = 512; s; s >>= 1) {
    if (tid < s) red[tid] = fmaxf(red[tid], red[tid + s]);
    __syncthreads();
  }
  if (tid == 0) scal[0] = 1.f / (mc * red[0]);
}

// ---------------------------------------------------------------- pinv (Newton-Schulz)
__device__ __forceinline__ void mm64(float (*D)[68], const float (*S1)[68],
                                     const float (*S2)[68], int tid) {
  const int ty = tid >> 4, tx = tid & 15;
  float acc[4][4] = {};
#pragma unroll
  for (int k4 = 0; k4 < 16; ++k4) {
    float4 a4[4], b4[4];
#pragma unroll
    for (int m = 0; m < 4; ++m) a4[m] = *(const float4*)&S1[ty * 4 + m][k4 * 4];
#pragma unroll
    for (int kk = 0; kk < 4; ++kk) b4[kk] = *(const float4*)&S2[k4 * 4 + kk][tx * 4];
#pragma unroll
    for (int kk = 0; kk < 4; ++kk) {
      const float* bp = (const float*)&b4[kk];
#pragma unroll
      for (int m = 0; m < 4; ++m) {
        float av = ((const float*)&a4[m])[kk];
#pragma unroll
        for (int n = 0; n < 4; ++n) acc[m][n] += av * bp[n];
      }
    }
  }
#pragma unroll
  for (int m = 0; m < 4; ++m)
    *(float4*)&D[ty * 4 + m][tx * 4] =
        make_float4(acc[m][0], acc[m][1], acc[m][2], acc[m][3]);
}

__global__ __launch_bounds__(256) void k_pinv(const float* __restrict__ A,
                                              const float* __restrict__ BV,
                                              const float* __restrict__ scal,
                                              float* __restrict__ C) {
  __shared__ float As[64][68], Zs[64][68], Ps[64][68], Qs[64][68], Rs[64][68];
  const int bh = blockIdx.x, tid = threadIdx.x;
  const int base = bh * 4096;
  for (int i = 0; i < 16; ++i) {
    int idx = i * 256 + tid;
    As[idx >> 6][idx & 63] = A[base + idx];
  }
  __syncthreads();
  const float sc = scal[0];
  for (int i = 0; i < 16; ++i) {
    int idx = i * 256 + tid;
    int r = idx >> 6, c = idx & 63;
    Zs[r][c] = As[c][r] * sc;  // z0 = A^T / (mc*mr)
  }
  __syncthreads();
  for (int it = 0; it < 6; ++it) {
    mm64(Ps, As, Zs, tid);  // P = A@Z
    __syncthreads();
    for (int i = 0; i < 16; ++i) {
      int idx = i * 256 + tid; int r = idx >> 6, c = idx & 63;
      Qs[r][c] = (r == c ? 7.f : 0.f) - Ps[r][c];
    }
    __syncthreads();
    mm64(Rs, Ps, Qs, tid);  // R = P@(7I-P)
    __syncthreads();
    for (int i = 0; i < 16; ++i) {
      int idx = i * 256 + tid; int r = idx >> 6, c = idx & 63;
      Qs[r][c] = (r == c ? 15.f : 0.f) - Rs[r][c];
    }
    __syncthreads();
    mm64(Rs, Ps, Qs, tid);  // R = P@(15I-...)
    __syncthreads();
    for (int i = 0; i < 16; ++i) {
      int idx = i * 256 + tid; int r = idx >> 6, c = idx & 63;
      Qs[r][c] = (r == c ? 13.f : 0.f) - Rs[r][c];
    }
    __syncthreads();
    mm64(Ps, Zs, Qs, tid);  // P = Z@(13I-...)
    __syncthreads();
    for (int i = 0; i < 16; ++i) {
      int idx = i * 256 + tid; int r = idx >> 6, c = idx & 63;
      Zs[r][c] = 0.25f * Ps[r][c];
    }
    __syncthreads();
  }
  // C = Z @ BV
  for (int i = 0; i < 16; ++i) {
    int idx = i * 256 + tid;
    Qs[idx >> 6][idx & 63] = BV[base + idx];
  }
  __syncthreads();
  mm64(Rs, Zs, Qs, tid);
  __syncthreads();
  for (int i = 0; i < 16; ++i) {
    int idx = i * 256 + tid;
    C[base + idx] = Rs[idx >> 6][idx & 63];
  }
}

// ---------------------------------------------------------------- F softmax + y = F@C
__global__ __launch_bounds__(512) void k_f_y(const float* __restrict__ q,
                                             const float* __restrict__ kl,
                                             const float* __restrict__ C,
                                             float* __restrict__ yh) {
  __shared__ float kls[64][65];
  __shared__ float Cs[64][65];
  __shared__ float qs[8][64];
  __shared__ float ps[8][64];
  const int bh = blockIdx.x;
  const int b = bh >> 3, h = bh & 7;
  const int tid = threadIdx.x;
  const int w = tid >> 6, lane = tid & 63;
  for (int i = 0; i < 8; ++i) {
    int idx = i * 512 + tid;
    int r = idx >> 6, c = idx & 63;
    kls[r][c] = kl[bh * 4096 + idx];
    Cs[r][c] = C[bh * 4096 + idx];
  }
  __syncthreads();
  const int t0 = blockIdx.y * 128 + w * 16;
  for (int rr = 0; rr < 16; ++rr) {
    int t = t0 + rr;
    qs[w][lane] = q[(bh * 2048 + t) * 64 + lane];
    float s = 0.f;
    for (int d = 0; d < 64; ++d) s += qs[w][d] * kls[lane][d];
    bool ok = lane <= t;
    float mv = ok ? s : -1e30f;
#pragma unroll
    for (int off = 32; off; off >>= 1) mv = fmaxf(mv, __shfl_xor(mv, off));
    float e = ok ? __expf(s - mv) : 0.f;
    float su = e;
#pragma unroll
    for (int off = 32; off; off >>= 1) su += __shfl_xor(su, off);
    ps[w][lane] = e / su;
    float acc = 0.f;
    for (int j = 0; j < 64; ++j) acc += ps[w][j] * Cs[j][lane];
    yh[(b * 2048 + t) * 512 + h * 64 + lane] = acc;
  }
}

// ---------------------------------------------------------------- output proj (f32 out)
__global__ __launch_bounds__(256) void k_gemm_proj(const float* __restrict__ yh,
                                                   const float* __restrict__ w,
                                                   const float* __restrict__ bp,
                                                   float* __restrict__ out) {
  __shared__ float As[16][68];
  __shared__ float Bs[16][68];
  const int tid = threadIdx.x;
  const int n0 = blockIdx.x * 64, m0 = blockIdx.y * 64;
  const int ty = tid >> 4, tx = tid & 15;
  const int lrow = tid >> 2, lkc = (tid & 3) * 4;
  const int brow = tid >> 4, bcol = (tid & 15) * 4;
  float acc[4][4] = {};
  for (int k0 = 0; k0 < 512; k0 += 16) {
    float4 av = *(const float4*)(yh + (m0 + lrow) * 512 + k0 + lkc);
    float4 bv = *(const float4*)(w + (k0 + brow) * 512 + n0 + bcol);
    As[lkc + 0][lrow] = av.x; As[lkc + 1][lrow] = av.y;
    As[lkc + 2][lrow] = av.z; As[lkc + 3][lrow] = av.w;
    *(float4*)&Bs[brow][bcol] = bv;
    __syncthreads();
#pragma unroll
    for (int kk = 0; kk < 16; ++kk) {
      float4 a4 = *(const float4*)&As[kk][ty * 4];
      float4 b4 = *(const float4*)&Bs[kk][tx * 4];
      const float* ap = (const float*)&a4;
      const float* bp2 = (const float*)&b4;
#pragma unroll
      for (int mi = 0; mi < 4; ++mi)
#pragma unroll
        for (int ni = 0; ni < 4; ++ni) acc[mi][ni] += ap[mi] * bp2[ni];
    }
    __syncthreads();
  }
#pragma unroll
  for (int mi = 0; mi < 4; ++mi) {
    int r = m0 + ty * 4 + mi;
#pragma unroll
    for (int ni = 0; ni < 4; ++ni) {
      int c = n0 + tx * 4 + ni;
      out[r * 512 + c] = acc[mi][ni] + bp[c];
    }
  }
}

// ---------------------------------------------------------------- launcher
extern "C" void kernel_launch(void* const* d_in, const int* in_sizes, int n_in,
                              void* d_out, int out_size, void* d_ws, size_t ws_size,
                              hipStream_t stream) {
  const float* x = (const float*)d_in[0];
  const float* w_qkv = (const float*)d_in[1];
  const float* b_qkv = (const float*)d_in[2];
  const float* w_proj = (const float*)d_in[3];
  const float* b_proj = (const float*)d_in[4];
  float* out = (float*)d_out;

  float* ws = (float*)d_ws;
  float* q = ws;              // 16*2048*64 = 2097152
  float* k64 = q + 2097152;   // 16*64*64 = 65536
  float* v64 = k64 + 65536;
  float* xp = v64 + 65536;    // 2*64*512
  float* ql = xp + 65536;
  float* kl = ql + 65536;
  float* Am = kl + 65536;
  float* BV = Am + 65536;
  float* Cm = BV + 65536;
  float* scal = Cm + 65536;   // 64 floats
  float* yh = scal + 64;      // 2*2048*512 = 2097152

  k_pool<<<dim3(256), dim3(256), 0, stream>>>(x, xp);
  k_gemm_q<<<dim3(8, 64), dim3(256), 0, stream>>>(x, w_qkv, b_qkv, q);
  k_gemm_small<<<dim3(16, 2, 2), dim3(256), 0, stream>>>(x, xp, w_qkv, b_qkv,
                                                         k64, v64, ql, kl);
  k_a_bv<<<dim3(16), dim3(256), 0, stream>>>(ql, kl, k64, v64, Am, BV);
  k_scal<<<dim3(1), dim3(1024), 0, stream>>>(Am, scal);
  k_pinv<<<dim3(16), dim3(256), 0, stream>>>(Am, BV, scal, Cm);
  k_f_y<<<dim3(16, 16), dim3(512), 0, stream>>>(q, kl, Cm, yh);
  k_gemm_proj<<<dim3(8, 64), dim3(256), 0, stream>>>(yh, w_proj, b_proj, out);
}

// Round 5
// 257.677 us; speedup vs baseline: 1.1557x; 1.1557x over previous
//
#include <hip/hip_runtime.h>
#include <hip/hip_bf16.h>

// Problem constants: B=2, T=2048, E=512, H=8, hd=64, M=64, l=32, BH=16.
#define TB 2048
#define EB 512

using short8 = __attribute__((ext_vector_type(8))) short;
using f32x4  = __attribute__((ext_vector_type(4))) float;

// ---------------------------------------------------------------- pool x
__global__ __launch_bounds__(256) void k_pool(const float* __restrict__ x,
                                              float* __restrict__ xp) {
  int idx = blockIdx.x * 256 + threadIdx.x;  // [0, 2*64*512)
  int b = idx >> 15;
  int rem = idx & 32767;
  int m = rem >> 9;
  int e = rem & 511;
  const float* src = x + (b * TB + m * 32) * EB + e;
  float s = 0.f;
#pragma unroll
  for (int i = 0; i < 32; ++i) s += src[i * EB];
  xp[idx] = s * (1.f / 32.f);
}

// ---------------------------------------------------------------- q GEMM
__global__ __launch_bounds__(256) void k_gemm_q(const float* __restrict__ x,
                                                const float* __restrict__ w,
                                                const float* __restrict__ bq,
                                                float* __restrict__ q) {
  __shared__ float As[16][68];
  __shared__ float Bs[16][68];
  const int tid = threadIdx.x;
  const int n0 = blockIdx.x * 64, m0 = blockIdx.y * 64;
  const int ty = tid >> 4, tx = tid & 15;
  const int lrow = tid >> 2, lkc = (tid & 3) * 4;
  const int brow = tid >> 4, bcol = (tid & 15) * 4;
  float acc[4][4] = {};
  for (int k0 = 0; k0 < 512; k0 += 16) {
    float4 av = *(const float4*)(x + (m0 + lrow) * 512 + k0 + lkc);
    float4 bv = *(const float4*)(w + (k0 + brow) * 1536 + n0 + bcol);
    As[lkc + 0][lrow] = av.x; As[lkc + 1][lrow] = av.y;
    As[lkc + 2][lrow] = av.z; As[lkc + 3][lrow] = av.w;
    *(float4*)&Bs[brow][bcol] = bv;
    __syncthreads();
#pragma unroll
    for (int kk = 0; kk < 16; ++kk) {
      float4 a4 = *(const float4*)&As[kk][ty * 4];
      float4 b4 = *(const float4*)&Bs[kk][tx * 4];
      const float* ap = (const float*)&a4;
      const float* bp = (const float*)&b4;
#pragma unroll
      for (int mi = 0; mi < 4; ++mi)
#pragma unroll
        for (int ni = 0; ni < 4; ++ni) acc[mi][ni] += ap[mi] * bp[ni];
    }
    __syncthreads();
  }
#pragma unroll
  for (int mi = 0; mi < 4; ++mi) {
    int r = m0 + ty * 4 + mi;
    int b = r >> 11, t = r & 2047;
#pragma unroll
    for (int ni = 0; ni < 4; ++ni) {
      int c = n0 + tx * 4 + ni;
      int h = c >> 6, d = c & 63;
      q[(((b << 3) | h) * 2048 + t) * 64 + d] = (acc[mi][ni] + bq[c]) * 0.125f;
    }
  }
}

// ---------------------------------------------------------------- small GEMMs
__global__ __launch_bounds__(256) void k_gemm_small(
    const float* __restrict__ x, const float* __restrict__ xp,
    const float* __restrict__ w, const float* __restrict__ bq,
    float* __restrict__ k64, float* __restrict__ v64,
    float* __restrict__ ql, float* __restrict__ kl) {
  __shared__ float As[16][68];
  __shared__ float Bs[16][68];
  const int variant = blockIdx.z;
  const int tid = threadIdx.x;
  const int n0 = blockIdx.x * 64, row0 = blockIdx.y * 64;
  const int bcol0 = (variant == 0 ? 512 : 0) + n0;
  const int ty = tid >> 4, tx = tid & 15;
  const int lrow = tid >> 2, lkc = (tid & 3) * 4;
  const int brow = tid >> 4, bcol = (tid & 15) * 4;
  float acc[4][4] = {};
  for (int k0 = 0; k0 < 512; k0 += 16) {
    int gr = row0 + lrow;
    const float* arow;
    if (variant == 0) {
      int b = gr >> 6, t = gr & 63;
      arow = x + (b * TB + t) * EB;
    } else {
      arow = xp + gr * EB;
    }
    float4 av = *(const float4*)(arow + k0 + lkc);
    float4 bv = *(const float4*)(w + (k0 + brow) * 1536 + bcol0 + bcol);
    As[lkc + 0][lrow] = av.x; As[lkc + 1][lrow] = av.y;
    As[lkc + 2][lrow] = av.z; As[lkc + 3][lrow] = av.w;
    *(float4*)&Bs[brow][bcol] = bv;
    __syncthreads();
#pragma unroll
    for (int kk = 0; kk < 16; ++kk) {
      float4 a4 = *(const float4*)&As[kk][ty * 4];
      float4 b4 = *(const float4*)&Bs[kk][tx * 4];
      const float* ap = (const float*)&a4;
      const float* bp = (const float*)&b4;
#pragma unroll
      for (int mi = 0; mi < 4; ++mi)
#pragma unroll
        for (int ni = 0; ni < 4; ++ni) acc[mi][ni] += ap[mi] * bp[ni];
    }
    __syncthreads();
  }
#pragma unroll
  for (int mi = 0; mi < 4; ++mi) {
    int r = row0 + ty * 4 + mi;
    int b = r >> 6, t = r & 63;
#pragma unroll
    for (int ni = 0; ni < 4; ++ni) {
      int j = tx * 4 + ni;
      int cloc = n0 + j;
      int gc = bcol0 + j;
      float val = acc[mi][ni] + bq[gc];
      int which = cloc >> 9;
      int hd_ = cloc & 511;
      int h = hd_ >> 6, d = hd_ & 63;
      int dst = ((b * 8 + h) * 64 + t) * 64 + d;
      if (variant == 0) {
        if (which == 0) k64[dst] = val; else v64[dst] = val;
      } else {
        if (which == 0) ql[dst] = val * 0.125f; else kl[dst] = val;
      }
    }
  }
}

// ---------------------------------------------------------------- A and BV
__global__ __launch_bounds__(256) void k_a_bv(
    const float* __restrict__ ql, const float* __restrict__ kl,
    const float* __restrict__ k64, const float* __restrict__ v64,
    float* __restrict__ A, float* __restrict__ BV) {
  __shared__ float qls[64][65], kls[64][65], ks[64][65], vs[64][65];
  __shared__ float ps[4][64];
  const int bh = blockIdx.x, tid = threadIdx.x;
  const int base = bh * 4096;
  for (int i = 0; i < 16; ++i) {
    int idx = i * 256 + tid;
    int r = idx >> 6, c = idx & 63;
    qls[r][c] = ql[base + idx];
    kls[r][c] = kl[base + idx];
    ks[r][c] = k64[base + idx];
    vs[r][c] = v64[base + idx];
  }
  __syncthreads();
  const int w = tid >> 6, lane = tid & 63;
  for (int rr = 0; rr < 16; ++rr) {
    int i = rr * 4 + w;
    bool ok = lane <= i;
    float s = 0.f;
    for (int d = 0; d < 64; ++d) s += qls[i][d] * kls[lane][d];
    float mv = ok ? s : -1e30f;
#pragma unroll
    for (int off = 32; off; off >>= 1) mv = fmaxf(mv, __shfl_xor(mv, off));
    float e = ok ? __expf(s - mv) : 0.f;
    float su = e;
#pragma unroll
    for (int off = 32; off; off >>= 1) su += __shfl_xor(su, off);
    A[base + i * 64 + lane] = e / su;
    s = 0.f;
    for (int d = 0; d < 64; ++d) s += qls[i][d] * ks[lane][d];
    mv = ok ? s : -1e30f;
#pragma unroll
    for (int off = 32; off; off >>= 1) mv = fmaxf(mv, __shfl_xor(mv, off));
    e = ok ? __expf(s - mv) : 0.f;
    su = e;
#pragma unroll
    for (int off = 32; off; off >>= 1) su += __shfl_xor(su, off);
    ps[w][lane] = e / su;
    float bv = 0.f;
    for (int j = 0; j < 64; ++j) bv += ps[w][j] * vs[j][lane];
    BV[base + i * 64 + lane] = bv;
  }
}

// ---------------------------------------------------------------- global scale
__global__ __launch_bounds__(1024) void k_scal(const float* __restrict__ A,
                                               float* __restrict__ scal) {
  __shared__ float red[1024];
  const int tid = threadIdx.x;
  const int bh = tid >> 6, i = tid & 63;
  const float* Ab = A + bh * 4096;
  float cs = 0.f, rs = 0.f;
  for (int j = 0; j < 64; ++j) {
    cs += fabsf(Ab[i * 64 + j]);
    rs += fabsf(Ab[j * 64 + i]);
  }
  red[tid] = cs;
  __syncthreads();
  for (int s = 512; s; s >>= 1) {
    if (tid < s) red[tid] = fmaxf(red[tid], red[tid + s]);
    __syncthreads();
  }
  float mc = red[0];
  __syncthreads();
  red[tid] = rs;
  __syncthreads();
  for (int s = 512; s; s >>= 1) {
    if (tid < s) red[tid] = fmaxf(red[tid], red[tid + s]);
    __syncthreads();
  }
  if (tid == 0) scal[0] = 1.f / (mc * red[0]);
}

// ---------------------------------------------------------------- pinv (MFMA Newton-Schulz)
// Matrices live in LDS as bf16 hi/lo planes [64][64] with XOR chunk swizzle:
//   element (row,col) at row*64 + ((((col>>3) ^ (row&7))<<3) | (col&7))
// "T" planes store M transposed (MT[c][r] = M[r][c]) so right-operand (B) frags
// load with the same contiguous-8 pattern as left-operand (A) frags.
// MFMA frag model: lane l supplies A[l&15][8*(l>>4)+i] / B[8*(l>>4)+i][l&15];
// C/D (verified): col=lane&15, row=(lane>>4)*4+reg.

__device__ __forceinline__ int swz_idx(int row, int col) {
  return row * 64 + ((((col >> 3) ^ (row & 7)) << 3) | (col & 7));
}

__device__ __forceinline__ void split_bf(float v, ushort& h, ushort& l) {
  __hip_bfloat16 bh = __float2bfloat16(v);
  float fh = __bfloat162float(bh);
  __hip_bfloat16 bl = __float2bfloat16(v - fh);
  h = *(ushort*)&bh;
  l = *(ushort*)&bl;
}

__device__ __forceinline__ void ld_afrags(const ushort* hp, const ushort* lp,
                                          int band, int lane,
                                          short8 ah[2], short8 al[2]) {
  const int g = lane >> 4, li = lane & 15;
  const int row = band + li;
#pragma unroll
  for (int kh = 0; kh < 2; ++kh) {
    int k0 = kh * 32 + 8 * g;
    int idx = row * 64 + ((((k0 >> 3) ^ (row & 7)) << 3));
    ah[kh] = *(const short8*)&hp[idx];
    al[kh] = *(const short8*)&lp[idx];
  }
}

// acc[nt] = S1 @ S2 for this wave's 16-row band; S1 frags in regs, S2 = T-planes.
__device__ __forceinline__ void mm_frags(const short8 ah[2], const short8 al[2],
                                         const ushort* bhp, const ushort* blp,
                                         int lane, f32x4 acc[4]) {
  const int g = lane >> 4, li = lane & 15;
#pragma unroll
  for (int nt = 0; nt < 4; ++nt) {
    f32x4 a = {0.f, 0.f, 0.f, 0.f};
#pragma unroll
    for (int kh = 0; kh < 2; ++kh) {
      int n = nt * 16 + li;
      int k0 = kh * 32 + 8 * g;
      int idx = n * 64 + ((((k0 >> 3) ^ (n & 7)) << 3));
      short8 bh = *(const short8*)&bhp[idx];
      short8 bl = *(const short8*)&blp[idx];
      a = __builtin_amdgcn_mfma_f32_16x16x32_bf16(al[kh], bh, a, 0, 0, 0);
      a = __builtin_amdgcn_mfma_f32_16x16x32_bf16(ah[kh], bl, a, 0, 0, 0);
      a = __builtin_amdgcn_mfma_f32_16x16x32_bf16(ah[kh], bh, a, 0, 0, 0);
    }
    acc[nt] = a;
  }
}

// write transposed planes: MT[col][row] = mul*acc + (row==col ? cI : 0)
__device__ __forceinline__ void wrT(ushort* hp, ushort* lp, int band, int lane,
                                    const f32x4 acc[4], float cI, float mul) {
  const int g = lane >> 4, li = lane & 15;
  const int r0 = band + 4 * g;
#pragma unroll
  for (int nt = 0; nt < 4; ++nt) {
    int c = nt * 16 + li;
    ushort h[4], l[4];
#pragma unroll
    for (int r = 0; r < 4; ++r) {
      float v = mul * acc[nt][r] + ((r0 + r) == c ? cI : 0.f);
      split_bf(v, h[r], l[r]);
    }
    int idx = c * 64 + (((((r0) >> 3) ^ (c & 7)) << 3) | (r0 & 7));
    *(ushort4*)&hp[idx] = make_ushort4(h[0], h[1], h[2], h[3]);
    *(ushort4*)&lp[idx] = make_ushort4(l[0], l[1], l[2], l[3]);
  }
}

// write normal planes: M[row][col] = mul*acc
__device__ __forceinline__ void wrN(ushort* hp, ushort* lp, int band, int lane,
                                    const f32x4 acc[4], float mul) {
  const int g = lane >> 4, li = lane & 15;
#pragma unroll
  for (int nt = 0; nt < 4; ++nt) {
    int c = nt * 16 + li;
#pragma unroll
    for (int r = 0; r < 4; ++r) {
      int row = band + 4 * g + r;
      ushort h, l;
      split_bf(mul * acc[nt][r], h, l);
      int idx = swz_idx(row, c);
      hp[idx] = h;
      lp[idx] = l;
    }
  }
}

__global__ __launch_bounds__(256) void k_pinv(const float* __restrict__ A,
                                              const float* __restrict__ BVg,
                                              const float* __restrict__ scal,
                                              float* __restrict__ C) {
  __shared__ ushort ZT_h[4096], ZT_l[4096], ZA_h[4096], ZA_l[4096],
                    PA_h[4096], PA_l[4096], QA_h[4096], QA_l[4096],
                    QB_h[4096], QB_l[4096], BT_h[4096], BT_l[4096];
  const int bh = blockIdx.x, tid = threadIdx.x;
  const int lane = tid & 63, w = tid >> 6, band = w * 16;
  const int base = bh * 4096;
  const float sc = scal[0];
  const float* Ag = A + base;
  const float* Bg = BVg + base;

  // --- prologue: ZT = sc*A (row-major), ZA = sc*A^T, BT = BV^T
  {
    int prow = tid >> 2;
    int pc0 = (tid & 3) * 16;
#pragma unroll 4
    for (int j = 0; j < 16; ++j) {
      int col = pc0 + j;
      float av = Ag[prow * 64 + col] * sc;
      ushort h, l;
      split_bf(av, h, l);
      int i1 = swz_idx(prow, col);
      ZT_h[i1] = h; ZT_l[i1] = l;
      int i2 = swz_idx(col, prow);
      ZA_h[i2] = h; ZA_l[i2] = l;
      float bv = Bg[prow * 64 + col];
      split_bf(bv, h, l);
      BT_h[i2] = h; BT_l[i2] = l;
    }
  }
  // --- A frags direct from global (cached whole kernel)
  short8 a_h[2], a_l[2];
  {
    const int g = lane >> 4, li = lane & 15;
    int row = band + li;
#pragma unroll
    for (int kh = 0; kh < 2; ++kh) {
      int k0 = kh * 32 + 8 * g;
      float tmp[8];
      *(float4*)&tmp[0] = *(const float4*)&Ag[row * 64 + k0];
      *(float4*)&tmp[4] = *(const float4*)&Ag[row * 64 + k0 + 4];
      short8 hv, lv;
#pragma unroll
      for (int i = 0; i < 8; ++i) {
        ushort h, l;
        split_bf(tmp[i], h, l);
        hv[i] = (short)h;
        lv[i] = (short)l;
      }
      a_h[kh] = hv;
      a_l[kh] = lv;
    }
  }
  __syncthreads();

  for (int it = 0; it < 6; ++it) {
    f32x4 acc[4];
    // mm1: P = A @ Z
    mm_frags(a_h, a_l, ZT_h, ZT_l, lane, acc);
    wrN(PA_h, PA_l, band, lane, acc, 1.f);        // P (left-operand form)
    wrT(QA_h, QA_l, band, lane, acc, 7.f, -1.f);  // Q1 = 7I - P
    __syncthreads();
    short8 p_h[2], p_l[2];
    ld_afrags(PA_h, PA_l, band, lane, p_h, p_l);
    // mm2: R = P @ Q1
    mm_frags(p_h, p_l, QA_h, QA_l, lane, acc);
    wrT(QB_h, QB_l, band, lane, acc, 15.f, -1.f); // Q2 = 15I - R
    __syncthreads();
    // mm3: R2 = P @ Q2
    mm_frags(p_h, p_l, QB_h, QB_l, lane, acc);
    wrT(QA_h, QA_l, band, lane, acc, 13.f, -1.f); // Q3 = 13I - R2
    __syncthreads();
    short8 z_h[2], z_l[2];
    ld_afrags(ZA_h, ZA_l, band, lane, z_h, z_l);
    // mm4: Znew = 0.25 * (Z @ Q3)
    mm_frags(z_h, z_l, QA_h, QA_l, lane, acc);
    wrN(ZA_h, ZA_l, band, lane, acc, 0.25f);
    wrT(ZT_h, ZT_l, band, lane, acc, 0.f, 0.25f);
    __syncthreads();
  }
  // --- epilogue: C = Z @ BV
  {
    short8 z_h[2], z_l[2];
    ld_afrags(ZA_h, ZA_l, band, lane, z_h, z_l);
    f32x4 acc[4];
    mm_frags(z_h, z_l, BT_h, BT_l, lane, acc);
    const int g = lane >> 4, li = lane & 15;
#pragma unroll
    for (int nt = 0; nt < 4; ++nt) {
#pragma unroll
      for (int r = 0; r < 4; ++r) {
        int row = band + 4 * g + r;
        int col = nt * 16 + li;
        C[base + row * 64 + col] = acc[nt][r];
      }
    }
  }
}

// ---------------------------------------------------------------- F softmax + y = F@C
__global__ __launch_bounds__(512) void k_f_y(const float* __restrict__ q,
                                             const float* __restrict__ kl,
                                             const float* __restrict__ C,
                                             float* __restrict__ yh) {
  __shared__ float kls[64][65];
  __shared__ float Cs[64][65];
  __shared__ float qs[8][64];
  __shared__ float ps[8][64];
  const int bh = blockIdx.x;
  const int b = bh >> 3, h = bh & 7;
  const int tid = threadIdx.x;
  const int w = tid >> 6, lane = tid & 63;
  for (int i = 0; i < 8; ++i) {
    int idx = i * 512 + tid;
    int r = idx >> 6, c = idx & 63;
    kls[r][c] = kl[bh * 4096 + idx];
    Cs[r][c] = C[bh * 4096 + idx];
  }
  __syncthreads();
  const int t0 = blockIdx.y * 128 + w * 16;
  for (int rr = 0; rr < 16; ++rr) {
    int t = t0 + rr;
    qs[w][lane] = q[(bh * 2048 + t) * 64 + lane];
    float s = 0.f;
    for (int d = 0; d < 64; ++d) s += qs[w][d] * kls[lane][d];
    bool ok = lane <= t;
    float mv = ok ? s : -1e30f;
#pragma unroll
    for (int off = 32; off; off >>= 1) mv = fmaxf(mv, __shfl_xor(mv, off));
    float e = ok ? __expf(s - mv) : 0.f;
    float su = e;
#pragma unroll
    for (int off = 32; off; off >>= 1) su += __shfl_xor(su, off);
    ps[w][lane] = e / su;
    float acc = 0.f;
    for (int j = 0; j < 64; ++j) acc += ps[w][j] * Cs[j][lane];
    yh[(b * 2048 + t) * 512 + h * 64 + lane] = acc;
  }
}

// ---------------------------------------------------------------- output proj (f32 out)
__global__ __launch_bounds__(256) void k_gemm_proj(const float* __restrict__ yh,
                                                   const float* __restrict__ w,
                                                   const float* __restrict__ bp,
                                                   float* __restrict__ out) {
  __shared__ float As[16][68];
  __shared__ float Bs[16][68];
  const int tid = threadIdx.x;
  const int n0 = blockIdx.x * 64, m0 = blockIdx.y * 64;
  const int ty = tid >> 4, tx = tid & 15;
  const int lrow = tid >> 2, lkc = (tid & 3) * 4;
  const int brow = tid >> 4, bcol = (tid & 15) * 4;
  float acc[4][4] = {};
  for (int k0 = 0; k0 < 512; k0 += 16) {
    float4 av = *(const float4*)(yh + (m0 + lrow) * 512 + k0 + lkc);
    float4 bv = *(const float4*)(w + (k0 + brow) * 512 + n0 + bcol);
    As[lkc + 0][lrow] = av.x; As[lkc + 1][lrow] = av.y;
    As[lkc + 2][lrow] = av.z; As[lkc + 3][lrow] = av.w;
    *(float4*)&Bs[brow][bcol] = bv;
    __syncthreads();
#pragma unroll
    for (int kk = 0; kk < 16; ++kk) {
      float4 a4 = *(const float4*)&As[kk][ty * 4];
      float4 b4 = *(const float4*)&Bs[kk][tx * 4];
      const float* ap = (const float*)&a4;
      const float* bp2 = (const float*)&b4;
#pragma unroll
      for (int mi = 0; mi < 4; ++mi)
#pragma unroll
        for (int ni = 0; ni < 4; ++ni) acc[mi][ni] += ap[mi] * bp2[ni];
    }
    __syncthreads();
  }
#pragma unroll
  for (int mi = 0; mi < 4; ++mi) {
    int r = m0 + ty * 4 + mi;
#pragma unroll
    for (int ni = 0; ni < 4; ++ni) {
      int c = n0 + tx * 4 + ni;
      out[r * 512 + c] = acc[mi][ni] + bp[c];
    }
  }
}

// ---------------------------------------------------------------- launcher
extern "C" void kernel_launch(void* const* d_in, const int* in_sizes, int n_in,
                              void* d_out, int out_size, void* d_ws, size_t ws_size,
                              hipStream_t stream) {
  const float* x = (const float*)d_in[0];
  const float* w_qkv = (const float*)d_in[1];
  const float* b_qkv = (const float*)d_in[2];
  const float* w_proj = (const float*)d_in[3];
  const float* b_proj = (const float*)d_in[4];
  float* out = (float*)d_out;

  float* ws = (float*)d_ws;
  float* q = ws;              // 16*2048*64 = 2097152
  float* k64 = q + 2097152;   // 16*64*64 = 65536
  float* v64 = k64 + 65536;
  float* xp = v64 + 65536;    // 2*64*512
  float* ql = xp + 65536;
  float* kl = ql + 65536;
  float* Am = kl + 65536;
  float* BV = Am + 65536;
  float* Cm = BV + 65536;
  float* scal = Cm + 65536;   // 64 floats
  float* yh = scal + 64;      // 2*2048*512 = 2097152

  k_pool<<<dim3(256), dim3(256), 0, stream>>>(x, xp);
  k_gemm_q<<<dim3(8, 64), dim3(256), 0, stream>>>(x, w_qkv, b_qkv, q);
  k_gemm_small<<<dim3(16, 2, 2), dim3(256), 0, stream>>>(x, xp, w_qkv, b_qkv,
                                                         k64, v64, ql, kl);
  k_a_bv<<<dim3(16), dim3(256), 0, stream>>>(ql, kl, k64, v64, Am, BV);
  k_scal<<<dim3(1), dim3(1024), 0, stream>>>(Am, scal);
  k_pinv<<<dim3(16), dim3(256), 0, stream>>>(Am, BV, scal, Cm);
  k_f_y<<<dim3(16, 16), dim3(512), 0, stream>>>(q, kl, Cm, yh);
  k_gemm_proj<<<dim3(8, 64), dim3(256), 0, stream>>>(yh, w_proj, b_proj, out);
}

// Round 6
// 219.046 us; speedup vs baseline: 1.3595x; 1.1764x over previous
//
#include <hip/hip_runtime.h>
#include <hip/hip_bf16.h>

// Problem constants: B=2, T=2048, E=512, H=8, hd=64, M=64, l=32, BH=16.
#define TB 2048
#define EB 512

using short8 = __attribute__((ext_vector_type(8))) short;
using f32x4  = __attribute__((ext_vector_type(4))) float;

// ---------------------------------------------------------------- pool x
__global__ __launch_bounds__(256) void k_pool(const float* __restrict__ x,
                                              float* __restrict__ xp) {
  int idx = blockIdx.x * 256 + threadIdx.x;  // [0, 2*64*512)
  int b = idx >> 15;
  int rem = idx & 32767;
  int m = rem >> 9;
  int e = rem & 511;
  const float* src = x + (b * TB + m * 32) * EB + e;
  float s = 0.f;
#pragma unroll
  for (int i = 0; i < 32; ++i) s += src[i * EB];
  xp[idx] = s * (1.f / 32.f);
}

// ---------------------------------------------------------------- shared helpers
__device__ __forceinline__ int swz_idx(int row, int col) {
  return row * 64 + ((((col >> 3) ^ (row & 7)) << 3) | (col & 7));
}

__device__ __forceinline__ void split_bf(float v, ushort& h, ushort& l) {
  __hip_bfloat16 bh = __float2bfloat16(v);
  float fh = __bfloat162float(bh);
  __hip_bfloat16 bl = __float2bfloat16(v - fh);
  h = *(ushort*)&bh;
  l = *(ushort*)&bl;
}

// ---------------------------------------------------------------- big GEMMs (MFMA, split-bf16)
// C[M x 64tile] = A[M x 512] @ W[512 x LDW](cols n0..n0+63) ; verified frag model:
// lane l supplies A[l&15][8*(l>>4)+i]; B[8*(l>>4)+i][l&15]; C/D col=lane&15,
// row=(lane>>4)*4+reg. A staged row-major hi/lo, W staged transposed hi/lo,
// both with XOR chunk swizzle (conflict-free 8-phase writes/reads).
// MODE 0: q-proj (LDW=1536, +bias, *0.125, head-major out)
// MODE 1: out-proj (LDW=512, +bias, row-major out)
template <int MODE>
__global__ __launch_bounds__(256) void k_gemm_mfma(const float* __restrict__ A,
                                                   const float* __restrict__ W,
                                                   const float* __restrict__ bias,
                                                   float* __restrict__ out) {
  constexpr int LDW = (MODE == 0) ? 1536 : 512;
  __shared__ ushort Ah[4096], Al[4096], Bh[4096], Bl[4096];
  const int tid = threadIdx.x;
  const int lane = tid & 63, w = tid >> 6, band = w * 16;
  const int n0 = blockIdx.x * 64, m0 = blockIdx.y * 64;
  const int g = lane >> 4, li = lane & 15;

  const int arow = tid >> 2, akc = (tid & 3) * 16;   // A staging coords
  const int bn = tid & 63, bkc = (tid >> 6) * 16;    // B staging coords

  f32x4 acc[4];
#pragma unroll
  for (int nt = 0; nt < 4; ++nt) acc[nt] = (f32x4){0.f, 0.f, 0.f, 0.f};

  for (int k0 = 0; k0 < 512; k0 += 64) {
    if (k0) __syncthreads();
    // --- stage A tile (64 rows x 64 k) as hi/lo planes
    {
      float av[16];
#pragma unroll
      for (int j = 0; j < 4; ++j)
        *(float4*)&av[j * 4] =
            *(const float4*)&A[(m0 + arow) * 512 + k0 + akc + j * 4];
#pragma unroll
      for (int c2 = 0; c2 < 2; ++c2) {
        short8 hv, lv;
#pragma unroll
        for (int i = 0; i < 8; ++i) {
          ushort h, l;
          split_bf(av[c2 * 8 + i], h, l);
          hv[i] = (short)h;
          lv[i] = (short)l;
        }
        int chunk = ((akc >> 3) + c2) ^ (arow & 7);
        int idx = arow * 64 + chunk * 8;
        *(short8*)&Ah[idx] = hv;
        *(short8*)&Al[idx] = lv;
      }
    }
    // --- stage W tile transposed (WT[n][k]) as hi/lo planes
    {
      float bv[16];
#pragma unroll
      for (int i = 0; i < 16; ++i)
        bv[i] = W[(k0 + bkc + i) * LDW + n0 + bn];
#pragma unroll
      for (int c2 = 0; c2 < 2; ++c2) {
        short8 hv, lv;
#pragma unroll
        for (int i = 0; i < 8; ++i) {
          ushort h, l;
          split_bf(bv[c2 * 8 + i], h, l);
          hv[i] = (short)h;
          lv[i] = (short)l;
        }
        int chunk = ((bkc >> 3) + c2) ^ (bn & 7);
        int idx = bn * 64 + chunk * 8;
        *(short8*)&Bh[idx] = hv;
        *(short8*)&Bl[idx] = lv;
      }
    }
    __syncthreads();
    // --- fragments + MFMA
    short8 a_h[2], a_l[2];
    const int row = band + li;
#pragma unroll
    for (int kh = 0; kh < 2; ++kh) {
      int chunk = ((kh * 32 + 8 * g) >> 3) ^ (row & 7);
      int idx = row * 64 + chunk * 8;
      a_h[kh] = *(const short8*)&Ah[idx];
      a_l[kh] = *(const short8*)&Al[idx];
    }
#pragma unroll
    for (int nt = 0; nt < 4; ++nt) {
      int n = nt * 16 + li;
      f32x4 a = acc[nt];
#pragma unroll
      for (int kh = 0; kh < 2; ++kh) {
        int chunk = ((kh * 32 + 8 * g) >> 3) ^ (n & 7);
        int idx = n * 64 + chunk * 8;
        short8 bh = *(const short8*)&Bh[idx];
        short8 bl = *(const short8*)&Bl[idx];
        a = __builtin_amdgcn_mfma_f32_16x16x32_bf16(a_l[kh], bh, a, 0, 0, 0);
        a = __builtin_amdgcn_mfma_f32_16x16x32_bf16(a_h[kh], bl, a, 0, 0, 0);
        a = __builtin_amdgcn_mfma_f32_16x16x32_bf16(a_h[kh], bh, a, 0, 0, 0);
      }
      acc[nt] = a;
    }
  }
  // --- epilogue
#pragma unroll
  for (int nt = 0; nt < 4; ++nt) {
#pragma unroll
    for (int r = 0; r < 4; ++r) {
      int trow = band + 4 * g + r;           // tile row
      int c = n0 + nt * 16 + li;             // global col
      float v = acc[nt][r] + bias[c];
      if (MODE == 0) {
        int rg = m0 + trow;
        int b = rg >> 11, t = rg & 2047;
        int h = c >> 6, d = c & 63;
        out[(((b << 3) | h) * 2048 + t) * 64 + d] = v * 0.125f;
      } else {
        out[(m0 + trow) * 512 + c] = v;
      }
    }
  }
}

// ---------------------------------------------------------------- small GEMMs
__global__ __launch_bounds__(256) void k_gemm_small(
    const float* __restrict__ x, const float* __restrict__ xp,
    const float* __restrict__ w, const float* __restrict__ bq,
    float* __restrict__ k64, float* __restrict__ v64,
    float* __restrict__ ql, float* __restrict__ kl) {
  __shared__ float As[16][68];
  __shared__ float Bs[16][68];
  const int variant = blockIdx.z;
  const int tid = threadIdx.x;
  const int n0 = blockIdx.x * 64, row0 = blockIdx.y * 64;
  const int bcol0 = (variant == 0 ? 512 : 0) + n0;
  const int ty = tid >> 4, tx = tid & 15;
  const int lrow = tid >> 2, lkc = (tid & 3) * 4;
  const int brow = tid >> 4, bcol = (tid & 15) * 4;
  float acc[4][4] = {};
  for (int k0 = 0; k0 < 512; k0 += 16) {
    int gr = row0 + lrow;
    const float* arow;
    if (variant == 0) {
      int b = gr >> 6, t = gr & 63;
      arow = x + (b * TB + t) * EB;
    } else {
      arow = xp + gr * EB;
    }
    float4 av = *(const float4*)(arow + k0 + lkc);
    float4 bv = *(const float4*)(w + (k0 + brow) * 1536 + bcol0 + bcol);
    As[lkc + 0][lrow] = av.x; As[lkc + 1][lrow] = av.y;
    As[lkc + 2][lrow] = av.z; As[lkc + 3][lrow] = av.w;
    *(float4*)&Bs[brow][bcol] = bv;
    __syncthreads();
#pragma unroll
    for (int kk = 0; kk < 16; ++kk) {
      float4 a4 = *(const float4*)&As[kk][ty * 4];
      float4 b4 = *(const float4*)&Bs[kk][tx * 4];
      const float* ap = (const float*)&a4;
      const float* bp = (const float*)&b4;
#pragma unroll
      for (int mi = 0; mi < 4; ++mi)
#pragma unroll
        for (int ni = 0; ni < 4; ++ni) acc[mi][ni] += ap[mi] * bp[ni];
    }
    __syncthreads();
  }
#pragma unroll
  for (int mi = 0; mi < 4; ++mi) {
    int r = row0 + ty * 4 + mi;
    int b = r >> 6, t = r & 63;
#pragma unroll
    for (int ni = 0; ni < 4; ++ni) {
      int j = tx * 4 + ni;
      int cloc = n0 + j;
      int gc = bcol0 + j;
      float val = acc[mi][ni] + bq[gc];
      int which = cloc >> 9;
      int hd_ = cloc & 511;
      int h = hd_ >> 6, d = hd_ & 63;
      int dst = ((b * 8 + h) * 64 + t) * 64 + d;
      if (variant == 0) {
        if (which == 0) k64[dst] = val; else v64[dst] = val;
      } else {
        if (which == 0) ql[dst] = val * 0.125f; else kl[dst] = val;
      }
    }
  }
}

// ---------------------------------------------------------------- A and BV
__global__ __launch_bounds__(256) void k_a_bv(
    const float* __restrict__ ql, const float* __restrict__ kl,
    const float* __restrict__ k64, const float* __restrict__ v64,
    float* __restrict__ A, float* __restrict__ BV) {
  __shared__ float qls[64][65], kls[64][65], ks[64][65], vs[64][65];
  __shared__ float ps[4][64];
  const int bh = blockIdx.x, tid = threadIdx.x;
  const int base = bh * 4096;
  for (int i = 0; i < 16; ++i) {
    int idx = i * 256 + tid;
    int r = idx >> 6, c = idx & 63;
    qls[r][c] = ql[base + idx];
    kls[r][c] = kl[base + idx];
    ks[r][c] = k64[base + idx];
    vs[r][c] = v64[base + idx];
  }
  __syncthreads();
  const int w = tid >> 6, lane = tid & 63;
  for (int rr = 0; rr < 16; ++rr) {
    int i = rr * 4 + w;
    bool ok = lane <= i;
    float s = 0.f;
    for (int d = 0; d < 64; ++d) s += qls[i][d] * kls[lane][d];
    float mv = ok ? s : -1e30f;
#pragma unroll
    for (int off = 32; off; off >>= 1) mv = fmaxf(mv, __shfl_xor(mv, off));
    float e = ok ? __expf(s - mv) : 0.f;
    float su = e;
#pragma unroll
    for (int off = 32; off; off >>= 1) su += __shfl_xor(su, off);
    A[base + i * 64 + lane] = e / su;
    s = 0.f;
    for (int d = 0; d < 64; ++d) s += qls[i][d] * ks[lane][d];
    mv = ok ? s : -1e30f;
#pragma unroll
    for (int off = 32; off; off >>= 1) mv = fmaxf(mv, __shfl_xor(mv, off));
    e = ok ? __expf(s - mv) : 0.f;
    su = e;
#pragma unroll
    for (int off = 32; off; off >>= 1) su += __shfl_xor(su, off);
    ps[w][lane] = e / su;
    float bv = 0.f;
    for (int j = 0; j < 64; ++j) bv += ps[w][j] * vs[j][lane];
    BV[base + i * 64 + lane] = bv;
  }
}

// ---------------------------------------------------------------- global scale
__global__ __launch_bounds__(1024) void k_scal(const float* __restrict__ A,
                                               float* __restrict__ scal) {
  __shared__ float red[1024];
  const int tid = threadIdx.x;
  const int bh = tid >> 6, i = tid & 63;
  const float* Ab = A + bh * 4096;
  float cs = 0.f, rs = 0.f;
  for (int j = 0; j < 64; ++j) {
    cs += fabsf(Ab[i * 64 + j]);
    rs += fabsf(Ab[j * 64 + i]);
  }
  red[tid] = cs;
  __syncthreads();
  for (int s = 512; s; s >>= 1) {
    if (tid < s) red[tid] = fmaxf(red[tid], red[tid + s]);
    __syncthreads();
  }
  float mc = red[0];
  __syncthreads();
  red[tid] = rs;
  __syncthreads();
  for (int s = 512; s; s >>= 1) {
    if (tid < s) red[tid] = fmaxf(red[tid], red[tid + s]);
    __syncthreads();
  }
  if (tid == 0) scal[0] = 1.f / (mc * red[0]);
}

// ---------------------------------------------------------------- pinv (MFMA Newton-Schulz)
__device__ __forceinline__ void ld_afrags(const ushort* hp, const ushort* lp,
                                          int band, int lane,
                                          short8 ah[2], short8 al[2]) {
  const int g = lane >> 4, li = lane & 15;
  const int row = band + li;
#pragma unroll
  for (int kh = 0; kh < 2; ++kh) {
    int k0 = kh * 32 + 8 * g;
    int idx = row * 64 + ((((k0 >> 3) ^ (row & 7)) << 3));
    ah[kh] = *(const short8*)&hp[idx];
    al[kh] = *(const short8*)&lp[idx];
  }
}

__device__ __forceinline__ void mm_frags(const short8 ah[2], const short8 al[2],
                                         const ushort* bhp, const ushort* blp,
                                         int lane, f32x4 acc[4]) {
  const int g = lane >> 4, li = lane & 15;
#pragma unroll
  for (int nt = 0; nt < 4; ++nt) {
    f32x4 a = {0.f, 0.f, 0.f, 0.f};
#pragma unroll
    for (int kh = 0; kh < 2; ++kh) {
      int n = nt * 16 + li;
      int k0 = kh * 32 + 8 * g;
      int idx = n * 64 + ((((k0 >> 3) ^ (n & 7)) << 3));
      short8 bh = *(const short8*)&bhp[idx];
      short8 bl = *(const short8*)&blp[idx];
      a = __builtin_amdgcn_mfma_f32_16x16x32_bf16(al[kh], bh, a, 0, 0, 0);
      a = __builtin_amdgcn_mfma_f32_16x16x32_bf16(ah[kh], bl, a, 0, 0, 0);
      a = __builtin_amdgcn_mfma_f32_16x16x32_bf16(ah[kh], bh, a, 0, 0, 0);
    }
    acc[nt] = a;
  }
}

__device__ __forceinline__ void wrT(ushort* hp, ushort* lp, int band, int lane,
                                    const f32x4 acc[4], float cI, float mul) {
  const int g = lane >> 4, li = lane & 15;
  const int r0 = band + 4 * g;
#pragma unroll
  for (int nt = 0; nt < 4; ++nt) {
    int c = nt * 16 + li;
    ushort h[4], l[4];
#pragma unroll
    for (int r = 0; r < 4; ++r) {
      float v = mul * acc[nt][r] + ((r0 + r) == c ? cI : 0.f);
      split_bf(v, h[r], l[r]);
    }
    int idx = c * 64 + (((((r0) >> 3) ^ (c & 7)) << 3) | (r0 & 7));
    *(ushort4*)&hp[idx] = make_ushort4(h[0], h[1], h[2], h[3]);
    *(ushort4*)&lp[idx] = make_ushort4(l[0], l[1], l[2], l[3]);
  }
}

__device__ __forceinline__ void wrN(ushort* hp, ushort* lp, int band, int lane,
                                    const f32x4 acc[4], float mul) {
  const int g = lane >> 4, li = lane & 15;
#pragma unroll
  for (int nt = 0; nt < 4; ++nt) {
    int c = nt * 16 + li;
#pragma unroll
    for (int r = 0; r < 4; ++r) {
      int row = band + 4 * g + r;
      ushort h, l;
      split_bf(mul * acc[nt][r], h, l);
      int idx = swz_idx(row, c);
      hp[idx] = h;
      lp[idx] = l;
    }
  }
}

__global__ __launch_bounds__(256) void k_pinv(const float* __restrict__ A,
                                              const float* __restrict__ BVg,
                                              const float* __restrict__ scal,
                                              float* __restrict__ C) {
  __shared__ ushort ZT_h[4096], ZT_l[4096], ZA_h[4096], ZA_l[4096],
                    PA_h[4096], PA_l[4096], QA_h[4096], QA_l[4096],
                    QB_h[4096], QB_l[4096], BT_h[4096], BT_l[4096];
  const int bh = blockIdx.x, tid = threadIdx.x;
  const int lane = tid & 63, w = tid >> 6, band = w * 16;
  const int base = bh * 4096;
  const float sc = scal[0];
  const float* Ag = A + base;
  const float* Bg = BVg + base;

  {
    int prow = tid >> 2;
    int pc0 = (tid & 3) * 16;
#pragma unroll 4
    for (int j = 0; j < 16; ++j) {
      int col = pc0 + j;
      float av = Ag[prow * 64 + col] * sc;
      ushort h, l;
      split_bf(av, h, l);
      int i1 = swz_idx(prow, col);
      ZT_h[i1] = h; ZT_l[i1] = l;
      int i2 = swz_idx(col, prow);
      ZA_h[i2] = h; ZA_l[i2] = l;
      float bv = Bg[prow * 64 + col];
      split_bf(bv, h, l);
      BT_h[i2] = h; BT_l[i2] = l;
    }
  }
  short8 a_h[2], a_l[2];
  {
    const int g = lane >> 4, li = lane & 15;
    int row = band + li;
#pragma unroll
    for (int kh = 0; kh < 2; ++kh) {
      int k0 = kh * 32 + 8 * g;
      float tmp[8];
      *(float4*)&tmp[0] = *(const float4*)&Ag[row * 64 + k0];
      *(float4*)&tmp[4] = *(const float4*)&Ag[row * 64 + k0 + 4];
      short8 hv, lv;
#pragma unroll
      for (int i = 0; i < 8; ++i) {
        ushort h, l;
        split_bf(tmp[i], h, l);
        hv[i] = (short)h;
        lv[i] = (short)l;
      }
      a_h[kh] = hv;
      a_l[kh] = lv;
    }
  }
  __syncthreads();

  for (int it = 0; it < 6; ++it) {
    f32x4 acc[4];
    mm_frags(a_h, a_l, ZT_h, ZT_l, lane, acc);
    wrN(PA_h, PA_l, band, lane, acc, 1.f);
    wrT(QA_h, QA_l, band, lane, acc, 7.f, -1.f);
    __syncthreads();
    short8 p_h[2], p_l[2];
    ld_afrags(PA_h, PA_l, band, lane, p_h, p_l);
    mm_frags(p_h, p_l, QA_h, QA_l, lane, acc);
    wrT(QB_h, QB_l, band, lane, acc, 15.f, -1.f);
    __syncthreads();
    mm_frags(p_h, p_l, QB_h, QB_l, lane, acc);
    wrT(QA_h, QA_l, band, lane, acc, 13.f, -1.f);
    __syncthreads();
    short8 z_h[2], z_l[2];
    ld_afrags(ZA_h, ZA_l, band, lane, z_h, z_l);
    mm_frags(z_h, z_l, QA_h, QA_l, lane, acc);
    wrN(ZA_h, ZA_l, band, lane, acc, 0.25f);
    wrT(ZT_h, ZT_l, band, lane, acc, 0.f, 0.25f);
    __syncthreads();
  }
  {
    short8 z_h[2], z_l[2];
    ld_afrags(ZA_h, ZA_l, band, lane, z_h, z_l);
    f32x4 acc[4];
    mm_frags(z_h, z_l, BT_h, BT_l, lane, acc);
    const int g = lane >> 4, li = lane & 15;
#pragma unroll
    for (int nt = 0; nt < 4; ++nt) {
#pragma unroll
      for (int r = 0; r < 4; ++r) {
        int row = band + 4 * g + r;
        int col = nt * 16 + li;
        C[base + row * 64 + col] = acc[nt][r];
      }
    }
  }
}

// ---------------------------------------------------------------- F softmax + y = F@C
__global__ __launch_bounds__(512) void k_f_y(const float* __restrict__ q,
                                             const float* __restrict__ kl,
                                             const float* __restrict__ C,
                                             float* __restrict__ yh) {
  __shared__ float kls[64][65];
  __shared__ float Cs[64][65];
  __shared__ float qs[8][64];
  __shared__ float ps[8][64];
  const int bh = blockIdx.x;
  const int b = bh >> 3, h = bh & 7;
  const int tid = threadIdx.x;
  const int w = tid >> 6, lane = tid & 63;
  for (int i = 0; i < 8; ++i) {
    int idx = i * 512 + tid;
    int r = idx >> 6, c = idx & 63;
    kls[r][c] = kl[bh * 4096 + idx];
    Cs[r][c] = C[bh * 4096 + idx];
  }
  __syncthreads();
  const int t0 = blockIdx.y * 128 + w * 16;
  for (int rr = 0; rr < 16; ++rr) {
    int t = t0 + rr;
    qs[w][lane] = q[(bh * 2048 + t) * 64 + lane];
    float s = 0.f;
    for (int d = 0; d < 64; ++d) s += qs[w][d] * kls[lane][d];
    bool ok = lane <= t;
    float mv = ok ? s : -1e30f;
#pragma unroll
    for (int off = 32; off; off >>= 1) mv = fmaxf(mv, __shfl_xor(mv, off));
    float e = ok ? __expf(s - mv) : 0.f;
    float su = e;
#pragma unroll
    for (int off = 32; off; off >>= 1) su += __shfl_xor(su, off);
    ps[w][lane] = e / su;
    float acc = 0.f;
    for (int j = 0; j < 64; ++j) acc += ps[w][j] * Cs[j][lane];
    yh[(b * 2048 + t) * 512 + h * 64 + lane] = acc;
  }
}

// ---------------------------------------------------------------- launcher
extern "C" void kernel_launch(void* const* d_in, const int* in_sizes, int n_in,
                              void* d_out, int out_size, void* d_ws, size_t ws_size,
                              hipStream_t stream) {
  const float* x = (const float*)d_in[0];
  const float* w_qkv = (const float*)d_in[1];
  const float* b_qkv = (const float*)d_in[2];
  const float* w_proj = (const float*)d_in[3];
  const float* b_proj = (const float*)d_in[4];
  float* out = (float*)d_out;

  float* ws = (float*)d_ws;
  float* q = ws;              // 16*2048*64 = 2097152
  float* k64 = q + 2097152;   // 16*64*64 = 65536
  float* v64 = k64 + 65536;
  float* xp = v64 + 65536;    // 2*64*512
  float* ql = xp + 65536;
  float* kl = ql + 65536;
  float* Am = kl + 65536;
  float* BV = Am + 65536;
  float* Cm = BV + 65536;
  float* scal = Cm + 65536;   // 64 floats
  float* yh = scal + 64;      // 2*2048*512 = 2097152

  k_pool<<<dim3(256), dim3(256), 0, stream>>>(x, xp);
  k_gemm_mfma<0><<<dim3(8, 64), dim3(256), 0, stream>>>(x, w_qkv, b_qkv, q);
  k_gemm_small<<<dim3(16, 2, 2), dim3(256), 0, stream>>>(x, xp, w_qkv, b_qkv,
                                                         k64, v64, ql, kl);
  k_a_bv<<<dim3(16), dim3(256), 0, stream>>>(ql, kl, k64, v64, Am, BV);
  k_scal<<<dim3(1), dim3(1024), 0, stream>>>(Am, scal);
  k_pinv<<<dim3(16), dim3(256), 0, stream>>>(Am, BV, scal, Cm);
  k_f_y<<<dim3(16, 16), dim3(512), 0, stream>>>(q, kl, Cm, yh);
  k_gemm_mfma<1><<<dim3(8, 64), dim3(256), 0, stream>>>(yh, w_proj, b_proj, out);
}

// Round 8
// 172.651 us; speedup vs baseline: 1.7248x; 1.2687x over previous
//
#include <hip/hip_runtime.h>
#include <hip/hip_bf16.h>

// Problem constants: B=2, T=2048, E=512, H=8, hd=64, M=64, l=32, BH=16.
#define TB 2048
#define EB 512

using short8 = __attribute__((ext_vector_type(8))) short;
using f32x4  = __attribute__((ext_vector_type(4))) float;

// ---------------------------------------------------------------- pool x
__global__ __launch_bounds__(256) void k_pool(const float* __restrict__ x,
                                              float* __restrict__ xp) {
  int idx = blockIdx.x * 256 + threadIdx.x;  // [0, 2*64*512)
  int b = idx >> 15;
  int rem = idx & 32767;
  int m = rem >> 9;
  int e = rem & 511;
  const float* src = x + (b * TB + m * 32) * EB + e;
  float s = 0.f;
#pragma unroll
  for (int i = 0; i < 32; ++i) s += src[i * EB];
  xp[idx] = s * (1.f / 32.f);
}

// ---------------------------------------------------------------- shared helpers
__device__ __forceinline__ int swz_idx(int row, int col) {
  return row * 64 + ((((col >> 3) ^ (row & 7)) << 3) | (col & 7));
}

__device__ __forceinline__ void split_bf(float v, ushort& h, ushort& l) {
  __hip_bfloat16 bh = __float2bfloat16(v);
  float fh = __bfloat162float(bh);
  __hip_bfloat16 bl = __float2bfloat16(v - fh);
  h = *(ushort*)&bh;
  l = *(ushort*)&bl;
}

// acc[nt] += A(frags) @ B(T-plane, hi/lo, swizzled)
__device__ __forceinline__ void mm_frags(const short8 ah[2], const short8 al[2],
                                         const ushort* bhp, const ushort* blp,
                                         int lane, f32x4 acc[4]) {
  const int g = lane >> 4, li = lane & 15;
#pragma unroll
  for (int nt = 0; nt < 4; ++nt) {
    f32x4 a = acc[nt];
#pragma unroll
    for (int kh = 0; kh < 2; ++kh) {
      int n = nt * 16 + li;
      int k0 = kh * 32 + 8 * g;
      int idx = n * 64 + ((((k0 >> 3) ^ (n & 7)) << 3));
      short8 bh = *(const short8*)&bhp[idx];
      short8 bl = *(const short8*)&blp[idx];
      a = __builtin_amdgcn_mfma_f32_16x16x32_bf16(al[kh], bh, a, 0, 0, 0);
      a = __builtin_amdgcn_mfma_f32_16x16x32_bf16(ah[kh], bl, a, 0, 0, 0);
      a = __builtin_amdgcn_mfma_f32_16x16x32_bf16(ah[kh], bh, a, 0, 0, 0);
    }
    acc[nt] = a;
  }
}

__device__ __forceinline__ void zero_acc(f32x4 acc[4]) {
#pragma unroll
  for (int nt = 0; nt < 4; ++nt) acc[nt] = (f32x4){0.f, 0.f, 0.f, 0.f};
}

// masked row-softmax on C/D layout: row = band+4g+r, col = nt*16+li.
// causal: allow col <= (t0 + row). Masked entries end as 0.
__device__ __forceinline__ void softmax_rows(f32x4 s[4], int band, int g, int li,
                                             bool causal, int t0) {
#pragma unroll
  for (int r = 0; r < 4; ++r) {
    int trow = t0 + band + 4 * g + r;
    float m = -1e30f;
    float sv[4];
#pragma unroll
    for (int nt = 0; nt < 4; ++nt) {
      int col = nt * 16 + li;
      bool ok = !causal || (col <= trow);
      sv[nt] = ok ? s[nt][r] : -1e30f;
      m = fmaxf(m, sv[nt]);
    }
    m = fmaxf(m, __shfl_xor(m, 1));
    m = fmaxf(m, __shfl_xor(m, 2));
    m = fmaxf(m, __shfl_xor(m, 4));
    m = fmaxf(m, __shfl_xor(m, 8));
    float su = 0.f;
    float ee[4];
#pragma unroll
    for (int nt = 0; nt < 4; ++nt) {
      ee[nt] = (sv[nt] > -1e29f) ? __expf(sv[nt] - m) : 0.f;
      su += ee[nt];
    }
    su += __shfl_xor(su, 1);
    su += __shfl_xor(su, 2);
    su += __shfl_xor(su, 4);
    su += __shfl_xor(su, 8);
    float inv = 1.f / su;
#pragma unroll
    for (int nt = 0; nt < 4; ++nt) s[nt][r] = ee[nt] * inv;
  }
}

// write a 16-row hi/lo P-plane (per-wave region), rows local 0..15
__device__ __forceinline__ void wrP(ushort* hp, ushort* lp, int lane,
                                    const f32x4 acc[4]) {
  const int g = lane >> 4, li = lane & 15;
#pragma unroll
  for (int nt = 0; nt < 4; ++nt) {
    int c = nt * 16 + li;
#pragma unroll
    for (int r = 0; r < 4; ++r) {
      int row = 4 * g + r;
      ushort h, l;
      split_bf(acc[nt][r], h, l);
      int idx = swz_idx(row, c);
      hp[idx] = h;
      lp[idx] = l;
    }
  }
}

__device__ __forceinline__ void ld_pfrags(const ushort* hp, const ushort* lp,
                                          int lane, short8 ah[2], short8 al[2]) {
  const int g = lane >> 4, li = lane & 15;
#pragma unroll
  for (int kh = 0; kh < 2; ++kh) {
    int k0 = kh * 32 + 8 * g;
    int idx = li * 64 + ((((k0 >> 3) ^ (li & 7)) << 3));
    ah[kh] = *(const short8*)&hp[idx];
    al[kh] = *(const short8*)&lp[idx];
  }
}

// ---------------------------------------------------------------- MFMA GEMMs vs W
// MODE 0: q-proj  A=x rows 4096, W cols 0..511,   out q head-major *0.125
// MODE 1: out-proj A=yh rows 4096, W cols 0..511 (LDW 512), out row-major
// MODE 2: kv64    A=x rows (b,t<64) 128, W cols 512..1535, out k64/v64
// MODE 3: ql/kl   A=xp rows 128, W cols 0..1023, out ql*0.125 / kl
template <int MODE>
__global__ __launch_bounds__(256) void k_gemm_mfma(const float* __restrict__ A,
                                                   const float* __restrict__ W,
                                                   const float* __restrict__ bias,
                                                   float* __restrict__ o0,
                                                   float* __restrict__ o1) {
  constexpr int LDW = (MODE == 1) ? 512 : 1536;
  __shared__ ushort Ah[4096], Al[4096], Bh[4096], Bl[4096];
  const int tid = threadIdx.x;
  const int lane = tid & 63, w = tid >> 6, band = w * 16;
  const int n0 = blockIdx.x * 64, m0 = blockIdx.y * 64;
  const int bcol0 = (MODE == 2 ? 512 : 0) + n0;
  const int g = lane >> 4, li = lane & 15;

  const int arow = tid >> 2, akc = (tid & 3) * 16;   // A staging coords
  const int bn = tid & 63, bkc = (tid >> 6) * 16;    // B staging coords

  const float* asrc;
  {
    int gr = m0 + arow;
    if constexpr (MODE == 2) {
      asrc = A + ((gr >> 6) * TB + (gr & 63)) * EB;
    } else {
      asrc = A + gr * EB;
    }
  }

  f32x4 acc[4];
  zero_acc(acc);

  for (int k0 = 0; k0 < 512; k0 += 64) {
    if (k0) __syncthreads();
    {
      float av[16];
#pragma unroll
      for (int j = 0; j < 4; ++j)
        *(float4*)&av[j * 4] = *(const float4*)&asrc[k0 + akc + j * 4];
#pragma unroll
      for (int c2 = 0; c2 < 2; ++c2) {
        short8 hv, lv;
#pragma unroll
        for (int i = 0; i < 8; ++i) {
          ushort h, l;
          split_bf(av[c2 * 8 + i], h, l);
          hv[i] = (short)h;
          lv[i] = (short)l;
        }
        int chunk = ((akc >> 3) + c2) ^ (arow & 7);
        int idx = arow * 64 + chunk * 8;
        *(short8*)&Ah[idx] = hv;
        *(short8*)&Al[idx] = lv;
      }
    }
    {
      float bv[16];
#pragma unroll
      for (int i = 0; i < 16; ++i)
        bv[i] = W[(k0 + bkc + i) * LDW + bcol0 + bn];
#pragma unroll
      for (int c2 = 0; c2 < 2; ++c2) {
        short8 hv, lv;
#pragma unroll
        for (int i = 0; i < 8; ++i) {
          ushort h, l;
          split_bf(bv[c2 * 8 + i], h, l);
          hv[i] = (short)h;
          lv[i] = (short)l;
        }
        int chunk = ((bkc >> 3) + c2) ^ (bn & 7);
        int idx = bn * 64 + chunk * 8;
        *(short8*)&Bh[idx] = hv;
        *(short8*)&Bl[idx] = lv;
      }
    }
    __syncthreads();
    short8 a_h[2], a_l[2];
    const int row = band + li;
#pragma unroll
    for (int kh = 0; kh < 2; ++kh) {
      int chunk = ((kh * 32 + 8 * g) >> 3) ^ (row & 7);
      int idx = row * 64 + chunk * 8;
      a_h[kh] = *(const short8*)&Ah[idx];
      a_l[kh] = *(const short8*)&Al[idx];
    }
    mm_frags(a_h, a_l, Bh, Bl, lane, acc);
  }
  // --- epilogue
#pragma unroll
  for (int nt = 0; nt < 4; ++nt) {
#pragma unroll
    for (int r = 0; r < 4; ++r) {
      int trow = band + 4 * g + r;
      int gcol = bcol0 + nt * 16 + li;
      float v = acc[nt][r] + bias[gcol];
      if constexpr (MODE == 0) {
        int rg = m0 + trow;
        int b = rg >> 11, t = rg & 2047;
        int h = gcol >> 6, d = gcol & 63;
        o0[(((b << 3) | h) * 2048 + t) * 64 + d] = v * 0.125f;
      } else if constexpr (MODE == 1) {
        o0[(m0 + trow) * 512 + gcol] = v;
      } else {
        int gr = m0 + trow;
        int b = gr >> 6, t = gr & 63;
        int cloc = gcol - (MODE == 2 ? 512 : 0);
        int which = cloc >> 9;
        int hd_ = cloc & 511;
        int h = hd_ >> 6, d = hd_ & 63;
        int dst = ((b * 8 + h) * 64 + t) * 64 + d;
        if constexpr (MODE == 2) {
          if (which == 0) o0[dst] = v; else o1[dst] = v;
        } else {
          if (which == 0) o0[dst] = v * 0.125f; else o1[dst] = v;
        }
      }
    }
  }
}

// ---------------------------------------------------------------- A and BV (MFMA)
__global__ __launch_bounds__(256) void k_a_bv_mfma(
    const float* __restrict__ qlg, const float* __restrict__ klg,
    const float* __restrict__ k64, const float* __restrict__ v64,
    float* __restrict__ A, float* __restrict__ BV) {
  __shared__ ushort KLh[4096], KLl[4096], Kh[4096], Kl_[4096], VTh[4096], VTl[4096];
  __shared__ ushort Ph[4][1024], Pl[4][1024];
  const int bh = blockIdx.x, tid = threadIdx.x;
  const int lane = tid & 63, w = tid >> 6, band = w * 16;
  const int g = lane >> 4, li = lane & 15;
  const int base = bh * 4096;
  // stage B planes: KL (kl rows), K (k64 rows), VT (v64 transposed)
  {
    int n = tid & 63, kc = (tid >> 6) * 16;
    float a[16], b[16], c[16];
#pragma unroll
    for (int i = 0; i < 16; ++i) {
      a[i] = klg[base + n * 64 + kc + i];
      b[i] = k64[base + n * 64 + kc + i];
      c[i] = v64[base + (kc + i) * 64 + n];
    }
#pragma unroll
    for (int c2 = 0; c2 < 2; ++c2) {
      int idx = n * 64 + ((((kc >> 3) + c2) ^ (n & 7)) << 3);
      short8 hv, lv;
#pragma unroll
      for (int i = 0; i < 8; ++i) { ushort h, l; split_bf(a[c2*8+i], h, l); hv[i]=(short)h; lv[i]=(short)l; }
      *(short8*)&KLh[idx] = hv; *(short8*)&KLl[idx] = lv;
#pragma unroll
      for (int i = 0; i < 8; ++i) { ushort h, l; split_bf(b[c2*8+i], h, l); hv[i]=(short)h; lv[i]=(short)l; }
      *(short8*)&Kh[idx] = hv; *(short8*)&Kl_[idx] = lv;
#pragma unroll
      for (int i = 0; i < 8; ++i) { ushort h, l; split_bf(c[c2*8+i], h, l); hv[i]=(short)h; lv[i]=(short)l; }
      *(short8*)&VTh[idx] = hv; *(short8*)&VTl[idx] = lv;
    }
  }
  // ql frags from global
  short8 q_h[2], q_l[2];
  {
    int row = band + li;
#pragma unroll
    for (int kh = 0; kh < 2; ++kh) {
      int k0 = kh * 32 + 8 * g;
      float tmp[8];
      *(float4*)&tmp[0] = *(const float4*)&qlg[base + row * 64 + k0];
      *(float4*)&tmp[4] = *(const float4*)&qlg[base + row * 64 + k0 + 4];
      short8 hv, lv;
#pragma unroll
      for (int i = 0; i < 8; ++i) { ushort h, l; split_bf(tmp[i], h, l); hv[i]=(short)h; lv[i]=(short)l; }
      q_h[kh] = hv; q_l[kh] = lv;
    }
  }
  __syncthreads();
  // S1 = ql @ kl^T -> masked softmax -> A
  f32x4 s1[4];
  zero_acc(s1);
  mm_frags(q_h, q_l, KLh, KLl, lane, s1);
  softmax_rows(s1, band, g, li, true, 0);
#pragma unroll
  for (int nt = 0; nt < 4; ++nt)
#pragma unroll
    for (int r = 0; r < 4; ++r)
      A[base + (band + 4 * g + r) * 64 + nt * 16 + li] = s1[nt][r];
  // S2 = ql @ k64^T -> masked softmax -> P -> BV = P @ v64
  f32x4 s2[4];
  zero_acc(s2);
  mm_frags(q_h, q_l, Kh, Kl_, lane, s2);
  softmax_rows(s2, band, g, li, true, 0);
  wrP(Ph[w], Pl[w], lane, s2);
  short8 p_h[2], p_l[2];
  ld_pfrags(Ph[w], Pl[w], lane, p_h, p_l);
  f32x4 y[4];
  zero_acc(y);
  mm_frags(p_h, p_l, VTh, VTl, lane, y);
#pragma unroll
  for (int nt = 0; nt < 4; ++nt)
#pragma unroll
    for (int r = 0; r < 4; ++r)
      BV[base + (band + 4 * g + r) * 64 + nt * 16 + li] = y[nt][r];
}

// ---------------------------------------------------------------- global scale
__global__ __launch_bounds__(1024) void k_scal(const float* __restrict__ A,
                                               float* __restrict__ scal) {
  __shared__ float red[1024];
  const int tid = threadIdx.x;
  const int bh = tid >> 6, i = tid & 63;
  const float* Ab = A + bh * 4096;
  float cs = 0.f, rs = 0.f;
  for (int j = 0; j < 64; ++j) {
    cs += fabsf(Ab[i * 64 + j]);
    rs += fabsf(Ab[j * 64 + i]);
  }
  red[tid] = cs;
  __syncthreads();
  for (int s = 512; s; s >>= 1) {
    if (tid < s) red[tid] = fmaxf(red[tid], red[tid + s]);
    __syncthreads();
  }
  float mc = red[0];
  __syncthreads();
  red[tid] = rs;
  __syncthreads();
  for (int s = 512; s; s >>= 1) {
    if (tid < s) red[tid] = fmaxf(red[tid], red[tid + s]);
    __syncthreads();
  }
  if (tid == 0) scal[0] = 1.f / (mc * red[0]);
}

// ---------------------------------------------------------------- pinv (MFMA Newton-Schulz)
__device__ __forceinline__ void ld_afrags(const ushort* hp, const ushort* lp,
                                          int band, int lane,
                                          short8 ah[2], short8 al[2]) {
  const int g = lane >> 4, li = lane & 15;
  const int row = band + li;
#pragma unroll
  for (int kh = 0; kh < 2; ++kh) {
    int k0 = kh * 32 + 8 * g;
    int idx = row * 64 + ((((k0 >> 3) ^ (row & 7)) << 3));
    ah[kh] = *(const short8*)&hp[idx];
    al[kh] = *(const short8*)&lp[idx];
  }
}

__device__ __forceinline__ void mm_frags0(const short8 ah[2], const short8 al[2],
                                          const ushort* bhp, const ushort* blp,
                                          int lane, f32x4 acc[4]) {
  zero_acc(acc);
  mm_frags(ah, al, bhp, blp, lane, acc);
}

__device__ __forceinline__ void wrT(ushort* hp, ushort* lp, int band, int lane,
                                    const f32x4 acc[4], float cI, float mul) {
  const int g = lane >> 4, li = lane & 15;
  const int r0 = band + 4 * g;
#pragma unroll
  for (int nt = 0; nt < 4; ++nt) {
    int c = nt * 16 + li;
    ushort h[4], l[4];
#pragma unroll
    for (int r = 0; r < 4; ++r) {
      float v = mul * acc[nt][r] + ((r0 + r) == c ? cI : 0.f);
      split_bf(v, h[r], l[r]);
    }
    int idx = c * 64 + (((((r0) >> 3) ^ (c & 7)) << 3) | (r0 & 7));
    *(ushort4*)&hp[idx] = make_ushort4(h[0], h[1], h[2], h[3]);
    *(ushort4*)&lp[idx] = make_ushort4(l[0], l[1], l[2], l[3]);
  }
}

__device__ __forceinline__ void wrN(ushort* hp, ushort* lp, int band, int lane,
                                    const f32x4 acc[4], float mul) {
  const int g = lane >> 4, li = lane & 15;
#pragma unroll
  for (int nt = 0; nt < 4; ++nt) {
    int c = nt * 16 + li;
#pragma unroll
    for (int r = 0; r < 4; ++r) {
      int row = band + 4 * g + r;
      ushort h, l;
      split_bf(mul * acc[nt][r], h, l);
      int idx = swz_idx(row, c);
      hp[idx] = h;
      lp[idx] = l;
    }
  }
}

__global__ __launch_bounds__(256) void k_pinv(const float* __restrict__ A,
                                              const float* __restrict__ BVg,
                                              const float* __restrict__ scal,
                                              float* __restrict__ C) {
  __shared__ ushort ZT_h[4096], ZT_l[4096], ZA_h[4096], ZA_l[4096],
                    PA_h[4096], PA_l[4096], QA_h[4096], QA_l[4096],
                    QB_h[4096], QB_l[4096], BT_h[4096], BT_l[4096];
  const int bh = blockIdx.x, tid = threadIdx.x;
  const int lane = tid & 63, w = tid >> 6, band = w * 16;
  const int base = bh * 4096;
  const float sc = scal[0];
  const float* Ag = A + base;
  const float* Bg = BVg + base;

  {
    int prow = tid >> 2;
    int pc0 = (tid & 3) * 16;
#pragma unroll 4
    for (int j = 0; j < 16; ++j) {
      int col = pc0 + j;
      float av = Ag[prow * 64 + col] * sc;
      ushort h, l;
      split_bf(av, h, l);
      int i1 = swz_idx(prow, col);
      ZT_h[i1] = h; ZT_l[i1] = l;
      int i2 = swz_idx(col, prow);
      ZA_h[i2] = h; ZA_l[i2] = l;
      float bv = Bg[prow * 64 + col];
      split_bf(bv, h, l);
      BT_h[i2] = h; BT_l[i2] = l;
    }
  }
  short8 a_h[2], a_l[2];
  {
    const int g = lane >> 4, li = lane & 15;
    int row = band + li;
#pragma unroll
    for (int kh = 0; kh < 2; ++kh) {
      int k0 = kh * 32 + 8 * g;
      float tmp[8];
      *(float4*)&tmp[0] = *(const float4*)&Ag[row * 64 + k0];
      *(float4*)&tmp[4] = *(const float4*)&Ag[row * 64 + k0 + 4];
      short8 hv, lv;
#pragma unroll
      for (int i = 0; i < 8; ++i) {
        ushort h, l;
        split_bf(tmp[i], h, l);
        hv[i] = (short)h;
        lv[i] = (short)l;
      }
      a_h[kh] = hv;
      a_l[kh] = lv;
    }
  }
  __syncthreads();

  for (int it = 0; it < 6; ++it) {
    f32x4 acc[4];
    mm_frags0(a_h, a_l, ZT_h, ZT_l, lane, acc);
    wrN(PA_h, PA_l, band, lane, acc, 1.f);
    wrT(QA_h, QA_l, band, lane, acc, 7.f, -1.f);
    __syncthreads();
    short8 p_h[2], p_l[2];
    ld_afrags(PA_h, PA_l, band, lane, p_h, p_l);
    mm_frags0(p_h, p_l, QA_h, QA_l, lane, acc);
    wrT(QB_h, QB_l, band, lane, acc, 15.f, -1.f);
    __syncthreads();
    mm_frags0(p_h, p_l, QB_h, QB_l, lane, acc);
    wrT(QA_h, QA_l, band, lane, acc, 13.f, -1.f);
    __syncthreads();
    short8 z_h[2], z_l[2];
    ld_afrags(ZA_h, ZA_l, band, lane, z_h, z_l);
    mm_frags0(z_h, z_l, QA_h, QA_l, lane, acc);
    wrN(ZA_h, ZA_l, band, lane, acc, 0.25f);
    wrT(ZT_h, ZT_l, band, lane, acc, 0.f, 0.25f);
    __syncthreads();
  }
  {
    short8 z_h[2], z_l[2];
    ld_afrags(ZA_h, ZA_l, band, lane, z_h, z_l);
    f32x4 acc[4];
    mm_frags0(z_h, z_l, BT_h, BT_l, lane, acc);
    const int g = lane >> 4, li = lane & 15;
#pragma unroll
    for (int nt = 0; nt < 4; ++nt) {
#pragma unroll
      for (int r = 0; r < 4; ++r) {
        int row = band + 4 * g + r;
        int col = nt * 16 + li;
        C[base + row * 64 + col] = acc[nt][r];
      }
    }
  }
}

// ---------------------------------------------------------------- F softmax + y = F@C (MFMA)
__global__ __launch_bounds__(256) void k_f_y_mfma(const float* __restrict__ q,
                                                  const float* __restrict__ klg,
                                                  const float* __restrict__ C,
                                                  float* __restrict__ yh) {
  __shared__ ushort KLh[4096], KLl[4096], CTh[4096], CTl[4096];
  __shared__ ushort Ph[4][1024], Pl[4][1024];
  const int bh = blockIdx.x;
  const int b = bh >> 3, h = bh & 7;
  const int t0 = blockIdx.y * 64;
  const int tid = threadIdx.x;
  const int lane = tid & 63, w = tid >> 6, band = w * 16;
  const int g = lane >> 4, li = lane & 15;
  const int base = bh * 4096;
  // stage KL (kl rows) + CT (C transposed)
  {
    int n = tid & 63, kc = (tid >> 6) * 16;
    float a[16], c[16];
#pragma unroll
    for (int i = 0; i < 16; ++i) {
      a[i] = klg[base + n * 64 + kc + i];
      c[i] = C[base + (kc + i) * 64 + n];
    }
#pragma unroll
    for (int c2 = 0; c2 < 2; ++c2) {
      int idx = n * 64 + ((((kc >> 3) + c2) ^ (n & 7)) << 3);
      short8 hv, lv;
#pragma unroll
      for (int i = 0; i < 8; ++i) { ushort hh, ll; split_bf(a[c2*8+i], hh, ll); hv[i]=(short)hh; lv[i]=(short)ll; }
      *(short8*)&KLh[idx] = hv; *(short8*)&KLl[idx] = lv;
#pragma unroll
      for (int i = 0; i < 8; ++i) { ushort hh, ll; split_bf(c[c2*8+i], hh, ll); hv[i]=(short)hh; lv[i]=(short)ll; }
      *(short8*)&CTh[idx] = hv; *(short8*)&CTl[idx] = lv;
    }
  }
  // q frags from global
  short8 q_h[2], q_l[2];
  {
    int t = t0 + band + li;
#pragma unroll
    for (int kh = 0; kh < 2; ++kh) {
      int k0 = kh * 32 + 8 * g;
      float tmp[8];
      *(float4*)&tmp[0] = *(const float4*)&q[(bh * 2048 + t) * 64 + k0];
      *(float4*)&tmp[4] = *(const float4*)&q[(bh * 2048 + t) * 64 + k0 + 4];
      short8 hv, lv;
#pragma unroll
      for (int i = 0; i < 8; ++i) { ushort hh, ll; split_bf(tmp[i], hh, ll); hv[i]=(short)hh; lv[i]=(short)ll; }
      q_h[kh] = hv; q_l[kh] = lv;
    }
  }
  __syncthreads();
  f32x4 s[4];
  zero_acc(s);
  mm_frags(q_h, q_l, KLh, KLl, lane, s);
  softmax_rows(s, band, g, li, blockIdx.y == 0, 0);
  wrP(Ph[w], Pl[w], lane, s);
  short8 p_h[2], p_l[2];
  ld_pfrags(Ph[w], Pl[w], lane, p_h, p_l);
  f32x4 y[4];
  zero_acc(y);
  mm_frags(p_h, p_l, CTh, CTl, lane, y);
#pragma unroll
  for (int nt = 0; nt < 4; ++nt)
#pragma unroll
    for (int r = 0; r < 4; ++r) {
      int t = t0 + band + 4 * g + r;
      int d = nt * 16 + li;
      yh[(b * 2048 + t) * 512 + h * 64 + d] = y[nt][r];
    }
}

// ---------------------------------------------------------------- launcher
extern "C" void kernel_launch(void* const* d_in, const int* in_sizes, int n_in,
                              void* d_out, int out_size, void* d_ws, size_t ws_size,
                              hipStream_t stream) {
  const float* x = (const float*)d_in[0];
  const float* w_qkv = (const float*)d_in[1];
  const float* b_qkv = (const float*)d_in[2];
  const float* w_proj = (const float*)d_in[3];
  const float* b_proj = (const float*)d_in[4];
  float* out = (float*)d_out;

  float* ws = (float*)d_ws;
  float* q = ws;              // 16*2048*64 = 2097152
  float* k64 = q + 2097152;   // 16*64*64 = 65536
  float* v64 = k64 + 65536;
  float* xp = v64 + 65536;    // 2*64*512
  float* ql = xp + 65536;
  float* kl = ql + 65536;
  float* Am = kl + 65536;
  float* BV = Am + 65536;
  float* Cm = BV + 65536;
  float* scal = Cm + 65536;   // 64 floats
  float* yh = scal + 64;      // 2*2048*512 = 2097152

  k_pool<<<dim3(256), dim3(256), 0, stream>>>(x, xp);
  k_gemm_mfma<0><<<dim3(8, 64), dim3(256), 0, stream>>>(x, w_qkv, b_qkv, q, nullptr);
  k_gemm_mfma<2><<<dim3(16, 2), dim3(256), 0, stream>>>(x, w_qkv, b_qkv, k64, v64);
  k_gemm_mfma<3><<<dim3(16, 2), dim3(256), 0, stream>>>(xp, w_qkv, b_qkv, ql, kl);
  k_a_bv_mfma<<<dim3(16), dim3(256), 0, stream>>>(ql, kl, k64, v64, Am, BV);
  k_scal<<<dim3(1), dim3(1024), 0, stream>>>(Am, scal);
  k_pinv<<<dim3(16), dim3(256), 0, stream>>>(Am, BV, scal, Cm);
  k_f_y_mfma<<<dim3(16, 32), dim3(256), 0, stream>>>(q, kl, Cm, yh);
  k_gemm_mfma<1><<<dim3(8, 64), dim3(256), 0, stream>>>(yh, w_proj, b_proj, out, nullptr);
}

// Round 9
// 159.909 us; speedup vs baseline: 1.8623x; 1.0797x over previous
//
#include <hip/hip_runtime.h>
#include <hip/hip_bf16.h>

// Problem constants: B=2, T=2048, E=512, H=8, hd=64, M=64, l=32, BH=16.
#define TB 2048
#define EB 512

using short8 = __attribute__((ext_vector_type(8))) short;
using f32x4  = __attribute__((ext_vector_type(4))) float;

// ---------------------------------------------------------------- pool x
__global__ __launch_bounds__(256) void k_pool(const float* __restrict__ x,
                                              float* __restrict__ xp,
                                              unsigned int* __restrict__ scal_u) {
  if (blockIdx.x == 0 && threadIdx.x == 0) scal_u[0] = 0u;  // init atomic max
  int idx = blockIdx.x * 256 + threadIdx.x;  // [0, 2*64*512)
  int b = idx >> 15;
  int rem = idx & 32767;
  int m = rem >> 9;
  int e = rem & 511;
  const float* src = x + (b * TB + m * 32) * EB + e;
  float s = 0.f;
#pragma unroll
  for (int i = 0; i < 32; ++i) s += src[i * EB];
  xp[idx] = s * (1.f / 32.f);
}

// ---------------------------------------------------------------- shared helpers
__device__ __forceinline__ int swz_idx(int row, int col) {
  return row * 64 + ((((col >> 3) ^ (row & 7)) << 3) | (col & 7));
}

__device__ __forceinline__ void split_bf(float v, ushort& h, ushort& l) {
  __hip_bfloat16 bh = __float2bfloat16(v);
  float fh = __bfloat162float(bh);
  __hip_bfloat16 bl = __float2bfloat16(v - fh);
  h = *(ushort*)&bh;
  l = *(ushort*)&bl;
}

// acc[nt] += A(frags) @ B(T-plane, hi/lo, swizzled)
__device__ __forceinline__ void mm_frags(const short8 ah[2], const short8 al[2],
                                         const ushort* bhp, const ushort* blp,
                                         int lane, f32x4 acc[4]) {
  const int g = lane >> 4, li = lane & 15;
#pragma unroll
  for (int nt = 0; nt < 4; ++nt) {
    f32x4 a = acc[nt];
#pragma unroll
    for (int kh = 0; kh < 2; ++kh) {
      int n = nt * 16 + li;
      int k0 = kh * 32 + 8 * g;
      int idx = n * 64 + ((((k0 >> 3) ^ (n & 7)) << 3));
      short8 bh = *(const short8*)&bhp[idx];
      short8 bl = *(const short8*)&blp[idx];
      a = __builtin_amdgcn_mfma_f32_16x16x32_bf16(al[kh], bh, a, 0, 0, 0);
      a = __builtin_amdgcn_mfma_f32_16x16x32_bf16(ah[kh], bl, a, 0, 0, 0);
      a = __builtin_amdgcn_mfma_f32_16x16x32_bf16(ah[kh], bh, a, 0, 0, 0);
    }
    acc[nt] = a;
  }
}

__device__ __forceinline__ void zero_acc(f32x4 acc[4]) {
#pragma unroll
  for (int nt = 0; nt < 4; ++nt) acc[nt] = (f32x4){0.f, 0.f, 0.f, 0.f};
}

// masked row-softmax on C/D layout: row = band+4g+r, col = nt*16+li.
__device__ __forceinline__ void softmax_rows(f32x4 s[4], int band, int g, int li,
                                             bool causal, int t0) {
#pragma unroll
  for (int r = 0; r < 4; ++r) {
    int trow = t0 + band + 4 * g + r;
    float m = -1e30f;
    float sv[4];
#pragma unroll
    for (int nt = 0; nt < 4; ++nt) {
      int col = nt * 16 + li;
      bool ok = !causal || (col <= trow);
      sv[nt] = ok ? s[nt][r] : -1e30f;
      m = fmaxf(m, sv[nt]);
    }
    m = fmaxf(m, __shfl_xor(m, 1));
    m = fmaxf(m, __shfl_xor(m, 2));
    m = fmaxf(m, __shfl_xor(m, 4));
    m = fmaxf(m, __shfl_xor(m, 8));
    float su = 0.f;
    float ee[4];
#pragma unroll
    for (int nt = 0; nt < 4; ++nt) {
      ee[nt] = (sv[nt] > -1e29f) ? __expf(sv[nt] - m) : 0.f;
      su += ee[nt];
    }
    su += __shfl_xor(su, 1);
    su += __shfl_xor(su, 2);
    su += __shfl_xor(su, 4);
    su += __shfl_xor(su, 8);
    float inv = 1.f / su;
#pragma unroll
    for (int nt = 0; nt < 4; ++nt) s[nt][r] = ee[nt] * inv;
  }
}

// write a 16-row hi/lo P-plane (per-wave region), rows local 0..15
__device__ __forceinline__ void wrP(ushort* hp, ushort* lp, int lane,
                                    const f32x4 acc[4]) {
  const int g = lane >> 4, li = lane & 15;
#pragma unroll
  for (int nt = 0; nt < 4; ++nt) {
    int c = nt * 16 + li;
#pragma unroll
    for (int r = 0; r < 4; ++r) {
      int row = 4 * g + r;
      ushort h, l;
      split_bf(acc[nt][r], h, l);
      int idx = swz_idx(row, c);
      hp[idx] = h;
      lp[idx] = l;
    }
  }
}

__device__ __forceinline__ void ld_pfrags(const ushort* hp, const ushort* lp,
                                          int lane, short8 ah[2], short8 al[2]) {
  const int g = lane >> 4, li = lane & 15;
#pragma unroll
  for (int kh = 0; kh < 2; ++kh) {
    int k0 = kh * 32 + 8 * g;
    int idx = li * 64 + ((((k0 >> 3) ^ (li & 7)) << 3));
    ah[kh] = *(const short8*)&hp[idx];
    al[kh] = *(const short8*)&lp[idx];
  }
}

// ---------------------------------------------------------------- MFMA GEMMs vs W
// MODE 0: q-proj  A=x rows 4096, W cols 0..511,   out q head-major *0.125
//         1-D grid 512: by=((bid&7)<<3)|(bid>>6), bx=(bid>>3)&7 -> XCD=by>>3
//         so each XCD keeps a 1MB A-band + 1MB B in its private L2.
// MODE 1: out-proj A=yh rows 4096, W cols 0..511 (LDW 512), out row-major; same remap
// MODE 2: kv64    A=x rows (b,t<64) 128, W cols 512..1535, out k64/v64
// MODE 3: ql/kl   A=xp rows 128, W cols 0..1023, out ql*0.125 / kl
template <int MODE>
__global__ __launch_bounds__(256) void k_gemm_mfma(const float* __restrict__ A,
                                                   const float* __restrict__ W,
                                                   const float* __restrict__ bias,
                                                   float* __restrict__ o0,
                                                   float* __restrict__ o1) {
  constexpr int LDW = (MODE == 1) ? 512 : 1536;
  __shared__ ushort Ah[4096], Al[4096], Bh[4096], Bl[4096];
  const int tid = threadIdx.x;
  const int lane = tid & 63, w = tid >> 6, band = w * 16;
  int bx, by;
  if constexpr (MODE == 0 || MODE == 1) {
    int bid = blockIdx.x;
    by = ((bid & 7) << 3) | (bid >> 6);
    bx = (bid >> 3) & 7;
  } else {
    bx = blockIdx.x;
    by = blockIdx.y;
  }
  const int n0 = bx * 64, m0 = by * 64;
  const int bcol0 = (MODE == 2 ? 512 : 0) + n0;
  const int g = lane >> 4, li = lane & 15;

  const int arow = tid >> 2, akc = (tid & 3) * 16;   // A staging coords
  const int bn = tid & 63, bkc = (tid >> 6) * 16;    // B staging coords

  const float* asrc;
  {
    int gr = m0 + arow;
    if constexpr (MODE == 2) {
      asrc = A + ((gr >> 6) * TB + (gr & 63)) * EB;
    } else {
      asrc = A + gr * EB;
    }
  }

  f32x4 acc[4];
  zero_acc(acc);

  for (int k0 = 0; k0 < 512; k0 += 64) {
    if (k0) __syncthreads();
    {
      float av[16];
#pragma unroll
      for (int j = 0; j < 4; ++j)
        *(float4*)&av[j * 4] = *(const float4*)&asrc[k0 + akc + j * 4];
#pragma unroll
      for (int c2 = 0; c2 < 2; ++c2) {
        short8 hv, lv;
#pragma unroll
        for (int i = 0; i < 8; ++i) {
          ushort h, l;
          split_bf(av[c2 * 8 + i], h, l);
          hv[i] = (short)h;
          lv[i] = (short)l;
        }
        int chunk = ((akc >> 3) + c2) ^ (arow & 7);
        int idx = arow * 64 + chunk * 8;
        *(short8*)&Ah[idx] = hv;
        *(short8*)&Al[idx] = lv;
      }
    }
    {
      float bv[16];
#pragma unroll
      for (int i = 0; i < 16; ++i)
        bv[i] = W[(k0 + bkc + i) * LDW + bcol0 + bn];
#pragma unroll
      for (int c2 = 0; c2 < 2; ++c2) {
        short8 hv, lv;
#pragma unroll
        for (int i = 0; i < 8; ++i) {
          ushort h, l;
          split_bf(bv[c2 * 8 + i], h, l);
          hv[i] = (short)h;
          lv[i] = (short)l;
        }
        int chunk = ((bkc >> 3) + c2) ^ (bn & 7);
        int idx = bn * 64 + chunk * 8;
        *(short8*)&Bh[idx] = hv;
        *(short8*)&Bl[idx] = lv;
      }
    }
    __syncthreads();
    short8 a_h[2], a_l[2];
    const int row = band + li;
#pragma unroll
    for (int kh = 0; kh < 2; ++kh) {
      int chunk = ((kh * 32 + 8 * g) >> 3) ^ (row & 7);
      int idx = row * 64 + chunk * 8;
      a_h[kh] = *(const short8*)&Ah[idx];
      a_l[kh] = *(const short8*)&Al[idx];
    }
    mm_frags(a_h, a_l, Bh, Bl, lane, acc);
  }
  // --- epilogue
#pragma unroll
  for (int nt = 0; nt < 4; ++nt) {
#pragma unroll
    for (int r = 0; r < 4; ++r) {
      int trow = band + 4 * g + r;
      int gcol = bcol0 + nt * 16 + li;
      float v = acc[nt][r] + bias[gcol];
      if constexpr (MODE == 0) {
        int rg = m0 + trow;
        int b = rg >> 11, t = rg & 2047;
        int h = gcol >> 6, d = gcol & 63;
        o0[(((b << 3) | h) * 2048 + t) * 64 + d] = v * 0.125f;
      } else if constexpr (MODE == 1) {
        o0[(m0 + trow) * 512 + gcol] = v;
      } else {
        int gr = m0 + trow;
        int b = gr >> 6, t = gr & 63;
        int cloc = gcol - (MODE == 2 ? 512 : 0);
        int which = cloc >> 9;
        int hd_ = cloc & 511;
        int h = hd_ >> 6, d = hd_ & 63;
        int dst = ((b * 8 + h) * 64 + t) * 64 + d;
        if constexpr (MODE == 2) {
          if (which == 0) o0[dst] = v; else o1[dst] = v;
        } else {
          if (which == 0) o0[dst] = v * 0.125f; else o1[dst] = v;
        }
      }
    }
  }
}

// ---------------------------------------------------------------- A and BV (MFMA) + pinv scale
// scal: ref z0 = A^T/(max(rowsum)*max(colsum)); rowsum==1 exactly (masked softmax
// incl. diagonal), so scal = 1/max(colsum) -> per-block colsum + global atomicMax.
__global__ __launch_bounds__(256) void k_a_bv_mfma(
    const float* __restrict__ qlg, const float* __restrict__ klg,
    const float* __restrict__ k64, const float* __restrict__ v64,
    float* __restrict__ A, float* __restrict__ BV,
    unsigned int* __restrict__ scal_u) {
  __shared__ ushort KLh[4096], KLl[4096], Kh[4096], Kl_[4096], VTh[4096], VTl[4096];
  __shared__ ushort Ph[4][1024], Pl[4][1024];
  __shared__ float red[4][64];
  const int bh = blockIdx.x, tid = threadIdx.x;
  const int lane = tid & 63, w = tid >> 6, band = w * 16;
  const int g = lane >> 4, li = lane & 15;
  const int base = bh * 4096;
  // stage B planes: KL (kl rows), K (k64 rows), VT (v64 transposed)
  {
    int n = tid & 63, kc = (tid >> 6) * 16;
    float a[16], b[16], c[16];
#pragma unroll
    for (int i = 0; i < 16; ++i) {
      a[i] = klg[base + n * 64 + kc + i];
      b[i] = k64[base + n * 64 + kc + i];
      c[i] = v64[base + (kc + i) * 64 + n];
    }
#pragma unroll
    for (int c2 = 0; c2 < 2; ++c2) {
      int idx = n * 64 + ((((kc >> 3) + c2) ^ (n & 7)) << 3);
      short8 hv, lv;
#pragma unroll
      for (int i = 0; i < 8; ++i) { ushort h, l; split_bf(a[c2*8+i], h, l); hv[i]=(short)h; lv[i]=(short)l; }
      *(short8*)&KLh[idx] = hv; *(short8*)&KLl[idx] = lv;
#pragma unroll
      for (int i = 0; i < 8; ++i) { ushort h, l; split_bf(b[c2*8+i], h, l); hv[i]=(short)h; lv[i]=(short)l; }
      *(short8*)&Kh[idx] = hv; *(short8*)&Kl_[idx] = lv;
#pragma unroll
      for (int i = 0; i < 8; ++i) { ushort h, l; split_bf(c[c2*8+i], h, l); hv[i]=(short)h; lv[i]=(short)l; }
      *(short8*)&VTh[idx] = hv; *(short8*)&VTl[idx] = lv;
    }
  }
  // ql frags from global
  short8 q_h[2], q_l[2];
  {
    int row = band + li;
#pragma unroll
    for (int kh = 0; kh < 2; ++kh) {
      int k0 = kh * 32 + 8 * g;
      float tmp[8];
      *(float4*)&tmp[0] = *(const float4*)&qlg[base + row * 64 + k0];
      *(float4*)&tmp[4] = *(const float4*)&qlg[base + row * 64 + k0 + 4];
      short8 hv, lv;
#pragma unroll
      for (int i = 0; i < 8; ++i) { ushort h, l; split_bf(tmp[i], h, l); hv[i]=(short)h; lv[i]=(short)l; }
      q_h[kh] = hv; q_l[kh] = lv;
    }
  }
  __syncthreads();
  // S1 = ql @ kl^T -> masked softmax -> A
  f32x4 s1[4];
  zero_acc(s1);
  mm_frags(q_h, q_l, KLh, KLl, lane, s1);
  softmax_rows(s1, band, g, li, true, 0);
#pragma unroll
  for (int nt = 0; nt < 4; ++nt)
#pragma unroll
    for (int r = 0; r < 4; ++r)
      A[base + (band + 4 * g + r) * 64 + nt * 16 + li] = s1[nt][r];
  // column sums of A -> global max (pinv scale)
  {
    float part[4];
#pragma unroll
    for (int nt = 0; nt < 4; ++nt) {
      part[nt] = s1[nt][0] + s1[nt][1] + s1[nt][2] + s1[nt][3];
      part[nt] += __shfl_xor(part[nt], 16);
      part[nt] += __shfl_xor(part[nt], 32);
    }
    if (g == 0) {
#pragma unroll
      for (int nt = 0; nt < 4; ++nt) red[w][nt * 16 + li] = part[nt];
    }
    __syncthreads();
    if (tid < 64) {
      float t = red[0][tid] + red[1][tid] + red[2][tid] + red[3][tid];
#pragma unroll
      for (int off = 32; off; off >>= 1) t = fmaxf(t, __shfl_xor(t, off));
      if (tid == 0) atomicMax(scal_u, __float_as_uint(t));
    }
  }
  // S2 = ql @ k64^T -> masked softmax -> P -> BV = P @ v64
  f32x4 s2[4];
  zero_acc(s2);
  mm_frags(q_h, q_l, Kh, Kl_, lane, s2);
  softmax_rows(s2, band, g, li, true, 0);
  wrP(Ph[w], Pl[w], lane, s2);
  short8 p_h[2], p_l[2];
  ld_pfrags(Ph[w], Pl[w], lane, p_h, p_l);
  f32x4 y[4];
  zero_acc(y);
  mm_frags(p_h, p_l, VTh, VTl, lane, y);
#pragma unroll
  for (int nt = 0; nt < 4; ++nt)
#pragma unroll
    for (int r = 0; r < 4; ++r)
      BV[base + (band + 4 * g + r) * 64 + nt * 16 + li] = y[nt][r];
}

// ---------------------------------------------------------------- pinv (MFMA Newton-Schulz)
__device__ __forceinline__ void ld_afrags(const ushort* hp, const ushort* lp,
                                          int band, int lane,
                                          short8 ah[2], short8 al[2]) {
  const int g = lane >> 4, li = lane & 15;
  const int row = band + li;
#pragma unroll
  for (int kh = 0; kh < 2; ++kh) {
    int k0 = kh * 32 + 8 * g;
    int idx = row * 64 + ((((k0 >> 3) ^ (row & 7)) << 3));
    ah[kh] = *(const short8*)&hp[idx];
    al[kh] = *(const short8*)&lp[idx];
  }
}

__device__ __forceinline__ void mm_frags0(const short8 ah[2], const short8 al[2],
                                          const ushort* bhp, const ushort* blp,
                                          int lane, f32x4 acc[4]) {
  zero_acc(acc);
  mm_frags(ah, al, bhp, blp, lane, acc);
}

__device__ __forceinline__ void wrT(ushort* hp, ushort* lp, int band, int lane,
                                    const f32x4 acc[4], float cI, float mul) {
  const int g = lane >> 4, li = lane & 15;
  const int r0 = band + 4 * g;
#pragma unroll
  for (int nt = 0; nt < 4; ++nt) {
    int c = nt * 16 + li;
    ushort h[4], l[4];
#pragma unroll
    for (int r = 0; r < 4; ++r) {
      float v = mul * acc[nt][r] + ((r0 + r) == c ? cI : 0.f);
      split_bf(v, h[r], l[r]);
    }
    int idx = c * 64 + (((((r0) >> 3) ^ (c & 7)) << 3) | (r0 & 7));
    *(ushort4*)&hp[idx] = make_ushort4(h[0], h[1], h[2], h[3]);
    *(ushort4*)&lp[idx] = make_ushort4(l[0], l[1], l[2], l[3]);
  }
}

__device__ __forceinline__ void wrN(ushort* hp, ushort* lp, int band, int lane,
                                    const f32x4 acc[4], float mul) {
  const int g = lane >> 4, li = lane & 15;
#pragma unroll
  for (int nt = 0; nt < 4; ++nt) {
    int c = nt * 16 + li;
#pragma unroll
    for (int r = 0; r < 4; ++r) {
      int row = band + 4 * g + r;
      ushort h, l;
      split_bf(mul * acc[nt][r], h, l);
      int idx = swz_idx(row, c);
      hp[idx] = h;
      lp[idx] = l;
    }
  }
}

__global__ __launch_bounds__(256) void k_pinv(const float* __restrict__ A,
                                              const float* __restrict__ BVg,
                                              const unsigned int* __restrict__ scal_u,
                                              float* __restrict__ C) {
  __shared__ ushort ZT_h[4096], ZT_l[4096], ZA_h[4096], ZA_l[4096],
                    PA_h[4096], PA_l[4096], QA_h[4096], QA_l[4096],
                    QB_h[4096], QB_l[4096], BT_h[4096], BT_l[4096];
  const int bh = blockIdx.x, tid = threadIdx.x;
  const int lane = tid & 63, w = tid >> 6, band = w * 16;
  const int base = bh * 4096;
  const float sc = 1.f / __uint_as_float(scal_u[0]);
  const float* Ag = A + base;
  const float* Bg = BVg + base;

  {
    int prow = tid >> 2;
    int pc0 = (tid & 3) * 16;
#pragma unroll 4
    for (int j = 0; j < 16; ++j) {
      int col = pc0 + j;
      float av = Ag[prow * 64 + col] * sc;
      ushort h, l;
      split_bf(av, h, l);
      int i1 = swz_idx(prow, col);
      ZT_h[i1] = h; ZT_l[i1] = l;
      int i2 = swz_idx(col, prow);
      ZA_h[i2] = h; ZA_l[i2] = l;
      float bv = Bg[prow * 64 + col];
      split_bf(bv, h, l);
      BT_h[i2] = h; BT_l[i2] = l;
    }
  }
  short8 a_h[2], a_l[2];
  {
    const int g = lane >> 4, li = lane & 15;
    int row = band + li;
#pragma unroll
    for (int kh = 0; kh < 2; ++kh) {
      int k0 = kh * 32 + 8 * g;
      float tmp[8];
      *(float4*)&tmp[0] = *(const float4*)&Ag[row * 64 + k0];
      *(float4*)&tmp[4] = *(const float4*)&Ag[row * 64 + k0 + 4];
      short8 hv, lv;
#pragma unroll
      for (int i = 0; i < 8; ++i) {
        ushort h, l;
        split_bf(tmp[i], h, l);
        hv[i] = (short)h;
        lv[i] = (short)l;
      }
      a_h[kh] = hv;
      a_l[kh] = lv;
    }
  }
  __syncthreads();

  for (int it = 0; it < 6; ++it) {
    f32x4 acc[4];
    mm_frags0(a_h, a_l, ZT_h, ZT_l, lane, acc);
    wrN(PA_h, PA_l, band, lane, acc, 1.f);
    wrT(QA_h, QA_l, band, lane, acc, 7.f, -1.f);
    __syncthreads();
    short8 p_h[2], p_l[2];
    ld_afrags(PA_h, PA_l, band, lane, p_h, p_l);
    mm_frags0(p_h, p_l, QA_h, QA_l, lane, acc);
    wrT(QB_h, QB_l, band, lane, acc, 15.f, -1.f);
    __syncthreads();
    mm_frags0(p_h, p_l, QB_h, QB_l, lane, acc);
    wrT(QA_h, QA_l, band, lane, acc, 13.f, -1.f);
    __syncthreads();
    short8 z_h[2], z_l[2];
    ld_afrags(ZA_h, ZA_l, band, lane, z_h, z_l);
    mm_frags0(z_h, z_l, QA_h, QA_l, lane, acc);
    wrN(ZA_h, ZA_l, band, lane, acc, 0.25f);
    wrT(ZT_h, ZT_l, band, lane, acc, 0.f, 0.25f);
    __syncthreads();
  }
  {
    short8 z_h[2], z_l[2];
    ld_afrags(ZA_h, ZA_l, band, lane, z_h, z_l);
    f32x4 acc[4];
    mm_frags0(z_h, z_l, BT_h, BT_l, lane, acc);
    const int g = lane >> 4, li = lane & 15;
#pragma unroll
    for (int nt = 0; nt < 4; ++nt) {
#pragma unroll
      for (int r = 0; r < 4; ++r) {
        int row = band + 4 * g + r;
        int col = nt * 16 + li;
        C[base + row * 64 + col] = acc[nt][r];
      }
    }
  }
}

// ---------------------------------------------------------------- F softmax + y = F@C (MFMA)
__global__ __launch_bounds__(256) void k_f_y_mfma(const float* __restrict__ q,
                                                  const float* __restrict__ klg,
                                                  const float* __restrict__ C,
                                                  float* __restrict__ yh) {
  __shared__ ushort KLh[4096], KLl[4096], CTh[4096], CTl[4096];
  __shared__ ushort Ph[4][1024], Pl[4][1024];
  const int bh = blockIdx.x;
  const int b = bh >> 3, h = bh & 7;
  const int t0 = blockIdx.y * 64;
  const int tid = threadIdx.x;
  const int lane = tid & 63, w = tid >> 6, band = w * 16;
  const int g = lane >> 4, li = lane & 15;
  const int base = bh * 4096;
  // stage KL (kl rows) + CT (C transposed)
  {
    int n = tid & 63, kc = (tid >> 6) * 16;
    float a[16], c[16];
#pragma unroll
    for (int i = 0; i < 16; ++i) {
      a[i] = klg[base + n * 64 + kc + i];
      c[i] = C[base + (kc + i) * 64 + n];
    }
#pragma unroll
    for (int c2 = 0; c2 < 2; ++c2) {
      int idx = n * 64 + ((((kc >> 3) + c2) ^ (n & 7)) << 3);
      short8 hv, lv;
#pragma unroll
      for (int i = 0; i < 8; ++i) { ushort hh, ll; split_bf(a[c2*8+i], hh, ll); hv[i]=(short)hh; lv[i]=(short)ll; }
      *(short8*)&KLh[idx] = hv; *(short8*)&KLl[idx] = lv;
#pragma unroll
      for (int i = 0; i < 8; ++i) { ushort hh, ll; split_bf(c[c2*8+i], hh, ll); hv[i]=(short)hh; lv[i]=(short)ll; }
      *(short8*)&CTh[idx] = hv; *(short8*)&CTl[idx] = lv;
    }
  }
  // q frags from global
  short8 q_h[2], q_l[2];
  {
    int t = t0 + band + li;
#pragma unroll
    for (int kh = 0; kh < 2; ++kh) {
      int k0 = kh * 32 + 8 * g;
      float tmp[8];
      *(float4*)&tmp[0] = *(const float4*)&q[(bh * 2048 + t) * 64 + k0];
      *(float4*)&tmp[4] = *(const float4*)&q[(bh * 2048 + t) * 64 + k0 + 4];
      short8 hv, lv;
#pragma unroll
      for (int i = 0; i < 8; ++i) { ushort hh, ll; split_bf(tmp[i], hh, ll); hv[i]=(short)hh; lv[i]=(short)ll; }
      q_h[kh] = hv; q_l[kh] = lv;
    }
  }
  __syncthreads();
  f32x4 s[4];
  zero_acc(s);
  mm_frags(q_h, q_l, KLh, KLl, lane, s);
  softmax_rows(s, band, g, li, blockIdx.y == 0, 0);
  wrP(Ph[w], Pl[w], lane, s);
  short8 p_h[2], p_l[2];
  ld_pfrags(Ph[w], Pl[w], lane, p_h, p_l);
  f32x4 y[4];
  zero_acc(y);
  mm_frags(p_h, p_l, CTh, CTl, lane, y);
#pragma unroll
  for (int nt = 0; nt < 4; ++nt)
#pragma unroll
    for (int r = 0; r < 4; ++r) {
      int t = t0 + band + 4 * g + r;
      int d = nt * 16 + li;
      yh[(b * 2048 + t) * 512 + h * 64 + d] = y[nt][r];
    }
}

// ---------------------------------------------------------------- launcher
extern "C" void kernel_launch(void* const* d_in, const int* in_sizes, int n_in,
                              void* d_out, int out_size, void* d_ws, size_t ws_size,
                              hipStream_t stream) {
  const float* x = (const float*)d_in[0];
  const float* w_qkv = (const float*)d_in[1];
  const float* b_qkv = (const float*)d_in[2];
  const float* w_proj = (const float*)d_in[3];
  const float* b_proj = (const float*)d_in[4];
  float* out = (float*)d_out;

  float* ws = (float*)d_ws;
  float* q = ws;              // 16*2048*64 = 2097152
  float* k64 = q + 2097152;   // 16*64*64 = 65536
  float* v64 = k64 + 65536;
  float* xp = v64 + 65536;    // 2*64*512
  float* ql = xp + 65536;
  float* kl = ql + 65536;
  float* Am = kl + 65536;
  float* BV = Am + 65536;
  float* Cm = BV + 65536;
  unsigned int* scal_u = (unsigned int*)(Cm + 65536);  // 1 uint (64 slots reserved)
  float* yh = (float*)(scal_u + 64);  // 2*2048*512 = 2097152

  k_pool<<<dim3(256), dim3(256), 0, stream>>>(x, xp, scal_u);
  k_gemm_mfma<0><<<dim3(512), dim3(256), 0, stream>>>(x, w_qkv, b_qkv, q, nullptr);
  k_gemm_mfma<2><<<dim3(16, 2), dim3(256), 0, stream>>>(x, w_qkv, b_qkv, k64, v64);
  k_gemm_mfma<3><<<dim3(16, 2), dim3(256), 0, stream>>>(xp, w_qkv, b_qkv, ql, kl);
  k_a_bv_mfma<<<dim3(16), dim3(256), 0, stream>>>(ql, kl, k64, v64, Am, BV, scal_u);
  k_pinv<<<dim3(16), dim3(256), 0, stream>>>(Am, BV, scal_u, Cm);
  k_f_y_mfma<<<dim3(16, 32), dim3(256), 0, stream>>>(q, kl, Cm, yh);
  k_gemm_mfma<1><<<dim3(512), dim3(256), 0, stream>>>(yh, w_proj, b_proj, out, nullptr);
}

// Round 10
// 143.751 us; speedup vs baseline: 2.0716x; 1.1124x over previous
//
#include <hip/hip_runtime.h>
#include <hip/hip_bf16.h>

// Problem constants: B=2, T=2048, E=512, H=8, hd=64, M=64, l=32, BH=16.
#define TB 2048
#define EB 512

using short8 = __attribute__((ext_vector_type(8))) short;
using f32x4  = __attribute__((ext_vector_type(4))) float;

// ---------------------------------------------------------------- pool x
__global__ __launch_bounds__(256) void k_pool(const float* __restrict__ x,
                                              float* __restrict__ xp,
                                              unsigned int* __restrict__ scal_u) {
  if (blockIdx.x == 0 && threadIdx.x == 0) scal_u[0] = 0u;  // init atomic max
  int idx = blockIdx.x * 256 + threadIdx.x;  // [0, 2*64*512)
  int b = idx >> 15;
  int rem = idx & 32767;
  int m = rem >> 9;
  int e = rem & 511;
  const float* src = x + (b * TB + m * 32) * EB + e;
  float s = 0.f;
#pragma unroll
  for (int i = 0; i < 32; ++i) s += src[i * EB];
  xp[idx] = s * (1.f / 32.f);
}

// ---------------------------------------------------------------- shared helpers
__device__ __forceinline__ int swz_idx(int row, int col) {
  return row * 64 + ((((col >> 3) ^ (row & 7)) << 3) | (col & 7));
}

__device__ __forceinline__ void split_bf(float v, ushort& h, ushort& l) {
  __hip_bfloat16 bh = __float2bfloat16(v);
  float fh = __bfloat162float(bh);
  __hip_bfloat16 bl = __float2bfloat16(v - fh);
  h = *(ushort*)&bh;
  l = *(ushort*)&bl;
}

// acc[nt] += A(frags) @ B(T-plane, hi/lo, swizzled)
__device__ __forceinline__ void mm_frags(const short8 ah[2], const short8 al[2],
                                         const ushort* bhp, const ushort* blp,
                                         int lane, f32x4 acc[4]) {
  const int g = lane >> 4, li = lane & 15;
#pragma unroll
  for (int nt = 0; nt < 4; ++nt) {
    f32x4 a = acc[nt];
#pragma unroll
    for (int kh = 0; kh < 2; ++kh) {
      int n = nt * 16 + li;
      int k0 = kh * 32 + 8 * g;
      int idx = n * 64 + ((((k0 >> 3) ^ (n & 7)) << 3));
      short8 bh = *(const short8*)&bhp[idx];
      short8 bl = *(const short8*)&blp[idx];
      a = __builtin_amdgcn_mfma_f32_16x16x32_bf16(al[kh], bh, a, 0, 0, 0);
      a = __builtin_amdgcn_mfma_f32_16x16x32_bf16(ah[kh], bl, a, 0, 0, 0);
      a = __builtin_amdgcn_mfma_f32_16x16x32_bf16(ah[kh], bh, a, 0, 0, 0);
    }
    acc[nt] = a;
  }
}

__device__ __forceinline__ void zero_acc(f32x4 acc[4]) {
#pragma unroll
  for (int nt = 0; nt < 4; ++nt) acc[nt] = (f32x4){0.f, 0.f, 0.f, 0.f};
}

// masked row-softmax on C/D layout: row = band+4g+r, col = nt*16+li.
__device__ __forceinline__ void softmax_rows(f32x4 s[4], int band, int g, int li,
                                             bool causal, int t0) {
#pragma unroll
  for (int r = 0; r < 4; ++r) {
    int trow = t0 + band + 4 * g + r;
    float m = -1e30f;
    float sv[4];
#pragma unroll
    for (int nt = 0; nt < 4; ++nt) {
      int col = nt * 16 + li;
      bool ok = !causal || (col <= trow);
      sv[nt] = ok ? s[nt][r] : -1e30f;
      m = fmaxf(m, sv[nt]);
    }
    m = fmaxf(m, __shfl_xor(m, 1));
    m = fmaxf(m, __shfl_xor(m, 2));
    m = fmaxf(m, __shfl_xor(m, 4));
    m = fmaxf(m, __shfl_xor(m, 8));
    float su = 0.f;
    float ee[4];
#pragma unroll
    for (int nt = 0; nt < 4; ++nt) {
      ee[nt] = (sv[nt] > -1e29f) ? __expf(sv[nt] - m) : 0.f;
      su += ee[nt];
    }
    su += __shfl_xor(su, 1);
    su += __shfl_xor(su, 2);
    su += __shfl_xor(su, 4);
    su += __shfl_xor(su, 8);
    float inv = 1.f / su;
#pragma unroll
    for (int nt = 0; nt < 4; ++nt) s[nt][r] = ee[nt] * inv;
  }
}

// write a 16-row hi/lo P-plane (per-wave region), rows local 0..15
__device__ __forceinline__ void wrP(ushort* hp, ushort* lp, int lane,
                                    const f32x4 acc[4]) {
  const int g = lane >> 4, li = lane & 15;
#pragma unroll
  for (int nt = 0; nt < 4; ++nt) {
    int c = nt * 16 + li;
#pragma unroll
    for (int r = 0; r < 4; ++r) {
      int row = 4 * g + r;
      ushort h, l;
      split_bf(acc[nt][r], h, l);
      int idx = swz_idx(row, c);
      hp[idx] = h;
      lp[idx] = l;
    }
  }
}

__device__ __forceinline__ void ld_pfrags(const ushort* hp, const ushort* lp,
                                          int lane, short8 ah[2], short8 al[2]) {
  const int g = lane >> 4, li = lane & 15;
#pragma unroll
  for (int kh = 0; kh < 2; ++kh) {
    int k0 = kh * 32 + 8 * g;
    int idx = li * 64 + ((((k0 >> 3) ^ (li & 7)) << 3));
    ah[kh] = *(const short8*)&hp[idx];
    al[kh] = *(const short8*)&lp[idx];
  }
}

// ---------------------------------------------------------------- MFMA GEMMs vs W
// MODE 0: q-proj  A=x rows 4096, W cols 0..511, out q head-major *0.125 (XCD remap)
// MODE 1: out-proj A=yh rows 4096, W cols 0..511 (LDW 512), out row-major (XCD remap)
// MODE 2: merged small GEMMs, grid (16,4): variant=by>>1
//         v0: A=x rows (b,t<64), W cols 512..1535 -> k64/v64 (o0/o1)
//         v1: A=xp rows 128,     W cols 0..1023   -> ql*0.125/kl (o2/o3)
// All modes: register-prefetch double-buffered staging (global->reg issued for
// tile k+1 before MFMA of tile k; vmcnt drains at next stage-write).
template <int MODE>
__global__ __launch_bounds__(256) void k_gemm_mfma(const float* __restrict__ A,
                                                   const float* __restrict__ A2,
                                                   const float* __restrict__ W,
                                                   const float* __restrict__ bias,
                                                   float* __restrict__ o0,
                                                   float* __restrict__ o1,
                                                   float* __restrict__ o2,
                                                   float* __restrict__ o3) {
  constexpr int LDW = (MODE == 1) ? 512 : 1536;
  __shared__ ushort Ah[4096], Al[4096], Bh[4096], Bl[4096];
  const int tid = threadIdx.x;
  const int lane = tid & 63, w = tid >> 6, band = w * 16;
  int bx, by;
  if constexpr (MODE == 0 || MODE == 1) {
    int bid = blockIdx.x;
    by = ((bid & 7) << 3) | (bid >> 6);
    bx = (bid >> 3) & 7;
  } else {
    bx = blockIdx.x;
    by = blockIdx.y;
  }
  const int variant = (MODE == 2) ? (by >> 1) : 0;
  const int m0 = (MODE == 2) ? ((by & 1) * 64) : by * 64;
  const int bcol0 = (MODE == 2) ? (variant == 0 ? 512 + bx * 64 : bx * 64)
                                : bx * 64;
  const int g = lane >> 4, li = lane & 15;

  const int arow = tid >> 2, akc = (tid & 3) * 16;   // A staging coords
  const int bn = tid & 63, bkc = (tid >> 6) * 16;    // B staging coords

  const float* asrc;
  {
    int gr = m0 + arow;
    if constexpr (MODE == 2) {
      asrc = (variant == 0) ? (A + ((gr >> 6) * TB + (gr & 63)) * EB)
                            : (A2 + gr * EB);
    } else {
      asrc = A + gr * EB;
    }
  }

  f32x4 acc[4];
  zero_acc(acc);

  float av[16], bv[16];
#pragma unroll
  for (int j = 0; j < 4; ++j)
    *(float4*)&av[j * 4] = *(const float4*)&asrc[akc + j * 4];
#pragma unroll
  for (int i = 0; i < 16; ++i) bv[i] = W[(bkc + i) * LDW + bcol0 + bn];

#pragma unroll
  for (int k0 = 0; k0 < 512; k0 += 64) {
    if (k0) __syncthreads();
    // --- convert current regs -> LDS hi/lo planes
#pragma unroll
    for (int c2 = 0; c2 < 2; ++c2) {
      short8 hv, lv;
#pragma unroll
      for (int i = 0; i < 8; ++i) {
        ushort h, l;
        split_bf(av[c2 * 8 + i], h, l);
        hv[i] = (short)h;
        lv[i] = (short)l;
      }
      int chunk = ((akc >> 3) + c2) ^ (arow & 7);
      int idx = arow * 64 + chunk * 8;
      *(short8*)&Ah[idx] = hv;
      *(short8*)&Al[idx] = lv;
    }
#pragma unroll
    for (int c2 = 0; c2 < 2; ++c2) {
      short8 hv, lv;
#pragma unroll
      for (int i = 0; i < 8; ++i) {
        ushort h, l;
        split_bf(bv[c2 * 8 + i], h, l);
        hv[i] = (short)h;
        lv[i] = (short)l;
      }
      int chunk = ((bkc >> 3) + c2) ^ (bn & 7);
      int idx = bn * 64 + chunk * 8;
      *(short8*)&Bh[idx] = hv;
      *(short8*)&Bl[idx] = lv;
    }
    __syncthreads();
    // --- prefetch next tile into regs (hides under frag-reads + MFMA)
    if (k0 + 64 < 512) {
#pragma unroll
      for (int j = 0; j < 4; ++j)
        *(float4*)&av[j * 4] = *(const float4*)&asrc[k0 + 64 + akc + j * 4];
#pragma unroll
      for (int i = 0; i < 16; ++i)
        bv[i] = W[(k0 + 64 + bkc + i) * LDW + bcol0 + bn];
    }
    // --- fragments + MFMA
    short8 a_h[2], a_l[2];
    const int row = band + li;
#pragma unroll
    for (int kh = 0; kh < 2; ++kh) {
      int chunk = ((kh * 32 + 8 * g) >> 3) ^ (row & 7);
      int idx = row * 64 + chunk * 8;
      a_h[kh] = *(const short8*)&Ah[idx];
      a_l[kh] = *(const short8*)&Al[idx];
    }
    mm_frags(a_h, a_l, Bh, Bl, lane, acc);
  }
  // --- epilogue
#pragma unroll
  for (int nt = 0; nt < 4; ++nt) {
#pragma unroll
    for (int r = 0; r < 4; ++r) {
      int trow = band + 4 * g + r;
      int gcol = bcol0 + nt * 16 + li;
      float v = acc[nt][r] + bias[gcol];
      if constexpr (MODE == 0) {
        int rg = m0 + trow;
        int b = rg >> 11, t = rg & 2047;
        int h = gcol >> 6, d = gcol & 63;
        o0[(((b << 3) | h) * 2048 + t) * 64 + d] = v * 0.125f;
      } else if constexpr (MODE == 1) {
        o0[(m0 + trow) * 512 + gcol] = v;
      } else {
        int gr = m0 + trow;
        int b = gr >> 6, t = gr & 63;
        int cloc = (variant == 0) ? (gcol - 512) : gcol;
        int which = cloc >> 9;
        int hd_ = cloc & 511;
        int h = hd_ >> 6, d = hd_ & 63;
        int dst = ((b * 8 + h) * 64 + t) * 64 + d;
        if (variant == 0) {
          if (which == 0) o0[dst] = v; else o1[dst] = v;
        } else {
          if (which == 0) o2[dst] = v * 0.125f; else o3[dst] = v;
        }
      }
    }
  }
}

// ---------------------------------------------------------------- A and BV (MFMA) + pinv scale
// scal: ref z0 = A^T/(max(rowsum)*max(colsum)); rowsum==1 exactly (masked softmax
// incl. diagonal), so scal = 1/max(colsum) -> per-block colsum + global atomicMax.
__global__ __launch_bounds__(256) void k_a_bv_mfma(
    const float* __restrict__ qlg, const float* __restrict__ klg,
    const float* __restrict__ k64, const float* __restrict__ v64,
    float* __restrict__ A, float* __restrict__ BV,
    unsigned int* __restrict__ scal_u) {
  __shared__ ushort KLh[4096], KLl[4096], Kh[4096], Kl_[4096], VTh[4096], VTl[4096];
  __shared__ ushort Ph[4][1024], Pl[4][1024];
  __shared__ float red[4][64];
  const int bh = blockIdx.x, tid = threadIdx.x;
  const int lane = tid & 63, w = tid >> 6, band = w * 16;
  const int g = lane >> 4, li = lane & 15;
  const int base = bh * 4096;
  // stage B planes: KL (kl rows), K (k64 rows), VT (v64 transposed)
  {
    int n = tid & 63, kc = (tid >> 6) * 16;
    float a[16], b[16], c[16];
#pragma unroll
    for (int i = 0; i < 16; ++i) {
      a[i] = klg[base + n * 64 + kc + i];
      b[i] = k64[base + n * 64 + kc + i];
      c[i] = v64[base + (kc + i) * 64 + n];
    }
#pragma unroll
    for (int c2 = 0; c2 < 2; ++c2) {
      int idx = n * 64 + ((((kc >> 3) + c2) ^ (n & 7)) << 3);
      short8 hv, lv;
#pragma unroll
      for (int i = 0; i < 8; ++i) { ushort h, l; split_bf(a[c2*8+i], h, l); hv[i]=(short)h; lv[i]=(short)l; }
      *(short8*)&KLh[idx] = hv; *(short8*)&KLl[idx] = lv;
#pragma unroll
      for (int i = 0; i < 8; ++i) { ushort h, l; split_bf(b[c2*8+i], h, l); hv[i]=(short)h; lv[i]=(short)l; }
      *(short8*)&Kh[idx] = hv; *(short8*)&Kl_[idx] = lv;
#pragma unroll
      for (int i = 0; i < 8; ++i) { ushort h, l; split_bf(c[c2*8+i], h, l); hv[i]=(short)h; lv[i]=(short)l; }
      *(short8*)&VTh[idx] = hv; *(short8*)&VTl[idx] = lv;
    }
  }
  // ql frags from global
  short8 q_h[2], q_l[2];
  {
    int row = band + li;
#pragma unroll
    for (int kh = 0; kh < 2; ++kh) {
      int k0 = kh * 32 + 8 * g;
      float tmp[8];
      *(float4*)&tmp[0] = *(const float4*)&qlg[base + row * 64 + k0];
      *(float4*)&tmp[4] = *(const float4*)&qlg[base + row * 64 + k0 + 4];
      short8 hv, lv;
#pragma unroll
      for (int i = 0; i < 8; ++i) { ushort h, l; split_bf(tmp[i], h, l); hv[i]=(short)h; lv[i]=(short)l; }
      q_h[kh] = hv; q_l[kh] = lv;
    }
  }
  __syncthreads();
  // S1 = ql @ kl^T -> masked softmax -> A
  f32x4 s1[4];
  zero_acc(s1);
  mm_frags(q_h, q_l, KLh, KLl, lane, s1);
  softmax_rows(s1, band, g, li, true, 0);
#pragma unroll
  for (int nt = 0; nt < 4; ++nt)
#pragma unroll
    for (int r = 0; r < 4; ++r)
      A[base + (band + 4 * g + r) * 64 + nt * 16 + li] = s1[nt][r];
  // column sums of A -> global max (pinv scale)
  {
    float part[4];
#pragma unroll
    for (int nt = 0; nt < 4; ++nt) {
      part[nt] = s1[nt][0] + s1[nt][1] + s1[nt][2] + s1[nt][3];
      part[nt] += __shfl_xor(part[nt], 16);
      part[nt] += __shfl_xor(part[nt], 32);
    }
    if (g == 0) {
#pragma unroll
      for (int nt = 0; nt < 4; ++nt) red[w][nt * 16 + li] = part[nt];
    }
    __syncthreads();
    if (tid < 64) {
      float t = red[0][tid] + red[1][tid] + red[2][tid] + red[3][tid];
#pragma unroll
      for (int off = 32; off; off >>= 1) t = fmaxf(t, __shfl_xor(t, off));
      if (tid == 0) atomicMax(scal_u, __float_as_uint(t));
    }
  }
  // S2 = ql @ k64^T -> masked softmax -> P -> BV = P @ v64
  f32x4 s2[4];
  zero_acc(s2);
  mm_frags(q_h, q_l, Kh, Kl_, lane, s2);
  softmax_rows(s2, band, g, li, true, 0);
  wrP(Ph[w], Pl[w], lane, s2);
  short8 p_h[2], p_l[2];
  ld_pfrags(Ph[w], Pl[w], lane, p_h, p_l);
  f32x4 y[4];
  zero_acc(y);
  mm_frags(p_h, p_l, VTh, VTl, lane, y);
#pragma unroll
  for (int nt = 0; nt < 4; ++nt)
#pragma unroll
    for (int r = 0; r < 4; ++r)
      BV[base + (band + 4 * g + r) * 64 + nt * 16 + li] = y[nt][r];
}

// ---------------------------------------------------------------- pinv (MFMA Newton-Schulz)
__device__ __forceinline__ void ld_afrags(const ushort* hp, const ushort* lp,
                                          int band, int lane,
                                          short8 ah[2], short8 al[2]) {
  const int g = lane >> 4, li = lane & 15;
  const int row = band + li;
#pragma unroll
  for (int kh = 0; kh < 2; ++kh) {
    int k0 = kh * 32 + 8 * g;
    int idx = row * 64 + ((((k0 >> 3) ^ (row & 7)) << 3));
    ah[kh] = *(const short8*)&hp[idx];
    al[kh] = *(const short8*)&lp[idx];
  }
}

__device__ __forceinline__ void mm_frags0(const short8 ah[2], const short8 al[2],
                                          const ushort* bhp, const ushort* blp,
                                          int lane, f32x4 acc[4]) {
  zero_acc(acc);
  mm_frags(ah, al, bhp, blp, lane, acc);
}

__device__ __forceinline__ void wrT(ushort* hp, ushort* lp, int band, int lane,
                                    const f32x4 acc[4], float cI, float mul) {
  const int g = lane >> 4, li = lane & 15;
  const int r0 = band + 4 * g;
#pragma unroll
  for (int nt = 0; nt < 4; ++nt) {
    int c = nt * 16 + li;
    ushort h[4], l[4];
#pragma unroll
    for (int r = 0; r < 4; ++r) {
      float v = mul * acc[nt][r] + ((r0 + r) == c ? cI : 0.f);
      split_bf(v, h[r], l[r]);
    }
    int idx = c * 64 + (((((r0) >> 3) ^ (c & 7)) << 3) | (r0 & 7));
    *(ushort4*)&hp[idx] = make_ushort4(h[0], h[1], h[2], h[3]);
    *(ushort4*)&lp[idx] = make_ushort4(l[0], l[1], l[2], l[3]);
  }
}

__device__ __forceinline__ void wrN(ushort* hp, ushort* lp, int band, int lane,
                                    const f32x4 acc[4], float mul) {
  const int g = lane >> 4, li = lane & 15;
#pragma unroll
  for (int nt = 0; nt < 4; ++nt) {
    int c = nt * 16 + li;
#pragma unroll
    for (int r = 0; r < 4; ++r) {
      int row = band + 4 * g + r;
      ushort h, l;
      split_bf(mul * acc[nt][r], h, l);
      int idx = swz_idx(row, c);
      hp[idx] = h;
      lp[idx] = l;
    }
  }
}

__global__ __launch_bounds__(256) void k_pinv(const float* __restrict__ A,
                                              const float* __restrict__ BVg,
                                              const unsigned int* __restrict__ scal_u,
                                              float* __restrict__ C) {
  __shared__ ushort ZT_h[4096], ZT_l[4096], ZA_h[4096], ZA_l[4096],
                    PA_h[4096], PA_l[4096], QA_h[4096], QA_l[4096],
                    QB_h[4096], QB_l[4096], BT_h[4096], BT_l[4096];
  const int bh = blockIdx.x, tid = threadIdx.x;
  const int lane = tid & 63, w = tid >> 6, band = w * 16;
  const int base = bh * 4096;
  const float sc = 1.f / __uint_as_float(scal_u[0]);
  const float* Ag = A + base;
  const float* Bg = BVg + base;

  {
    int prow = tid >> 2;
    int pc0 = (tid & 3) * 16;
#pragma unroll 4
    for (int j = 0; j < 16; ++j) {
      int col = pc0 + j;
      float av = Ag[prow * 64 + col] * sc;
      ushort h, l;
      split_bf(av, h, l);
      int i1 = swz_idx(prow, col);
      ZT_h[i1] = h; ZT_l[i1] = l;
      int i2 = swz_idx(col, prow);
      ZA_h[i2] = h; ZA_l[i2] = l;
      float bv = Bg[prow * 64 + col];
      split_bf(bv, h, l);
      BT_h[i2] = h; BT_l[i2] = l;
    }
  }
  short8 a_h[2], a_l[2];
  {
    const int g = lane >> 4, li = lane & 15;
    int row = band + li;
#pragma unroll
    for (int kh = 0; kh < 2; ++kh) {
      int k0 = kh * 32 + 8 * g;
      float tmp[8];
      *(float4*)&tmp[0] = *(const float4*)&Ag[row * 64 + k0];
      *(float4*)&tmp[4] = *(const float4*)&Ag[row * 64 + k0 + 4];
      short8 hv, lv;
#pragma unroll
      for (int i = 0; i < 8; ++i) {
        ushort h, l;
        split_bf(tmp[i], h, l);
        hv[i] = (short)h;
        lv[i] = (short)l;
      }
      a_h[kh] = hv;
      a_l[kh] = lv;
    }
  }
  __syncthreads();

  for (int it = 0; it < 6; ++it) {
    f32x4 acc[4];
    mm_frags0(a_h, a_l, ZT_h, ZT_l, lane, acc);
    wrN(PA_h, PA_l, band, lane, acc, 1.f);
    wrT(QA_h, QA_l, band, lane, acc, 7.f, -1.f);
    __syncthreads();
    short8 p_h[2], p_l[2];
    ld_afrags(PA_h, PA_l, band, lane, p_h, p_l);
    mm_frags0(p_h, p_l, QA_h, QA_l, lane, acc);
    wrT(QB_h, QB_l, band, lane, acc, 15.f, -1.f);
    __syncthreads();
    mm_frags0(p_h, p_l, QB_h, QB_l, lane, acc);
    wrT(QA_h, QA_l, band, lane, acc, 13.f, -1.f);
    __syncthreads();
    short8 z_h[2], z_l[2];
    ld_afrags(ZA_h, ZA_l, band, lane, z_h, z_l);
    mm_frags0(z_h, z_l, QA_h, QA_l, lane, acc);
    wrN(ZA_h, ZA_l, band, lane, acc, 0.25f);
    wrT(ZT_h, ZT_l, band, lane, acc, 0.f, 0.25f);
    __syncthreads();
  }
  {
    short8 z_h[2], z_l[2];
    ld_afrags(ZA_h, ZA_l, band, lane, z_h, z_l);
    f32x4 acc[4];
    mm_frags0(z_h, z_l, BT_h, BT_l, lane, acc);
    const int g = lane >> 4, li = lane & 15;
#pragma unroll
    for (int nt = 0; nt < 4; ++nt) {
#pragma unroll
      for (int r = 0; r < 4; ++r) {
        int row = band + 4 * g + r;
        int col = nt * 16 + li;
        C[base + row * 64 + col] = acc[nt][r];
      }
    }
  }
}

// ---------------------------------------------------------------- F softmax + y = F@C (MFMA)
__global__ __launch_bounds__(256) void k_f_y_mfma(const float* __restrict__ q,
                                                  const float* __restrict__ klg,
                                                  const float* __restrict__ C,
                                                  float* __restrict__ yh) {
  __shared__ ushort KLh[4096], KLl[4096], CTh[4096], CTl[4096];
  __shared__ ushort Ph[4][1024], Pl[4][1024];
  const int bh = blockIdx.x;
  const int b = bh >> 3, h = bh & 7;
  const int t0 = blockIdx.y * 64;
  const int tid = threadIdx.x;
  const int lane = tid & 63, w = tid >> 6, band = w * 16;
  const int g = lane >> 4, li = lane & 15;
  const int base = bh * 4096;
  // stage KL (kl rows) + CT (C transposed)
  {
    int n = tid & 63, kc = (tid >> 6) * 16;
    float a[16], c[16];
#pragma unroll
    for (int i = 0; i < 16; ++i) {
      a[i] = klg[base + n * 64 + kc + i];
      c[i] = C[base + (kc + i) * 64 + n];
    }
#pragma unroll
    for (int c2 = 0; c2 < 2; ++c2) {
      int idx = n * 64 + ((((kc >> 3) + c2) ^ (n & 7)) << 3);
      short8 hv, lv;
#pragma unroll
      for (int i = 0; i < 8; ++i) { ushort hh, ll; split_bf(a[c2*8+i], hh, ll); hv[i]=(short)hh; lv[i]=(short)ll; }
      *(short8*)&KLh[idx] = hv; *(short8*)&KLl[idx] = lv;
#pragma unroll
      for (int i = 0; i < 8; ++i) { ushort hh, ll; split_bf(c[c2*8+i], hh, ll); hv[i]=(short)hh; lv[i]=(short)ll; }
      *(short8*)&CTh[idx] = hv; *(short8*)&CTl[idx] = lv;
    }
  }
  // q frags from global
  short8 q_h[2], q_l[2];
  {
    int t = t0 + band + li;
#pragma unroll
    for (int kh = 0; kh < 2; ++kh) {
      int k0 = kh * 32 + 8 * g;
      float tmp[8];
      *(float4*)&tmp[0] = *(const float4*)&q[(bh * 2048 + t) * 64 + k0];
      *(float4*)&tmp[4] = *(const float4*)&q[(bh * 2048 + t) * 64 + k0 + 4];
      short8 hv, lv;
#pragma unroll
      for (int i = 0; i < 8; ++i) { ushort hh, ll; split_bf(tmp[i], hh, ll); hv[i]=(short)hh; lv[i]=(short)ll; }
      q_h[kh] = hv; q_l[kh] = lv;
    }
  }
  __syncthreads();
  f32x4 s[4];
  zero_acc(s);
  mm_frags(q_h, q_l, KLh, KLl, lane, s);
  softmax_rows(s, band, g, li, blockIdx.y == 0, 0);
  wrP(Ph[w], Pl[w], lane, s);
  short8 p_h[2], p_l[2];
  ld_pfrags(Ph[w], Pl[w], lane, p_h, p_l);
  f32x4 y[4];
  zero_acc(y);
  mm_frags(p_h, p_l, CTh, CTl, lane, y);
#pragma unroll
  for (int nt = 0; nt < 4; ++nt)
#pragma unroll
    for (int r = 0; r < 4; ++r) {
      int t = t0 + band + 4 * g + r;
      int d = nt * 16 + li;
      yh[(b * 2048 + t) * 512 + h * 64 + d] = y[nt][r];
    }
}

// ---------------------------------------------------------------- launcher
extern "C" void kernel_launch(void* const* d_in, const int* in_sizes, int n_in,
                              void* d_out, int out_size, void* d_ws, size_t ws_size,
                              hipStream_t stream) {
  const float* x = (const float*)d_in[0];
  const float* w_qkv = (const float*)d_in[1];
  const float* b_qkv = (const float*)d_in[2];
  const float* w_proj = (const float*)d_in[3];
  const float* b_proj = (const float*)d_in[4];
  float* out = (float*)d_out;

  float* ws = (float*)d_ws;
  float* q = ws;              // 16*2048*64 = 2097152
  float* k64 = q + 2097152;   // 16*64*64 = 65536
  float* v64 = k64 + 65536;
  float* xp = v64 + 65536;    // 2*64*512
  float* ql = xp + 65536;
  float* kl = ql + 65536;
  float* Am = kl + 65536;
  float* BV = Am + 65536;
  float* Cm = BV + 65536;
  unsigned int* scal_u = (unsigned int*)(Cm + 65536);  // 1 uint (64 slots reserved)
  float* yh = (float*)(scal_u + 64);  // 2*2048*512 = 2097152

  k_pool<<<dim3(256), dim3(256), 0, stream>>>(x, xp, scal_u);
  k_gemm_mfma<0><<<dim3(512), dim3(256), 0, stream>>>(x, nullptr, w_qkv, b_qkv,
                                                      q, nullptr, nullptr, nullptr);
  k_gemm_mfma<2><<<dim3(16, 4), dim3(256), 0, stream>>>(x, xp, w_qkv, b_qkv,
                                                        k64, v64, ql, kl);
  k_a_bv_mfma<<<dim3(16), dim3(256), 0, stream>>>(ql, kl, k64, v64, Am, BV, scal_u);
  k_pinv<<<dim3(16), dim3(256), 0, stream>>>(Am, BV, scal_u, Cm);
  k_f_y_mfma<<<dim3(16, 32), dim3(256), 0, stream>>>(q, kl, Cm, yh);
  k_gemm_mfma<1><<<dim3(512), dim3(256), 0, stream>>>(yh, nullptr, w_proj, b_proj,
                                                      out, nullptr, nullptr, nullptr);
}

// Round 11
// 139.253 us; speedup vs baseline: 2.1385x; 1.0323x over previous
//
#include <hip/hip_runtime.h>
#include <hip/hip_bf16.h>

// Problem constants: B=2, T=2048, E=512, H=8, hd=64, M=64, l=32, BH=16.
#define TB 2048
#define EB 512

using short8 = __attribute__((ext_vector_type(8))) short;
using f32x4  = __attribute__((ext_vector_type(4))) float;

// ---------------------------------------------------------------- pool x
__global__ __launch_bounds__(256) void k_pool(const float* __restrict__ x,
                                              float* __restrict__ xp,
                                              unsigned int* __restrict__ scal_u) {
  if (blockIdx.x == 0 && threadIdx.x == 0) scal_u[0] = 0u;  // init atomic max
  int idx = blockIdx.x * 256 + threadIdx.x;  // [0, 2*64*512)
  int b = idx >> 15;
  int rem = idx & 32767;
  int m = rem >> 9;
  int e = rem & 511;
  const float* src = x + (b * TB + m * 32) * EB + e;
  float s = 0.f;
#pragma unroll
  for (int i = 0; i < 32; ++i) s += src[i * EB];
  xp[idx] = s * (1.f / 32.f);
}

// ---------------------------------------------------------------- shared helpers
__device__ __forceinline__ int swz_idx(int row, int col) {
  return row * 64 + ((((col >> 3) ^ (row & 7)) << 3) | (col & 7));
}

__device__ __forceinline__ void split_bf(float v, ushort& h, ushort& l) {
  __hip_bfloat16 bh = __float2bfloat16(v);
  float fh = __bfloat162float(bh);
  __hip_bfloat16 bl = __float2bfloat16(v - fh);
  h = *(ushort*)&bh;
  l = *(ushort*)&bl;
}

// acc[nt] += A(frags) @ B(T-plane, hi/lo, swizzled)
__device__ __forceinline__ void mm_frags(const short8 ah[2], const short8 al[2],
                                         const ushort* bhp, const ushort* blp,
                                         int lane, f32x4 acc[4]) {
  const int g = lane >> 4, li = lane & 15;
#pragma unroll
  for (int nt = 0; nt < 4; ++nt) {
    f32x4 a = acc[nt];
#pragma unroll
    for (int kh = 0; kh < 2; ++kh) {
      int n = nt * 16 + li;
      int k0 = kh * 32 + 8 * g;
      int idx = n * 64 + ((((k0 >> 3) ^ (n & 7)) << 3));
      short8 bh = *(const short8*)&bhp[idx];
      short8 bl = *(const short8*)&blp[idx];
      a = __builtin_amdgcn_mfma_f32_16x16x32_bf16(al[kh], bh, a, 0, 0, 0);
      a = __builtin_amdgcn_mfma_f32_16x16x32_bf16(ah[kh], bl, a, 0, 0, 0);
      a = __builtin_amdgcn_mfma_f32_16x16x32_bf16(ah[kh], bh, a, 0, 0, 0);
    }
    acc[nt] = a;
  }
}

__device__ __forceinline__ void zero_acc(f32x4 acc[4]) {
#pragma unroll
  for (int nt = 0; nt < 4; ++nt) acc[nt] = (f32x4){0.f, 0.f, 0.f, 0.f};
}

// masked row-softmax on C/D layout: row = band+4g+r, col = nt*16+li.
__device__ __forceinline__ void softmax_rows(f32x4 s[4], int band, int g, int li,
                                             bool causal, int t0) {
#pragma unroll
  for (int r = 0; r < 4; ++r) {
    int trow = t0 + band + 4 * g + r;
    float m = -1e30f;
    float sv[4];
#pragma unroll
    for (int nt = 0; nt < 4; ++nt) {
      int col = nt * 16 + li;
      bool ok = !causal || (col <= trow);
      sv[nt] = ok ? s[nt][r] : -1e30f;
      m = fmaxf(m, sv[nt]);
    }
    m = fmaxf(m, __shfl_xor(m, 1));
    m = fmaxf(m, __shfl_xor(m, 2));
    m = fmaxf(m, __shfl_xor(m, 4));
    m = fmaxf(m, __shfl_xor(m, 8));
    float su = 0.f;
    float ee[4];
#pragma unroll
    for (int nt = 0; nt < 4; ++nt) {
      ee[nt] = (sv[nt] > -1e29f) ? __expf(sv[nt] - m) : 0.f;
      su += ee[nt];
    }
    su += __shfl_xor(su, 1);
    su += __shfl_xor(su, 2);
    su += __shfl_xor(su, 4);
    su += __shfl_xor(su, 8);
    float inv = 1.f / su;
#pragma unroll
    for (int nt = 0; nt < 4; ++nt) s[nt][r] = ee[nt] * inv;
  }
}

// write a 16-row hi/lo P-plane (per-wave region), rows local 0..15
__device__ __forceinline__ void wrP(ushort* hp, ushort* lp, int lane,
                                    const f32x4 acc[4]) {
  const int g = lane >> 4, li = lane & 15;
#pragma unroll
  for (int nt = 0; nt < 4; ++nt) {
    int c = nt * 16 + li;
#pragma unroll
    for (int r = 0; r < 4; ++r) {
      int row = 4 * g + r;
      ushort h, l;
      split_bf(acc[nt][r], h, l);
      int idx = swz_idx(row, c);
      hp[idx] = h;
      lp[idx] = l;
    }
  }
}

__device__ __forceinline__ void ld_pfrags(const ushort* hp, const ushort* lp,
                                          int lane, short8 ah[2], short8 al[2]) {
  const int g = lane >> 4, li = lane & 15;
#pragma unroll
  for (int kh = 0; kh < 2; ++kh) {
    int k0 = kh * 32 + 8 * g;
    int idx = li * 64 + ((((k0 >> 3) ^ (li & 7)) << 3));
    ah[kh] = *(const short8*)&hp[idx];
    al[kh] = *(const short8*)&lp[idx];
  }
}

// ---------------------------------------------------------------- MFMA GEMMs vs W
// MODE 1: out-proj A=yh rows 4096, W cols 0..511 (LDW 512), out row-major (XCD remap)
// MODE 2: merged small GEMMs, grid (16,4): variant=by>>1
//         v0: A=x rows (b,t<64), W cols 512..1535 -> k64/v64 (o0/o1)
//         v1: A=xp rows 128,     W cols 0..1023   -> ql*0.125/kl (o2/o3)
// Register-prefetch double-buffered staging.
template <int MODE>
__global__ __launch_bounds__(256) void k_gemm_mfma(const float* __restrict__ A,
                                                   const float* __restrict__ A2,
                                                   const float* __restrict__ W,
                                                   const float* __restrict__ bias,
                                                   float* __restrict__ o0,
                                                   float* __restrict__ o1,
                                                   float* __restrict__ o2,
                                                   float* __restrict__ o3) {
  constexpr int LDW = (MODE == 1) ? 512 : 1536;
  __shared__ ushort Ah[4096], Al[4096], Bh[4096], Bl[4096];
  const int tid = threadIdx.x;
  const int lane = tid & 63, w = tid >> 6, band = w * 16;
  int bx, by;
  if constexpr (MODE == 0 || MODE == 1) {
    int bid = blockIdx.x;
    by = ((bid & 7) << 3) | (bid >> 6);
    bx = (bid >> 3) & 7;
  } else {
    bx = blockIdx.x;
    by = blockIdx.y;
  }
  const int variant = (MODE == 2) ? (by >> 1) : 0;
  const int m0 = (MODE == 2) ? ((by & 1) * 64) : by * 64;
  const int bcol0 = (MODE == 2) ? (variant == 0 ? 512 + bx * 64 : bx * 64)
                                : bx * 64;
  const int g = lane >> 4, li = lane & 15;

  const int arow = tid >> 2, akc = (tid & 3) * 16;   // A staging coords
  const int bn = tid & 63, bkc = (tid >> 6) * 16;    // B staging coords

  const float* asrc;
  {
    int gr = m0 + arow;
    if constexpr (MODE == 2) {
      asrc = (variant == 0) ? (A + ((gr >> 6) * TB + (gr & 63)) * EB)
                            : (A2 + gr * EB);
    } else {
      asrc = A + gr * EB;
    }
  }

  f32x4 acc[4];
  zero_acc(acc);

  float av[16], bv[16];
#pragma unroll
  for (int j = 0; j < 4; ++j)
    *(float4*)&av[j * 4] = *(const float4*)&asrc[akc + j * 4];
#pragma unroll
  for (int i = 0; i < 16; ++i) bv[i] = W[(bkc + i) * LDW + bcol0 + bn];

#pragma unroll
  for (int k0 = 0; k0 < 512; k0 += 64) {
    if (k0) __syncthreads();
#pragma unroll
    for (int c2 = 0; c2 < 2; ++c2) {
      short8 hv, lv;
#pragma unroll
      for (int i = 0; i < 8; ++i) {
        ushort h, l;
        split_bf(av[c2 * 8 + i], h, l);
        hv[i] = (short)h;
        lv[i] = (short)l;
      }
      int chunk = ((akc >> 3) + c2) ^ (arow & 7);
      int idx = arow * 64 + chunk * 8;
      *(short8*)&Ah[idx] = hv;
      *(short8*)&Al[idx] = lv;
    }
#pragma unroll
    for (int c2 = 0; c2 < 2; ++c2) {
      short8 hv, lv;
#pragma unroll
      for (int i = 0; i < 8; ++i) {
        ushort h, l;
        split_bf(bv[c2 * 8 + i], h, l);
        hv[i] = (short)h;
        lv[i] = (short)l;
      }
      int chunk = ((bkc >> 3) + c2) ^ (bn & 7);
      int idx = bn * 64 + chunk * 8;
      *(short8*)&Bh[idx] = hv;
      *(short8*)&Bl[idx] = lv;
    }
    __syncthreads();
    if (k0 + 64 < 512) {
#pragma unroll
      for (int j = 0; j < 4; ++j)
        *(float4*)&av[j * 4] = *(const float4*)&asrc[k0 + 64 + akc + j * 4];
#pragma unroll
      for (int i = 0; i < 16; ++i)
        bv[i] = W[(k0 + 64 + bkc + i) * LDW + bcol0 + bn];
    }
    short8 a_h[2], a_l[2];
    const int row = band + li;
#pragma unroll
    for (int kh = 0; kh < 2; ++kh) {
      int chunk = ((kh * 32 + 8 * g) >> 3) ^ (row & 7);
      int idx = row * 64 + chunk * 8;
      a_h[kh] = *(const short8*)&Ah[idx];
      a_l[kh] = *(const short8*)&Al[idx];
    }
    mm_frags(a_h, a_l, Bh, Bl, lane, acc);
  }
  // --- epilogue
#pragma unroll
  for (int nt = 0; nt < 4; ++nt) {
#pragma unroll
    for (int r = 0; r < 4; ++r) {
      int trow = band + 4 * g + r;
      int gcol = bcol0 + nt * 16 + li;
      float v = acc[nt][r] + bias[gcol];
      if constexpr (MODE == 1) {
        o0[(m0 + trow) * 512 + gcol] = v;
      } else {
        int gr = m0 + trow;
        int b = gr >> 6, t = gr & 63;
        int cloc = (variant == 0) ? (gcol - 512) : gcol;
        int which = cloc >> 9;
        int hd_ = cloc & 511;
        int h = hd_ >> 6, d = hd_ & 63;
        int dst = ((b * 8 + h) * 64 + t) * 64 + d;
        if (variant == 0) {
          if (which == 0) o0[dst] = v; else o1[dst] = v;
        } else {
          if (which == 0) o2[dst] = v * 0.125f; else o3[dst] = v;
        }
      }
    }
  }
}

// ---------------------------------------------------------------- A/BV (blk 0-15) + W2 precompute (blk 16-31)
// a_bv: A = softmax(tril(ql@kl^T)); BV = softmax(tril(ql@k64^T)) @ v64;
//       scal = 1/max(colsum(A)) via atomicMax (rowsum==1 exactly).
// W2:   W2[bh] = 0.125 * Wq[:,h-slice] @ kl[bh]^T   (512x64)
//       bconst[bh][j] = 0.125 * sum_d bq[h*64+d]*kl[bh][j][d]
__global__ __launch_bounds__(256) void k_abv_w2(
    const float* __restrict__ qlg, const float* __restrict__ klg,
    const float* __restrict__ k64, const float* __restrict__ v64,
    const float* __restrict__ w_qkv, const float* __restrict__ b_qkv,
    float* __restrict__ A, float* __restrict__ BV,
    float* __restrict__ W2g, float* __restrict__ bcst,
    unsigned int* __restrict__ scal_u) {
  __shared__ ushort KLh[4096], KLl[4096], Kh[4096], Kl_[4096], VTh[4096], VTl[4096];
  __shared__ ushort Ph[4][1024], Pl[4][1024];
  __shared__ float red[4][64];
  const int tid = threadIdx.x;
  const int lane = tid & 63, w = tid >> 6, band = w * 16;
  const int g = lane >> 4, li = lane & 15;

  if (blockIdx.x >= 16) {
    // ---------------- W2 precompute for bh = blockIdx.x - 16
    const int bh = blockIdx.x - 16;
    const int h = bh & 7;
    const int base = bh * 4096;
    {
      int n = tid & 63, kc = (tid >> 6) * 16;
      float a[16];
#pragma unroll
      for (int i = 0; i < 16; ++i) a[i] = klg[base + n * 64 + kc + i];
#pragma unroll
      for (int c2 = 0; c2 < 2; ++c2) {
        int idx = n * 64 + ((((kc >> 3) + c2) ^ (n & 7)) << 3);
        short8 hv, lv;
#pragma unroll
        for (int i = 0; i < 8; ++i) {
          ushort hh, ll;
          split_bf(a[c2 * 8 + i], hh, ll);
          hv[i] = (short)hh;
          lv[i] = (short)ll;
        }
        *(short8*)&KLh[idx] = hv;
        *(short8*)&KLl[idx] = lv;
      }
    }
    __syncthreads();
    if (tid < 64) {
      float bc = 0.f;
      for (int d = 0; d < 64; ++d)
        bc += b_qkv[h * 64 + d] * klg[base + tid * 64 + d];
      bcst[bh * 64 + tid] = 0.125f * bc;
    }
#pragma unroll
    for (int m0 = 0; m0 < 512; m0 += 64) {
      short8 a_h[2], a_l[2];
      int row = m0 + band + li;
#pragma unroll
      for (int kh = 0; kh < 2; ++kh) {
        int d0 = kh * 32 + 8 * g;
        float tmp[8];
        *(float4*)&tmp[0] = *(const float4*)&w_qkv[row * 1536 + h * 64 + d0];
        *(float4*)&tmp[4] = *(const float4*)&w_qkv[row * 1536 + h * 64 + d0 + 4];
        short8 hv, lv;
#pragma unroll
        for (int i = 0; i < 8; ++i) {
          ushort hh, ll;
          split_bf(tmp[i], hh, ll);
          hv[i] = (short)hh;
          lv[i] = (short)ll;
        }
        a_h[kh] = hv;
        a_l[kh] = lv;
      }
      f32x4 acc[4];
      zero_acc(acc);
      mm_frags(a_h, a_l, KLh, KLl, lane, acc);
#pragma unroll
      for (int nt = 0; nt < 4; ++nt)
#pragma unroll
        for (int r = 0; r < 4; ++r)
          W2g[bh * 32768 + (m0 + band + 4 * g + r) * 64 + nt * 16 + li] =
              0.125f * acc[nt][r];
    }
    return;
  }

  // ---------------- a_bv for bh = blockIdx.x
  const int bh = blockIdx.x;
  const int base = bh * 4096;
  {
    int n = tid & 63, kc = (tid >> 6) * 16;
    float a[16], b[16], c[16];
#pragma unroll
    for (int i = 0; i < 16; ++i) {
      a[i] = klg[base + n * 64 + kc + i];
      b[i] = k64[base + n * 64 + kc + i];
      c[i] = v64[base + (kc + i) * 64 + n];
    }
#pragma unroll
    for (int c2 = 0; c2 < 2; ++c2) {
      int idx = n * 64 + ((((kc >> 3) + c2) ^ (n & 7)) << 3);
      short8 hv, lv;
#pragma unroll
      for (int i = 0; i < 8; ++i) { ushort h, l; split_bf(a[c2*8+i], h, l); hv[i]=(short)h; lv[i]=(short)l; }
      *(short8*)&KLh[idx] = hv; *(short8*)&KLl[idx] = lv;
#pragma unroll
      for (int i = 0; i < 8; ++i) { ushort h, l; split_bf(b[c2*8+i], h, l); hv[i]=(short)h; lv[i]=(short)l; }
      *(short8*)&Kh[idx] = hv; *(short8*)&Kl_[idx] = lv;
#pragma unroll
      for (int i = 0; i < 8; ++i) { ushort h, l; split_bf(c[c2*8+i], h, l); hv[i]=(short)h; lv[i]=(short)l; }
      *(short8*)&VTh[idx] = hv; *(short8*)&VTl[idx] = lv;
    }
  }
  short8 q_h[2], q_l[2];
  {
    int row = band + li;
#pragma unroll
    for (int kh = 0; kh < 2; ++kh) {
      int k0 = kh * 32 + 8 * g;
      float tmp[8];
      *(float4*)&tmp[0] = *(const float4*)&qlg[base + row * 64 + k0];
      *(float4*)&tmp[4] = *(const float4*)&qlg[base + row * 64 + k0 + 4];
      short8 hv, lv;
#pragma unroll
      for (int i = 0; i < 8; ++i) { ushort h, l; split_bf(tmp[i], h, l); hv[i]=(short)h; lv[i]=(short)l; }
      q_h[kh] = hv; q_l[kh] = lv;
    }
  }
  __syncthreads();
  f32x4 s1[4];
  zero_acc(s1);
  mm_frags(q_h, q_l, KLh, KLl, lane, s1);
  softmax_rows(s1, band, g, li, true, 0);
#pragma unroll
  for (int nt = 0; nt < 4; ++nt)
#pragma unroll
    for (int r = 0; r < 4; ++r)
      A[base + (band + 4 * g + r) * 64 + nt * 16 + li] = s1[nt][r];
  {
    float part[4];
#pragma unroll
    for (int nt = 0; nt < 4; ++nt) {
      part[nt] = s1[nt][0] + s1[nt][1] + s1[nt][2] + s1[nt][3];
      part[nt] += __shfl_xor(part[nt], 16);
      part[nt] += __shfl_xor(part[nt], 32);
    }
    if (g == 0) {
#pragma unroll
      for (int nt = 0; nt < 4; ++nt) red[w][nt * 16 + li] = part[nt];
    }
    __syncthreads();
    if (tid < 64) {
      float t = red[0][tid] + red[1][tid] + red[2][tid] + red[3][tid];
#pragma unroll
      for (int off = 32; off; off >>= 1) t = fmaxf(t, __shfl_xor(t, off));
      if (tid == 0) atomicMax(scal_u, __float_as_uint(t));
    }
  }
  f32x4 s2[4];
  zero_acc(s2);
  mm_frags(q_h, q_l, Kh, Kl_, lane, s2);
  softmax_rows(s2, band, g, li, true, 0);
  wrP(Ph[w], Pl[w], lane, s2);
  short8 p_h[2], p_l[2];
  ld_pfrags(Ph[w], Pl[w], lane, p_h, p_l);
  f32x4 y[4];
  zero_acc(y);
  mm_frags(p_h, p_l, VTh, VTl, lane, y);
#pragma unroll
  for (int nt = 0; nt < 4; ++nt)
#pragma unroll
    for (int r = 0; r < 4; ++r)
      BV[base + (band + 4 * g + r) * 64 + nt * 16 + li] = y[nt][r];
}

// ---------------------------------------------------------------- pinv (MFMA Newton-Schulz)
__device__ __forceinline__ void ld_afrags(const ushort* hp, const ushort* lp,
                                          int band, int lane,
                                          short8 ah[2], short8 al[2]) {
  const int g = lane >> 4, li = lane & 15;
  const int row = band + li;
#pragma unroll
  for (int kh = 0; kh < 2; ++kh) {
    int k0 = kh * 32 + 8 * g;
    int idx = row * 64 + ((((k0 >> 3) ^ (row & 7)) << 3));
    ah[kh] = *(const short8*)&hp[idx];
    al[kh] = *(const short8*)&lp[idx];
  }
}

__device__ __forceinline__ void mm_frags0(const short8 ah[2], const short8 al[2],
                                          const ushort* bhp, const ushort* blp,
                                          int lane, f32x4 acc[4]) {
  zero_acc(acc);
  mm_frags(ah, al, bhp, blp, lane, acc);
}

__device__ __forceinline__ void wrT(ushort* hp, ushort* lp, int band, int lane,
                                    const f32x4 acc[4], float cI, float mul) {
  const int g = lane >> 4, li = lane & 15;
  const int r0 = band + 4 * g;
#pragma unroll
  for (int nt = 0; nt < 4; ++nt) {
    int c = nt * 16 + li;
    ushort h[4], l[4];
#pragma unroll
    for (int r = 0; r < 4; ++r) {
      float v = mul * acc[nt][r] + ((r0 + r) == c ? cI : 0.f);
      split_bf(v, h[r], l[r]);
    }
    int idx = c * 64 + (((((r0) >> 3) ^ (c & 7)) << 3) | (r0 & 7));
    *(ushort4*)&hp[idx] = make_ushort4(h[0], h[1], h[2], h[3]);
    *(ushort4*)&lp[idx] = make_ushort4(l[0], l[1], l[2], l[3]);
  }
}

__device__ __forceinline__ void wrN(ushort* hp, ushort* lp, int band, int lane,
                                    const f32x4 acc[4], float mul) {
  const int g = lane >> 4, li = lane & 15;
#pragma unroll
  for (int nt = 0; nt < 4; ++nt) {
    int c = nt * 16 + li;
#pragma unroll
    for (int r = 0; r < 4; ++r) {
      int row = band + 4 * g + r;
      ushort h, l;
      split_bf(mul * acc[nt][r], h, l);
      int idx = swz_idx(row, c);
      hp[idx] = h;
      lp[idx] = l;
    }
  }
}

__global__ __launch_bounds__(256) void k_pinv(const float* __restrict__ A,
                                              const float* __restrict__ BVg,
                                              const unsigned int* __restrict__ scal_u,
                                              float* __restrict__ C) {
  __shared__ ushort ZT_h[4096], ZT_l[4096], ZA_h[4096], ZA_l[4096],
                    PA_h[4096], PA_l[4096], QA_h[4096], QA_l[4096],
                    QB_h[4096], QB_l[4096], BT_h[4096], BT_l[4096];
  const int bh = blockIdx.x, tid = threadIdx.x;
  const int lane = tid & 63, w = tid >> 6, band = w * 16;
  const int base = bh * 4096;
  const float sc = 1.f / __uint_as_float(scal_u[0]);
  const float* Ag = A + base;
  const float* Bg = BVg + base;

  {
    int prow = tid >> 2;
    int pc0 = (tid & 3) * 16;
#pragma unroll 4
    for (int j = 0; j < 16; ++j) {
      int col = pc0 + j;
      float av = Ag[prow * 64 + col] * sc;
      ushort h, l;
      split_bf(av, h, l);
      int i1 = swz_idx(prow, col);
      ZT_h[i1] = h; ZT_l[i1] = l;
      int i2 = swz_idx(col, prow);
      ZA_h[i2] = h; ZA_l[i2] = l;
      float bv = Bg[prow * 64 + col];
      split_bf(bv, h, l);
      BT_h[i2] = h; BT_l[i2] = l;
    }
  }
  short8 a_h[2], a_l[2];
  {
    const int g = lane >> 4, li = lane & 15;
    int row = band + li;
#pragma unroll
    for (int kh = 0; kh < 2; ++kh) {
      int k0 = kh * 32 + 8 * g;
      float tmp[8];
      *(float4*)&tmp[0] = *(const float4*)&Ag[row * 64 + k0];
      *(float4*)&tmp[4] = *(const float4*)&Ag[row * 64 + k0 + 4];
      short8 hv, lv;
#pragma unroll
      for (int i = 0; i < 8; ++i) {
        ushort h, l;
        split_bf(tmp[i], h, l);
        hv[i] = (short)h;
        lv[i] = (short)l;
      }
      a_h[kh] = hv;
      a_l[kh] = lv;
    }
  }
  __syncthreads();

  for (int it = 0; it < 6; ++it) {
    f32x4 acc[4];
    mm_frags0(a_h, a_l, ZT_h, ZT_l, lane, acc);
    wrN(PA_h, PA_l, band, lane, acc, 1.f);
    wrT(QA_h, QA_l, band, lane, acc, 7.f, -1.f);
    __syncthreads();
    short8 p_h[2], p_l[2];
    ld_afrags(PA_h, PA_l, band, lane, p_h, p_l);
    mm_frags0(p_h, p_l, QA_h, QA_l, lane, acc);
    wrT(QB_h, QB_l, band, lane, acc, 15.f, -1.f);
    __syncthreads();
    mm_frags0(p_h, p_l, QB_h, QB_l, lane, acc);
    wrT(QA_h, QA_l, band, lane, acc, 13.f, -1.f);
    __syncthreads();
    short8 z_h[2], z_l[2];
    ld_afrags(ZA_h, ZA_l, band, lane, z_h, z_l);
    mm_frags0(z_h, z_l, QA_h, QA_l, lane, acc);
    wrN(ZA_h, ZA_l, band, lane, acc, 0.25f);
    wrT(ZT_h, ZT_l, band, lane, acc, 0.f, 0.25f);
    __syncthreads();
  }
  {
    short8 z_h[2], z_l[2];
    ld_afrags(ZA_h, ZA_l, band, lane, z_h, z_l);
    f32x4 acc[4];
    mm_frags0(z_h, z_l, BT_h, BT_l, lane, acc);
    const int g = lane >> 4, li = lane & 15;
#pragma unroll
    for (int nt = 0; nt < 4; ++nt) {
#pragma unroll
      for (int r = 0; r < 4; ++r) {
        int row = band + 4 * g + r;
        int col = nt * 16 + li;
        C[base + row * 64 + col] = acc[nt][r];
      }
    }
  }
}

// ---------------------------------------------------------------- fused F GEMM: x@W2 -> softmax -> @C -> yh
__global__ __launch_bounds__(256) void k_f_y2(const float* __restrict__ x,
                                              const float* __restrict__ W2g,
                                              const float* __restrict__ bcst,
                                              const float* __restrict__ C,
                                              float* __restrict__ yh) {
  __shared__ ushort Ah[4096], Al[4096], Bh[4096], Bl[4096];
  __shared__ ushort CTh[4096], CTl[4096];
  __shared__ ushort Ph[4][1024], Pl[4][1024];
  const int tid = threadIdx.x;
  const int lane = tid & 63, w = tid >> 6, band = w * 16;
  const int bid = blockIdx.x;
  const int by = ((bid & 7) << 3) | (bid >> 6);  // 0..63 row-group
  const int bx = (bid >> 3) & 7;                 // head
  const int b = by >> 5, t0 = (by & 31) * 64, h = bx;
  const int bh = b * 8 + h;
  const int g = lane >> 4, li = lane & 15;
  const int arow = tid >> 2, akc = (tid & 3) * 16;
  const int bn = tid & 63, bkc = (tid >> 6) * 16;
  const float* asrc = x + (b * TB + t0 + arow) * EB;
  const float* wsrc = W2g + bh * 32768;
  const int base = bh * 4096;

  // stage CT (C transposed)
  {
    int n = tid & 63, kc = (tid >> 6) * 16;
    float c[16];
#pragma unroll
    for (int i = 0; i < 16; ++i) c[i] = C[base + (kc + i) * 64 + n];
#pragma unroll
    for (int c2 = 0; c2 < 2; ++c2) {
      int idx = n * 64 + ((((kc >> 3) + c2) ^ (n & 7)) << 3);
      short8 hv, lv;
#pragma unroll
      for (int i = 0; i < 8; ++i) {
        ushort hh, ll;
        split_bf(c[c2 * 8 + i], hh, ll);
        hv[i] = (short)hh;
        lv[i] = (short)ll;
      }
      *(short8*)&CTh[idx] = hv;
      *(short8*)&CTl[idx] = lv;
    }
  }

  f32x4 acc[4];
  zero_acc(acc);
  float av[16], bv[16];
#pragma unroll
  for (int j = 0; j < 4; ++j)
    *(float4*)&av[j * 4] = *(const float4*)&asrc[akc + j * 4];
#pragma unroll
  for (int i = 0; i < 16; ++i) bv[i] = wsrc[(bkc + i) * 64 + bn];

#pragma unroll
  for (int k0 = 0; k0 < 512; k0 += 64) {
    if (k0) __syncthreads();
#pragma unroll
    for (int c2 = 0; c2 < 2; ++c2) {
      short8 hv, lv;
#pragma unroll
      for (int i = 0; i < 8; ++i) {
        ushort hh, ll;
        split_bf(av[c2 * 8 + i], hh, ll);
        hv[i] = (short)hh;
        lv[i] = (short)ll;
      }
      int chunk = ((akc >> 3) + c2) ^ (arow & 7);
      int idx = arow * 64 + chunk * 8;
      *(short8*)&Ah[idx] = hv;
      *(short8*)&Al[idx] = lv;
    }
#pragma unroll
    for (int c2 = 0; c2 < 2; ++c2) {
      short8 hv, lv;
#pragma unroll
      for (int i = 0; i < 8; ++i) {
        ushort hh, ll;
        split_bf(bv[c2 * 8 + i], hh, ll);
        hv[i] = (short)hh;
        lv[i] = (short)ll;
      }
      int chunk = ((bkc >> 3) + c2) ^ (bn & 7);
      int idx = bn * 64 + chunk * 8;
      *(short8*)&Bh[idx] = hv;
      *(short8*)&Bl[idx] = lv;
    }
    __syncthreads();
    if (k0 + 64 < 512) {
#pragma unroll
      for (int j = 0; j < 4; ++j)
        *(float4*)&av[j * 4] = *(const float4*)&asrc[k0 + 64 + akc + j * 4];
#pragma unroll
      for (int i = 0; i < 16; ++i)
        bv[i] = wsrc[(k0 + 64 + bkc + i) * 64 + bn];
    }
    short8 a_h[2], a_l[2];
    const int row = band + li;
#pragma unroll
    for (int kh = 0; kh < 2; ++kh) {
      int chunk = ((kh * 32 + 8 * g) >> 3) ^ (row & 7);
      int idx = row * 64 + chunk * 8;
      a_h[kh] = *(const short8*)&Ah[idx];
      a_l[kh] = *(const short8*)&Al[idx];
    }
    mm_frags(a_h, a_l, Bh, Bl, lane, acc);
  }
  // --- epilogue: + bconst -> softmax -> P@C -> yh
#pragma unroll
  for (int nt = 0; nt < 4; ++nt) {
    float bc = bcst[bh * 64 + nt * 16 + li];
#pragma unroll
    for (int r = 0; r < 4; ++r) acc[nt][r] += bc;
  }
  softmax_rows(acc, band, g, li, t0 == 0, 0);
  wrP(Ph[w], Pl[w], lane, acc);
  short8 p_h[2], p_l[2];
  ld_pfrags(Ph[w], Pl[w], lane, p_h, p_l);
  f32x4 y[4];
  zero_acc(y);
  mm_frags(p_h, p_l, CTh, CTl, lane, y);
#pragma unroll
  for (int nt = 0; nt < 4; ++nt)
#pragma unroll
    for (int r = 0; r < 4; ++r) {
      int t = t0 + band + 4 * g + r;
      int d = nt * 16 + li;
      yh[(b * 2048 + t) * 512 + h * 64 + d] = y[nt][r];
    }
}

// ---------------------------------------------------------------- launcher
extern "C" void kernel_launch(void* const* d_in, const int* in_sizes, int n_in,
                              void* d_out, int out_size, void* d_ws, size_t ws_size,
                              hipStream_t stream) {
  const float* x = (const float*)d_in[0];
  const float* w_qkv = (const float*)d_in[1];
  const float* b_qkv = (const float*)d_in[2];
  const float* w_proj = (const float*)d_in[3];
  const float* b_proj = (const float*)d_in[4];
  float* out = (float*)d_out;

  float* ws = (float*)d_ws;
  float* W2 = ws;                 // 16*512*64 = 524288 (reuses old q slot)
  float* bcst = ws + 524288;      // 1024
  float* k64 = ws + 2097152;      // 16*64*64 = 65536
  float* v64 = k64 + 65536;
  float* xp = v64 + 65536;        // 2*64*512
  float* ql = xp + 65536;
  float* kl = ql + 65536;
  float* Am = kl + 65536;
  float* BV = Am + 65536;
  float* Cm = BV + 65536;
  unsigned int* scal_u = (unsigned int*)(Cm + 65536);  // 1 uint (64 slots)
  float* yh = (float*)(scal_u + 64);  // 2*2048*512 = 2097152

  k_pool<<<dim3(256), dim3(256), 0, stream>>>(x, xp, scal_u);
  k_gemm_mfma<2><<<dim3(16, 4), dim3(256), 0, stream>>>(x, xp, w_qkv, b_qkv,
                                                        k64, v64, ql, kl);
  k_abv_w2<<<dim3(32), dim3(256), 0, stream>>>(ql, kl, k64, v64, w_qkv, b_qkv,
                                               Am, BV, W2, bcst, scal_u);
  k_pinv<<<dim3(16), dim3(256), 0, stream>>>(Am, BV, scal_u, Cm);
  k_f_y2<<<dim3(512), dim3(256), 0, stream>>>(x, W2, bcst, Cm, yh);
  k_gemm_mfma<1><<<dim3(512), dim3(256), 0, stream>>>(yh, nullptr, w_proj, b_proj,
                                                      out, nullptr, nullptr, nullptr);
}

// Round 12
// 135.555 us; speedup vs baseline: 2.1969x; 1.0273x over previous
//
#include <hip/hip_runtime.h>
#include <hip/hip_bf16.h>

// Problem constants: B=2, T=2048, E=512, H=8, hd=64, M=64, l=32, BH=16.
#define TB 2048
#define EB 512

using short8 = __attribute__((ext_vector_type(8))) short;
using f32x4  = __attribute__((ext_vector_type(4))) float;

// ---------------------------------------------------------------- shared helpers
__device__ __forceinline__ int swz_idx(int row, int col) {
  return row * 64 + ((((col >> 3) ^ (row & 7)) << 3) | (col & 7));
}

__device__ __forceinline__ void split_bf(float v, ushort& h, ushort& l) {
  __hip_bfloat16 bh = __float2bfloat16(v);
  float fh = __bfloat162float(bh);
  __hip_bfloat16 bl = __float2bfloat16(v - fh);
  h = *(ushort*)&bh;
  l = *(ushort*)&bl;
}

// acc[nt] += A(frags) @ B(plane [n][k], hi/lo, swizzled)
__device__ __forceinline__ void mm_frags(const short8 ah[2], const short8 al[2],
                                         const ushort* bhp, const ushort* blp,
                                         int lane, f32x4 acc[4]) {
  const int g = lane >> 4, li = lane & 15;
#pragma unroll
  for (int nt = 0; nt < 4; ++nt) {
    f32x4 a = acc[nt];
#pragma unroll
    for (int kh = 0; kh < 2; ++kh) {
      int n = nt * 16 + li;
      int k0 = kh * 32 + 8 * g;
      int idx = n * 64 + ((((k0 >> 3) ^ (n & 7)) << 3));
      short8 bh = *(const short8*)&bhp[idx];
      short8 bl = *(const short8*)&blp[idx];
      a = __builtin_amdgcn_mfma_f32_16x16x32_bf16(al[kh], bh, a, 0, 0, 0);
      a = __builtin_amdgcn_mfma_f32_16x16x32_bf16(ah[kh], bl, a, 0, 0, 0);
      a = __builtin_amdgcn_mfma_f32_16x16x32_bf16(ah[kh], bh, a, 0, 0, 0);
    }
    acc[nt] = a;
  }
}

__device__ __forceinline__ void zero_acc(f32x4 acc[4]) {
#pragma unroll
  for (int nt = 0; nt < 4; ++nt) acc[nt] = (f32x4){0.f, 0.f, 0.f, 0.f};
}

// masked row-softmax on C/D layout: row = band+4g+r, col = nt*16+li.
__device__ __forceinline__ void softmax_rows(f32x4 s[4], int band, int g, int li,
                                             bool causal, int t0) {
#pragma unroll
  for (int r = 0; r < 4; ++r) {
    int trow = t0 + band + 4 * g + r;
    float m = -1e30f;
    float sv[4];
#pragma unroll
    for (int nt = 0; nt < 4; ++nt) {
      int col = nt * 16 + li;
      bool ok = !causal || (col <= trow);
      sv[nt] = ok ? s[nt][r] : -1e30f;
      m = fmaxf(m, sv[nt]);
    }
    m = fmaxf(m, __shfl_xor(m, 1));
    m = fmaxf(m, __shfl_xor(m, 2));
    m = fmaxf(m, __shfl_xor(m, 4));
    m = fmaxf(m, __shfl_xor(m, 8));
    float su = 0.f;
    float ee[4];
#pragma unroll
    for (int nt = 0; nt < 4; ++nt) {
      ee[nt] = (sv[nt] > -1e29f) ? __expf(sv[nt] - m) : 0.f;
      su += ee[nt];
    }
    su += __shfl_xor(su, 1);
    su += __shfl_xor(su, 2);
    su += __shfl_xor(su, 4);
    su += __shfl_xor(su, 8);
    float inv = 1.f / su;
#pragma unroll
    for (int nt = 0; nt < 4; ++nt) s[nt][r] = ee[nt] * inv;
  }
}

// write a 16-row hi/lo P-plane (per-wave region), rows local 0..15
__device__ __forceinline__ void wrP(ushort* hp, ushort* lp, int lane,
                                    const f32x4 acc[4]) {
  const int g = lane >> 4, li = lane & 15;
#pragma unroll
  for (int nt = 0; nt < 4; ++nt) {
    int c = nt * 16 + li;
#pragma unroll
    for (int r = 0; r < 4; ++r) {
      int row = 4 * g + r;
      ushort h, l;
      split_bf(acc[nt][r], h, l);
      int idx = swz_idx(row, c);
      hp[idx] = h;
      lp[idx] = l;
    }
  }
}

__device__ __forceinline__ void ld_pfrags(const ushort* hp, const ushort* lp,
                                          int lane, short8 ah[2], short8 al[2]) {
  const int g = lane >> 4, li = lane & 15;
#pragma unroll
  for (int kh = 0; kh < 2; ++kh) {
    int k0 = kh * 32 + 8 * g;
    int idx = li * 64 + ((((k0 >> 3) ^ (li & 7)) << 3));
    ah[kh] = *(const short8*)&hp[idx];
    al[kh] = *(const short8*)&lp[idx];
  }
}

__device__ __forceinline__ void ld_afrags(const ushort* hp, const ushort* lp,
                                          int band, int lane,
                                          short8 ah[2], short8 al[2]) {
  const int g = lane >> 4, li = lane & 15;
  const int row = band + li;
#pragma unroll
  for (int kh = 0; kh < 2; ++kh) {
    int k0 = kh * 32 + 8 * g;
    int idx = row * 64 + ((((k0 >> 3) ^ (row & 7)) << 3));
    ah[kh] = *(const short8*)&hp[idx];
    al[kh] = *(const short8*)&lp[idx];
  }
}

__device__ __forceinline__ void mm_frags0(const short8 ah[2], const short8 al[2],
                                          const ushort* bhp, const ushort* blp,
                                          int lane, f32x4 acc[4]) {
  zero_acc(acc);
  mm_frags(ah, al, bhp, blp, lane, acc);
}

// plane[col][r0..r0+3] = mul*acc + cI on diagonal (works for LDS or global ptr)
__device__ __forceinline__ void wrT(ushort* hp, ushort* lp, int band, int lane,
                                    const f32x4 acc[4], float cI, float mul) {
  const int g = lane >> 4, li = lane & 15;
  const int r0 = band + 4 * g;
#pragma unroll
  for (int nt = 0; nt < 4; ++nt) {
    int c = nt * 16 + li;
    ushort h[4], l[4];
#pragma unroll
    for (int r = 0; r < 4; ++r) {
      float v = mul * acc[nt][r] + ((r0 + r) == c ? cI : 0.f);
      split_bf(v, h[r], l[r]);
    }
    int idx = c * 64 + (((((r0) >> 3) ^ (c & 7)) << 3) | (r0 & 7));
    *(ushort4*)&hp[idx] = make_ushort4(h[0], h[1], h[2], h[3]);
    *(ushort4*)&lp[idx] = make_ushort4(l[0], l[1], l[2], l[3]);
  }
}

// plane[row][col] = mul*acc
__device__ __forceinline__ void wrN(ushort* hp, ushort* lp, int band, int lane,
                                    const f32x4 acc[4], float mul) {
  const int g = lane >> 4, li = lane & 15;
#pragma unroll
  for (int nt = 0; nt < 4; ++nt) {
    int c = nt * 16 + li;
#pragma unroll
    for (int r = 0; r < 4; ++r) {
      int row = band + 4 * g + r;
      ushort h, l;
      split_bf(mul * acc[nt][r], h, l);
      int idx = swz_idx(row, c);
      hp[idx] = h;
      lp[idx] = l;
    }
  }
}

// ---------------------------------------------------------------- pool x (blk 0-255) + w_proj pre-split (blk 256-319)
__global__ __launch_bounds__(256) void k_pool(const float* __restrict__ x,
                                              const float* __restrict__ w_proj,
                                              float* __restrict__ xp,
                                              ushort* __restrict__ WpH,
                                              ushort* __restrict__ WpL) {
  const int tid = threadIdx.x;
  if (blockIdx.x >= 256) {
    int t = blockIdx.x - 256;  // tile id: bx*8 + kt
    int bxp = t >> 3, kt = t & 7;
    int n = tid & 63, kc = (tid >> 6) * 16;
#pragma unroll
    for (int i = 0; i < 16; ++i) {
      int k = kc + i;
      float v = w_proj[(kt * 64 + k) * 512 + bxp * 64 + n];
      ushort h, l;
      split_bf(v, h, l);
      int idx = t * 4096 + swz_idx(n, k);
      WpH[idx] = h;
      WpL[idx] = l;
    }
    return;
  }
  int idx = blockIdx.x * 256 + tid;  // [0, 2*64*512)
  int b = idx >> 15;
  int rem = idx & 32767;
  int m = rem >> 9;
  int e = rem & 511;
  const float* src = x + (b * TB + m * 32) * EB + e;
  float s = 0.f;
#pragma unroll
  for (int i = 0; i < 32; ++i) s += src[i * EB];
  xp[idx] = s * (1.f / 32.f);
}

// ---------------------------------------------------------------- small GEMMs (k64/v64, ql/kl)
__global__ __launch_bounds__(256) void k_small(const float* __restrict__ A,
                                               const float* __restrict__ A2,
                                               const float* __restrict__ W,
                                               const float* __restrict__ bias,
                                               float* __restrict__ o0,
                                               float* __restrict__ o1,
                                               float* __restrict__ o2,
                                               float* __restrict__ o3) {
  constexpr int LDW = 1536;
  __shared__ ushort Ah[4096], Al[4096], Bh[4096], Bl[4096];
  const int tid = threadIdx.x;
  const int lane = tid & 63, w = tid >> 6, band = w * 16;
  const int bx = blockIdx.x, by = blockIdx.y;
  const int variant = by >> 1;
  const int m0 = (by & 1) * 64;
  const int bcol0 = (variant == 0 ? 512 + bx * 64 : bx * 64);
  const int g = lane >> 4, li = lane & 15;
  const int arow = tid >> 2, akc = (tid & 3) * 16;
  const int bn = tid & 63, bkc = (tid >> 6) * 16;

  const float* asrc;
  {
    int gr = m0 + arow;
    asrc = (variant == 0) ? (A + ((gr >> 6) * TB + (gr & 63)) * EB)
                          : (A2 + gr * EB);
  }

  f32x4 acc[4];
  zero_acc(acc);
  float av[16], bv[16];
#pragma unroll
  for (int j = 0; j < 4; ++j)
    *(float4*)&av[j * 4] = *(const float4*)&asrc[akc + j * 4];
#pragma unroll
  for (int i = 0; i < 16; ++i) bv[i] = W[(bkc + i) * LDW + bcol0 + bn];

#pragma unroll
  for (int k0 = 0; k0 < 512; k0 += 64) {
    if (k0) __syncthreads();
#pragma unroll
    for (int c2 = 0; c2 < 2; ++c2) {
      short8 hv, lv;
#pragma unroll
      for (int i = 0; i < 8; ++i) {
        ushort h, l;
        split_bf(av[c2 * 8 + i], h, l);
        hv[i] = (short)h;
        lv[i] = (short)l;
      }
      int chunk = ((akc >> 3) + c2) ^ (arow & 7);
      int idx = arow * 64 + chunk * 8;
      *(short8*)&Ah[idx] = hv;
      *(short8*)&Al[idx] = lv;
    }
#pragma unroll
    for (int c2 = 0; c2 < 2; ++c2) {
      short8 hv, lv;
#pragma unroll
      for (int i = 0; i < 8; ++i) {
        ushort h, l;
        split_bf(bv[c2 * 8 + i], h, l);
        hv[i] = (short)h;
        lv[i] = (short)l;
      }
      int chunk = ((bkc >> 3) + c2) ^ (bn & 7);
      int idx = bn * 64 + chunk * 8;
      *(short8*)&Bh[idx] = hv;
      *(short8*)&Bl[idx] = lv;
    }
    __syncthreads();
    if (k0 + 64 < 512) {
#pragma unroll
      for (int j = 0; j < 4; ++j)
        *(float4*)&av[j * 4] = *(const float4*)&asrc[k0 + 64 + akc + j * 4];
#pragma unroll
      for (int i = 0; i < 16; ++i)
        bv[i] = W[(k0 + 64 + bkc + i) * LDW + bcol0 + bn];
    }
    short8 a_h[2], a_l[2];
    const int row = band + li;
#pragma unroll
    for (int kh = 0; kh < 2; ++kh) {
      int chunk = ((kh * 32 + 8 * g) >> 3) ^ (row & 7);
      int idx = row * 64 + chunk * 8;
      a_h[kh] = *(const short8*)&Ah[idx];
      a_l[kh] = *(const short8*)&Al[idx];
    }
    mm_frags(a_h, a_l, Bh, Bl, lane, acc);
  }
#pragma unroll
  for (int nt = 0; nt < 4; ++nt) {
#pragma unroll
    for (int r = 0; r < 4; ++r) {
      int trow = band + 4 * g + r;
      int gcol = bcol0 + nt * 16 + li;
      float v = acc[nt][r] + bias[gcol];
      int gr = m0 + trow;
      int b = gr >> 6, t = gr & 63;
      int cloc = (variant == 0) ? (gcol - 512) : gcol;
      int which = cloc >> 9;
      int hd_ = cloc & 511;
      int h = hd_ >> 6, d = hd_ & 63;
      int dst = ((b * 8 + h) * 64 + t) * 64 + d;
      if (variant == 0) {
        if (which == 0) o0[dst] = v; else o1[dst] = v;
      } else {
        if (which == 0) o2[dst] = v * 0.125f; else o3[dst] = v;
      }
    }
  }
}

// ---------------------------------------------------------------- a_bv + pinv fused (blk 0-15) ; W2 planes (blk 16-31)
// Per-bh pinv scale: rowsum(A)==1 exactly, so z0 = A^T / colsum_max(this bh) --
// the per-matrix ||A||_1*||A||_inf bound (tighter than ref's batch-max; both
// fully converged after 6 cubic NS iters). C written directly as CT planes.
__global__ __launch_bounds__(256) void k_abv_pinv(
    const float* __restrict__ qlg, const float* __restrict__ klg,
    const float* __restrict__ k64, const float* __restrict__ v64,
    const float* __restrict__ w_qkv, const float* __restrict__ b_qkv,
    ushort* __restrict__ W2H, ushort* __restrict__ W2L,
    float* __restrict__ bcst,
    ushort* __restrict__ CTH, ushort* __restrict__ CTL) {
  __shared__ ushort pl[12][4096];
  __shared__ float red[4][64];
  __shared__ float scs;
  const int tid = threadIdx.x;
  const int lane = tid & 63, w = tid >> 6, band = w * 16;
  const int g = lane >> 4, li = lane & 15;

  if (blockIdx.x >= 16) {
    // ---------------- W2 planes for bh = blockIdx.x - 16
    const int bh = blockIdx.x - 16;
    const int h = bh & 7;
    const int base = bh * 4096;
    {
      int n = tid & 63, kc = (tid >> 6) * 16;
      float a[16];
#pragma unroll
      for (int i = 0; i < 16; ++i) a[i] = klg[base + n * 64 + kc + i];
#pragma unroll
      for (int c2 = 0; c2 < 2; ++c2) {
        int idx = n * 64 + ((((kc >> 3) + c2) ^ (n & 7)) << 3);
        short8 hv, lv;
#pragma unroll
        for (int i = 0; i < 8; ++i) {
          ushort hh, ll;
          split_bf(a[c2 * 8 + i], hh, ll);
          hv[i] = (short)hh;
          lv[i] = (short)ll;
        }
        *(short8*)&pl[0][idx] = hv;
        *(short8*)&pl[1][idx] = lv;
      }
    }
    __syncthreads();
    if (tid < 64) {
      float bc = 0.f;
      for (int d = 0; d < 64; ++d)
        bc += b_qkv[h * 64 + d] * klg[base + tid * 64 + d];
      bcst[bh * 64 + tid] = 0.125f * bc;
    }
#pragma unroll
    for (int m0 = 0; m0 < 512; m0 += 64) {
      short8 a_h[2], a_l[2];
      int row = m0 + band + li;
#pragma unroll
      for (int kh = 0; kh < 2; ++kh) {
        int d0 = kh * 32 + 8 * g;
        float tmp[8];
        *(float4*)&tmp[0] = *(const float4*)&w_qkv[row * 1536 + h * 64 + d0];
        *(float4*)&tmp[4] = *(const float4*)&w_qkv[row * 1536 + h * 64 + d0 + 4];
        short8 hv, lv;
#pragma unroll
        for (int i = 0; i < 8; ++i) {
          ushort hh, ll;
          split_bf(tmp[i], hh, ll);
          hv[i] = (short)hh;
          lv[i] = (short)ll;
        }
        a_h[kh] = hv;
        a_l[kh] = lv;
      }
      f32x4 acc[4];
      mm_frags0(a_h, a_l, pl[0], pl[1], lane, acc);
      // B-plane format [n=j][k=e]: wrT writes plane[col][row] = 0.125*acc
      wrT(W2H + bh * 32768 + (m0 >> 6) * 4096,
          W2L + bh * 32768 + (m0 >> 6) * 4096, band, lane, acc, 0.f, 0.125f);
    }
    return;
  }

  // ---------------- a_bv for bh = blockIdx.x
  const int bh = blockIdx.x;
  const int base = bh * 4096;
  // stage: KL=pl0/1, K=pl2/3, VT=pl4/5 (P lives in pl6/7)
  {
    int n = tid & 63, kc = (tid >> 6) * 16;
    float a[16], b[16], c[16];
#pragma unroll
    for (int i = 0; i < 16; ++i) {
      a[i] = klg[base + n * 64 + kc + i];
      b[i] = k64[base + n * 64 + kc + i];
      c[i] = v64[base + (kc + i) * 64 + n];
    }
#pragma unroll
    for (int c2 = 0; c2 < 2; ++c2) {
      int idx = n * 64 + ((((kc >> 3) + c2) ^ (n & 7)) << 3);
      short8 hv, lv;
#pragma unroll
      for (int i = 0; i < 8; ++i) { ushort h, l; split_bf(a[c2*8+i], h, l); hv[i]=(short)h; lv[i]=(short)l; }
      *(short8*)&pl[0][idx] = hv; *(short8*)&pl[1][idx] = lv;
#pragma unroll
      for (int i = 0; i < 8; ++i) { ushort h, l; split_bf(b[c2*8+i], h, l); hv[i]=(short)h; lv[i]=(short)l; }
      *(short8*)&pl[2][idx] = hv; *(short8*)&pl[3][idx] = lv;
#pragma unroll
      for (int i = 0; i < 8; ++i) { ushort h, l; split_bf(c[c2*8+i], h, l); hv[i]=(short)h; lv[i]=(short)l; }
      *(short8*)&pl[4][idx] = hv; *(short8*)&pl[5][idx] = lv;
    }
  }
  short8 q_h[2], q_l[2];
  {
    int row = band + li;
#pragma unroll
    for (int kh = 0; kh < 2; ++kh) {
      int k0 = kh * 32 + 8 * g;
      float tmp[8];
      *(float4*)&tmp[0] = *(const float4*)&qlg[base + row * 64 + k0];
      *(float4*)&tmp[4] = *(const float4*)&qlg[base + row * 64 + k0 + 4];
      short8 hv, lv;
#pragma unroll
      for (int i = 0; i < 8; ++i) { ushort h, l; split_bf(tmp[i], h, l); hv[i]=(short)h; lv[i]=(short)l; }
      q_h[kh] = hv; q_l[kh] = lv;
    }
  }
  __syncthreads();
  // S1 = ql @ kl^T -> softmax -> A (regs)
  f32x4 s1[4];
  mm_frags0(q_h, q_l, pl[0], pl[1], lane, s1);
  softmax_rows(s1, band, g, li, true, 0);
  // per-bh scal = 1 / max colsum(A)
  {
    float part[4];
#pragma unroll
    for (int nt = 0; nt < 4; ++nt) {
      part[nt] = s1[nt][0] + s1[nt][1] + s1[nt][2] + s1[nt][3];
      part[nt] += __shfl_xor(part[nt], 16);
      part[nt] += __shfl_xor(part[nt], 32);
    }
    if (g == 0) {
#pragma unroll
      for (int nt = 0; nt < 4; ++nt) red[w][nt * 16 + li] = part[nt];
    }
    __syncthreads();
    if (tid < 64) {
      float t = red[0][tid] + red[1][tid] + red[2][tid] + red[3][tid];
#pragma unroll
      for (int off = 32; off; off >>= 1) t = fmaxf(t, __shfl_xor(t, off));
      if (tid == 0) scs = 1.f / t;
    }
    __syncthreads();
  }
  const float sc = scs;
  // S2 = ql @ k64^T -> softmax -> P -> BV = P @ v64
  f32x4 s2[4];
  mm_frags0(q_h, q_l, pl[2], pl[3], lane, s2);
  softmax_rows(s2, band, g, li, true, 0);
  wrP(&pl[6][w * 1024], &pl[7][w * 1024], lane, s2);
  short8 p_h[2], p_l[2];
  ld_pfrags(&pl[6][w * 1024], &pl[7][w * 1024], lane, p_h, p_l);
  f32x4 y[4];
  mm_frags0(p_h, p_l, pl[4], pl[5], lane, y);
  __syncthreads();  // all waves done with all abv planes
  // ---------------- transition to pinv (planes: ZT=10/11 ZA=2/3 PA=4/5 QA=6/7 QB=0/1 BT=8/9)
  wrT(pl[8], pl[9], band, lane, y, 0.f, 1.f);    // BT[n=d][k=i] = BV[i][d]
  wrN(pl[10], pl[11], band, lane, s1, sc);       // ZT[n][k] = sc*A[n][k]
  wrT(pl[2], pl[3], band, lane, s1, 0.f, sc);    // ZA[row][k] = sc*A[k][row]
  wrN(pl[0], pl[1], band, lane, s1, 1.f);        // AN (A as left operand)
  __syncthreads();
  short8 a_h[2], a_l[2];
  ld_afrags(pl[0], pl[1], band, lane, a_h, a_l);
  __syncthreads();  // a-frags in regs before QB overwrites pl0/1
  for (int it = 0; it < 6; ++it) {
    f32x4 acc[4];
    mm_frags0(a_h, a_l, pl[10], pl[11], lane, acc);   // P = A@Z
    wrN(pl[4], pl[5], band, lane, acc, 1.f);          // PA
    wrT(pl[6], pl[7], band, lane, acc, 7.f, -1.f);    // QA = 7I-P
    __syncthreads();
    short8 pp_h[2], pp_l[2];
    ld_afrags(pl[4], pl[5], band, lane, pp_h, pp_l);
    mm_frags0(pp_h, pp_l, pl[6], pl[7], lane, acc);   // R = P@QA
    wrT(pl[0], pl[1], band, lane, acc, 15.f, -1.f);   // QB = 15I-R
    __syncthreads();
    mm_frags0(pp_h, pp_l, pl[0], pl[1], lane, acc);   // R2 = P@QB
    wrT(pl[6], pl[7], band, lane, acc, 13.f, -1.f);   // QA = 13I-R2
    __syncthreads();
    short8 z_h[2], z_l[2];
    ld_afrags(pl[2], pl[3], band, lane, z_h, z_l);
    mm_frags0(z_h, z_l, pl[6], pl[7], lane, acc);     // Znew' = Z@QA
    __syncthreads();  // ld(ZA) complete everywhere before overwrite
    wrN(pl[2], pl[3], band, lane, acc, 0.25f);        // ZA
    wrT(pl[10], pl[11], band, lane, acc, 0.f, 0.25f); // ZT
    __syncthreads();
  }
  // epilogue: C = Z @ BV -> CT planes (global)
  {
    short8 z_h[2], z_l[2];
    ld_afrags(pl[2], pl[3], band, lane, z_h, z_l);
    f32x4 acc[4];
    mm_frags0(z_h, z_l, pl[8], pl[9], lane, acc);
    wrT(CTH + bh * 4096, CTL + bh * 4096, band, lane, acc, 0.f, 1.f);
  }
}

// ---------------------------------------------------------------- fused F: x@W2 -> softmax -> @C -> yh planes
__global__ __launch_bounds__(256) void k_f_y2(const float* __restrict__ x,
                                              const ushort* __restrict__ W2H,
                                              const ushort* __restrict__ W2L,
                                              const float* __restrict__ bcst,
                                              const ushort* __restrict__ CTH,
                                              const ushort* __restrict__ CTL,
                                              ushort* __restrict__ yhH,
                                              ushort* __restrict__ yhL) {
  __shared__ ushort Bh[4096], Bl[4096], CTs_h[4096], CTs_l[4096];
  const int tid = threadIdx.x;
  const int lane = tid & 63, w = tid >> 6, band = w * 16;
  const int bid = blockIdx.x;
  const int by = ((bid & 7) << 3) | (bid >> 6);  // row-group 0..63 (XCD remap)
  const int bx = (bid >> 3) & 7;                 // head
  const int b = by >> 5, t0 = (by & 31) * 64, h = bx;
  const int bh = b * 8 + h;
  const int g = lane >> 4, li = lane & 15;

  // CT copy (once)
  {
    const ushort* sh = CTH + bh * 4096;
    const ushort* sl = CTL + bh * 4096;
    *(short8*)&CTs_h[tid * 8] = *(const short8*)&sh[tid * 8];
    *(short8*)&CTs_h[2048 + tid * 8] = *(const short8*)&sh[2048 + tid * 8];
    *(short8*)&CTs_l[tid * 8] = *(const short8*)&sl[tid * 8];
    *(short8*)&CTs_l[2048 + tid * 8] = *(const short8*)&sl[2048 + tid * 8];
  }
  const ushort* wH = W2H + bh * 32768;
  const ushort* wL = W2L + bh * 32768;
  const float* xrow = x + (b * TB + t0 + band + li) * EB;  // per-lane A row

  f32x4 acc[4];
  zero_acc(acc);
  float a8[2][2][8];
  short8 rb[2][4];
  // prefetch tile 0
#pragma unroll
  for (int kh = 0; kh < 2; ++kh) {
    *(float4*)&a8[0][kh][0] = *(const float4*)&xrow[kh * 32 + 8 * g];
    *(float4*)&a8[0][kh][4] = *(const float4*)&xrow[kh * 32 + 8 * g + 4];
  }
  rb[0][0] = *(const short8*)&wH[tid * 8];
  rb[0][1] = *(const short8*)&wH[2048 + tid * 8];
  rb[0][2] = *(const short8*)&wL[tid * 8];
  rb[0][3] = *(const short8*)&wL[2048 + tid * 8];

#pragma unroll
  for (int kt = 0; kt < 8; ++kt) {
    const int cur = kt & 1, nxt = cur ^ 1;
    if (kt) __syncthreads();
    *(short8*)&Bh[tid * 8] = rb[cur][0];
    *(short8*)&Bh[2048 + tid * 8] = rb[cur][1];
    *(short8*)&Bl[tid * 8] = rb[cur][2];
    *(short8*)&Bl[2048 + tid * 8] = rb[cur][3];
    __syncthreads();
    if (kt < 7) {
      int k0 = (kt + 1) * 64;
#pragma unroll
      for (int kh = 0; kh < 2; ++kh) {
        *(float4*)&a8[nxt][kh][0] = *(const float4*)&xrow[k0 + kh * 32 + 8 * g];
        *(float4*)&a8[nxt][kh][4] = *(const float4*)&xrow[k0 + kh * 32 + 8 * g + 4];
      }
      const ushort* wHt = wH + (kt + 1) * 4096;
      const ushort* wLt = wL + (kt + 1) * 4096;
      rb[nxt][0] = *(const short8*)&wHt[tid * 8];
      rb[nxt][1] = *(const short8*)&wHt[2048 + tid * 8];
      rb[nxt][2] = *(const short8*)&wLt[tid * 8];
      rb[nxt][3] = *(const short8*)&wLt[2048 + tid * 8];
    }
    short8 a_h[2], a_l[2];
#pragma unroll
    for (int kh = 0; kh < 2; ++kh) {
      short8 hv, lv;
#pragma unroll
      for (int i = 0; i < 8; ++i) {
        ushort hh, ll;
        split_bf(a8[cur][kh][i], hh, ll);
        hv[i] = (short)hh;
        lv[i] = (short)ll;
      }
      a_h[kh] = hv;
      a_l[kh] = lv;
    }
    mm_frags(a_h, a_l, Bh, Bl, lane, acc);
  }
  // epilogue: + bconst -> softmax -> P (aliased into Bh/Bl) -> @CT -> yh planes
#pragma unroll
  for (int nt = 0; nt < 4; ++nt) {
    float bc = bcst[bh * 64 + nt * 16 + li];
#pragma unroll
    for (int r = 0; r < 4; ++r) acc[nt][r] += bc;
  }
  softmax_rows(acc, band, g, li, t0 == 0, 0);
  __syncthreads();  // all waves done reading Bh/Bl
  wrP(&Bh[w * 1024], &Bl[w * 1024], lane, acc);
  short8 p_h[2], p_l[2];
  ld_pfrags(&Bh[w * 1024], &Bl[w * 1024], lane, p_h, p_l);
  f32x4 y[4];
  mm_frags0(p_h, p_l, CTs_h, CTs_l, lane, y);
  const int pb = (by * 8 + h) * 4096;  // A-plane tile (row-group by, k-tile h)
#pragma unroll
  for (int nt = 0; nt < 4; ++nt) {
#pragma unroll
    for (int r = 0; r < 4; ++r) {
      ushort hh, ll;
      split_bf(y[nt][r], hh, ll);
      int idx = pb + swz_idx(band + 4 * g + r, nt * 16 + li);
      yhH[idx] = hh;
      yhL[idx] = ll;
    }
  }
}

// ---------------------------------------------------------------- out-proj from planes
__global__ __launch_bounds__(256) void k_proj(const ushort* __restrict__ yhH,
                                              const ushort* __restrict__ yhL,
                                              const ushort* __restrict__ WpH,
                                              const ushort* __restrict__ WpL,
                                              const float* __restrict__ bias,
                                              float* __restrict__ out) {
  __shared__ ushort Bh[4096], Bl[4096];
  const int tid = threadIdx.x;
  const int lane = tid & 63, w = tid >> 6, band = w * 16;
  const int bid = blockIdx.x;
  const int by = ((bid & 7) << 3) | (bid >> 6);
  const int bx = (bid >> 3) & 7;
  const int g = lane >> 4, li = lane & 15;
  const ushort* aH = yhH + by * 32768;
  const ushort* aL = yhL + by * 32768;
  const ushort* wH = WpH + bx * 32768;
  const ushort* wL = WpL + bx * 32768;

  f32x4 acc[4];
  zero_acc(acc);
  short8 rb[2][4];
  rb[0][0] = *(const short8*)&wH[tid * 8];
  rb[0][1] = *(const short8*)&wH[2048 + tid * 8];
  rb[0][2] = *(const short8*)&wL[tid * 8];
  rb[0][3] = *(const short8*)&wL[2048 + tid * 8];

  const int row = band + li;
#pragma unroll
  for (int kt = 0; kt < 8; ++kt) {
    const int cur = kt & 1, nxt = cur ^ 1;
    if (kt) __syncthreads();
    *(short8*)&Bh[tid * 8] = rb[cur][0];
    *(short8*)&Bh[2048 + tid * 8] = rb[cur][1];
    *(short8*)&Bl[tid * 8] = rb[cur][2];
    *(short8*)&Bl[2048 + tid * 8] = rb[cur][3];
    __syncthreads();
    if (kt < 7) {
      const ushort* wHt = wH + (kt + 1) * 4096;
      const ushort* wLt = wL + (kt + 1) * 4096;
      rb[nxt][0] = *(const short8*)&wHt[tid * 8];
      rb[nxt][1] = *(const short8*)&wHt[2048 + tid * 8];
      rb[nxt][2] = *(const short8*)&wLt[tid * 8];
      rb[nxt][3] = *(const short8*)&wLt[2048 + tid * 8];
    }
    // A-frags direct from global planes (per-wave exclusive rows)
    short8 a_h[2], a_l[2];
#pragma unroll
    for (int kh = 0; kh < 2; ++kh) {
      int chunk = ((kh * 32 + 8 * g) >> 3) ^ (row & 7);
      int idx = kt * 4096 + row * 64 + chunk * 8;
      a_h[kh] = *(const short8*)&aH[idx];
      a_l[kh] = *(const short8*)&aL[idx];
    }
    mm_frags(a_h, a_l, Bh, Bl, lane, acc);
  }
#pragma unroll
  for (int nt = 0; nt < 4; ++nt) {
#pragma unroll
    for (int r = 0; r < 4; ++r) {
      int trow = by * 64 + band + 4 * g + r;
      int gcol = bx * 64 + nt * 16 + li;
      out[trow * 512 + gcol] = acc[nt][r] + bias[gcol];
    }
  }
}

// ---------------------------------------------------------------- launcher
extern "C" void kernel_launch(void* const* d_in, const int* in_sizes, int n_in,
                              void* d_out, int out_size, void* d_ws, size_t ws_size,
                              hipStream_t stream) {
  const float* x = (const float*)d_in[0];
  const float* w_qkv = (const float*)d_in[1];
  const float* b_qkv = (const float*)d_in[2];
  const float* w_proj = (const float*)d_in[3];
  const float* b_proj = (const float*)d_in[4];
  float* out = (float*)d_out;

  char* base = (char*)d_ws;
  ushort* W2H = (ushort*)(base);                         // 1MB
  ushort* W2L = (ushort*)(base + (1 << 20));             // 1MB
  float* bcst = (float*)(base + (2 << 20));              // 4KB
  ushort* CTH = (ushort*)(base + (2 << 20) + (1 << 16)); // 128KB
  ushort* CTL = (ushort*)(base + (2 << 20) + (3 << 16)); // 128KB
  ushort* WpH = (ushort*)(base + (3 << 20));             // 512KB
  ushort* WpL = (ushort*)(base + (3 << 20) + (1 << 19)); // 512KB
  ushort* yhH = (ushort*)(base + (4 << 20));             // 4MB
  ushort* yhL = (ushort*)(base + (8 << 20));             // 4MB
  float* k64 = (float*)(base + (12 << 20));
  float* v64 = (float*)(base + (13 << 20));
  float* xp  = (float*)(base + (14 << 20));
  float* ql  = (float*)(base + (15 << 20));
  float* kl  = (float*)(base + (16 << 20));

  k_pool<<<dim3(320), dim3(256), 0, stream>>>(x, w_proj, xp, WpH, WpL);
  k_small<<<dim3(16, 4), dim3(256), 0, stream>>>(x, xp, w_qkv, b_qkv,
                                                 k64, v64, ql, kl);
  k_abv_pinv<<<dim3(32), dim3(256), 0, stream>>>(ql, kl, k64, v64, w_qkv, b_qkv,
                                                 W2H, W2L, bcst, CTH, CTL);
  k_f_y2<<<dim3(512), dim3(256), 0, stream>>>(x, W2H, W2L, bcst, CTH, CTL,
                                              yhH, yhL);
  k_proj<<<dim3(512), dim3(256), 0, stream>>>(yhH, yhL, WpH, WpL, b_proj, out);
}